// Round 14
// baseline (418.853 us; speedup 1.0000x reference)
//
#include <hip/hip_runtime.h>
#include <math.h>

#define NPTS 16384
#define KG 20
#define KN 10
#define KC 6
#define EPSF 1e-8f

#define GDIM 32
#define GL 4.75f
#define CW 0.296875f
#define GINV 3.3684210526f
#define RMAX 6

typedef __attribute__((ext_vector_type(8))) short short8v;
typedef __attribute__((ext_vector_type(4))) float floatx4;

__device__ __forceinline__ unsigned short f2bf(float v) {
  union { float f; unsigned u; } x;
  x.f = v;
  unsigned r = x.u + 0x7FFFu + ((x.u >> 16) & 1u);  // RNE (finite inputs)
  return (unsigned short)(r >> 16);
}

__device__ __forceinline__ float bf2f(unsigned short u) {
  union { unsigned u32; float f; } x;
  x.u32 = (unsigned)u << 16;
  return x.f;
}

// sorted insert into KG-register list (strict <, stable by scan order)
#define KNN_INSERT(d2v, iv)                                                 \
  if ((d2v) < dist[KG - 1]) {                                               \
    dist[KG - 1] = (d2v); idx[KG - 1] = (iv);                               \
    _Pragma("unroll")                                                       \
    for (int s_ = KG - 1; s_ > 0; --s_) {                                   \
      if (dist[s_] < dist[s_ - 1]) {                                        \
        float td_ = dist[s_]; dist[s_] = dist[s_ - 1]; dist[s_ - 1] = td_;  \
        int ti_ = idx[s_]; idx[s_] = idx[s_ - 1]; idx[s_ - 1] = ti_;        \
      }                                                                     \
    }                                                                       \
  }

// sorted insert into KC-register list
#define KNN_INSERTC(d2v, iv)                                                \
  if ((d2v) < dist[KC - 1]) {                                               \
    dist[KC - 1] = (d2v); idx[KC - 1] = (iv);                               \
    _Pragma("unroll")                                                       \
    for (int s_ = KC - 1; s_ > 0; --s_) {                                   \
      if (dist[s_] < dist[s_ - 1]) {                                        \
        float td_ = dist[s_]; dist[s_] = dist[s_ - 1]; dist[s_ - 1] = td_;  \
        int ti_ = idx[s_]; idx[s_] = idx[s_ - 1]; idx[s_ - 1] = ti_;        \
      }                                                                     \
    }                                                                       \
  }

__device__ __forceinline__ int cell_of(float x) {
  int c = (int)floorf((x + GL) * GINV);
  return min(max(c, 0), GDIM - 1);
}

// ---------------------------------------------------------------- pos concat + bin (fused)
__global__ __launch_bounds__(256) void posbin_kernel(const float* __restrict__ pts,
                                                     const float* __restrict__ als,
                                                     float4* __restrict__ pos4,
                                                     int* __restrict__ cell_count,
                                                     int* __restrict__ pt_cell) {
  int n = blockIdx.x * 256 + threadIdx.x;
  if (n >= NPTS) return;
  const float* src = (n < 8192) ? (pts + (size_t)n * 3) : (als + (size_t)(n - 8192) * 3);
  float x = src[0], y = src[1], z = src[2];
  pos4[n] = make_float4(x, y, z, 0.f);
  int c = (cell_of(z) * GDIM + cell_of(y)) * GDIM + cell_of(x);
  pt_cell[n] = c;
  atomicAdd(&cell_count[c], 1);
}

__global__ __launch_bounds__(1024) void scan_kernel(const int* __restrict__ cell_count,
                                                    int* __restrict__ cell_start,
                                                    int* __restrict__ cell_cursor) {
  __shared__ int s[1024];
  int tid = threadIdx.x;
  int base = tid * 32;
  int local[32];
  int sum = 0;
#pragma unroll
  for (int i = 0; i < 32; ++i) { local[i] = cell_count[base + i]; sum += local[i]; }
  s[tid] = sum;
  __syncthreads();
  for (int off = 1; off < 1024; off <<= 1) {
    int v = (tid >= off) ? s[tid - off] : 0;
    __syncthreads();
    s[tid] += v;
    __syncthreads();
  }
  int run = s[tid] - sum;  // exclusive prefix
#pragma unroll
  for (int i = 0; i < 32; ++i) {
    cell_start[base + i] = run;
    cell_cursor[base + i] = run;
    run += local[i];
  }
}

// scatter into sorted order; sortmap[slot] = original index
__global__ __launch_bounds__(256) void scatter_kernel(const float4* __restrict__ pos4,
                                                      const int* __restrict__ pt_cell,
                                                      int* __restrict__ cell_cursor,
                                                      float4* __restrict__ sorted4,
                                                      int* __restrict__ sortmap) {
  int i = blockIdx.x * 256 + threadIdx.x;
  if (i >= NPTS) return;
  int c = pt_cell[i];
  int dst = atomicAdd(&cell_cursor[c], 1);
  float4 p = pos4[i];
  p.w = __int_as_float(i);
  sorted4[dst] = p;
  sortmap[dst] = i;
}

// ---------------- sparse-first query ordering: 64-bin occupancy histogram + scatter
__global__ __launch_bounds__(256) void qhist_kernel(const float4* __restrict__ sorted4,
                                                    const int* __restrict__ cell_count,
                                                    int* __restrict__ bcur) {
  __shared__ int hist[64];
  int tid = threadIdx.x;
  if (tid < 64) hist[tid] = 0;
  __syncthreads();
  for (int s = tid; s < NPTS; s += 256) {
    float4 p = sorted4[s];
    int c = (cell_of(p.z) * GDIM + cell_of(p.y)) * GDIM + cell_of(p.x);
    int occ = min(cell_count[c], 63);
    atomicAdd(&hist[occ], 1);
  }
  __syncthreads();
  if (tid == 0) {
    int run = 0;
    for (int b = 0; b < 64; ++b) { bcur[b] = run; run += hist[b]; }
  }
}

__global__ __launch_bounds__(256) void qorder_kernel(const float4* __restrict__ sorted4,
                                                     const int* __restrict__ cell_count,
                                                     int* __restrict__ bcur,
                                                     int* __restrict__ qorder) {
  int s = blockIdx.x * 256 + threadIdx.x;
  if (s >= NPTS) return;
  float4 p = sorted4[s];
  int c = (cell_of(p.z) * GDIM + cell_of(p.y)) * GDIM + cell_of(p.x);
  int occ = min(cell_count[c], 63);
  int dst = atomicAdd(&bcur[occ], 1);
  qorder[dst] = s;
}

// --------- grid knn in SORTED-SLOT space: 2 queries/wave, 32 lanes each, cap-KC.
// Queries processed sparse-first via qorder to kill the drain tail.
__global__ __launch_bounds__(256) void knn_grid_kernel(const float4* __restrict__ sorted4,
                                                       const int* __restrict__ cell_start,
                                                       const int* __restrict__ cell_count,
                                                       const int* __restrict__ qorder,
                                                       int* __restrict__ nbr,
                                                       int* __restrict__ fb_list,
                                                       int* __restrict__ fb_count) {
  int lane = threadIdx.x & 63;
  int sub = lane >> 5;   // 2 query subgroups per wave
  int sl = lane & 31;    // lane within subgroup
  int qlin = blockIdx.x * 8 + (threadIdx.x >> 6) * 2 + sub;
  if (qlin >= NPTS) return;
  int qs = qorder[qlin];  // sparse-first order (broadcast load)
  float4 p = sorted4[qs];
  int cx = cell_of(p.x), cy = cell_of(p.y), cz = cell_of(p.z);
  float dist[KC];
  int idx[KC];
#pragma unroll
  for (int i = 0; i < KC; ++i) { dist[i] = 3.4e38f; idx[i] = 0; }

  // ---- phase 1: full box r<=1 (continuous round-robin over 32 lanes)
  {
    int tot = 0;
    int x0 = max(cx - 1, 0), x1 = min(cx + 1, GDIM - 1);
    int zlo = max(cz - 1, 0), zhi = min(cz + 1, GDIM - 1);
    int ylo = max(cy - 1, 0), yhi = min(cy + 1, GDIM - 1);
    for (int z = zlo; z <= zhi; ++z) {
      for (int y = ylo; y <= yhi; ++y) {
        int c0 = (z * GDIM + y) * GDIM + x0;
        int c1 = (z * GDIM + y) * GDIM + x1;
        int beg = cell_start[c0];
        int end = cell_start[c1] + cell_count[c1];
        int off = (sl - tot) & 31;
        for (int j = beg + off; j < end; j += 32) {
          float4 sp = sorted4[j];
          float dx = sp.x - p.x, dy = sp.y - p.y, dz = sp.z - p.z;
          float d2 = dx * dx + dy * dy + dz * dz;
          KNN_INSERTC(d2, j);
        }
        tot += end - beg;
      }
    }
  }
  int done;
  {
    float b2 = CW * CW;
    int cnt = 0;
#pragma unroll
    for (int i = 0; i < KC; ++i) cnt += (dist[i] <= b2) ? 1 : 0;
#pragma unroll
    for (int s = 1; s < 32; s <<= 1) cnt += __shfl_xor(cnt, s, 64);
    done = (cnt >= KG) ? 1 : 0;
  }

  // ---- phase 2: rings r=2..RMAX, lane-per-segment over 32 lanes
  for (int r = 2; r <= RMAX && !done; ++r) {
    int side = 2 * r + 1;
    int nt = side * side;
    float rcp = 1.0f / (float)side;
    for (int t = sl; t < nt; t += 32) {
      int qz = (int)(((float)t + 0.5f) * rcp);  // exact floor(t/side) for t<169
      int dz = qz - r;
      int dy = t - qz * side - r;
      int z = cz + dz, y = cy + dy;
      if (z < 0 || z >= GDIM || y < 0 || y >= GDIM) continue;
      int rowbase = (z * GDIM + y) * GDIM;
      if (dz == -r || dz == r || dy == -r || dy == r) {
        int xa = max(cx - r, 0), xb = min(cx + r, GDIM - 1);
        int beg = cell_start[rowbase + xa];
        int end = cell_start[rowbase + xb] + cell_count[rowbase + xb];
        for (int j = beg; j < end; ++j) {
          float4 sp = sorted4[j];
          float ddx = sp.x - p.x, ddy = sp.y - p.y, ddz = sp.z - p.z;
          float d2 = ddx * ddx + ddy * ddy + ddz * ddz;
          KNN_INSERTC(d2, j);
        }
      } else {
        int x = cx - r;
        if (x >= 0) {
          int c = rowbase + x;
          int beg = cell_start[c], end = beg + cell_count[c];
          for (int j = beg; j < end; ++j) {
            float4 sp = sorted4[j];
            float ddx = sp.x - p.x, ddy = sp.y - p.y, ddz = sp.z - p.z;
            float d2 = ddx * ddx + ddy * ddy + ddz * ddz;
            KNN_INSERTC(d2, j);
          }
        }
        x = cx + r;
        if (x < GDIM) {
          int c = rowbase + x;
          int beg = cell_start[c], end = beg + cell_count[c];
          for (int j = beg; j < end; ++j) {
            float4 sp = sorted4[j];
            float ddx = sp.x - p.x, ddy = sp.y - p.y, ddz = sp.z - p.z;
            float d2 = ddx * ddx + ddy * ddy + ddz * ddz;
            KNN_INSERTC(d2, j);
          }
        }
      }
    }
    float b = CW * (float)r;
    float b2 = b * b;
    int cnt = 0;
#pragma unroll
    for (int i = 0; i < KC; ++i) cnt += (dist[i] <= b2) ? 1 : 0;
#pragma unroll
    for (int s = 1; s < 32; s <<= 1) cnt += __shfl_xor(cnt, s, 64);
    if (cnt >= KG) done = 1;
  }

  // 32-way merge: 20 rounds of subgroup argmin over packed (d2,slot) keys.
  // Exactness guard: lane pops all KC entries OR rings exhausted -> exact fallback.
  int popc = 0, ovf = 0;
  for (int round = 0; round < KG; ++round) {
    unsigned long long key = ((unsigned long long)__float_as_uint(dist[0]) << 14) |
                             (unsigned long long)(unsigned)idx[0];
    unsigned long long m = key;
#pragma unroll
    for (int s = 1; s < 32; s <<= 1) {
      unsigned long long o = __shfl_xor(m, s, 64);
      if (o < m) m = o;
    }
    if (key == m) {
      nbr[(size_t)qs * KG + round] = (int)(m & 0x3FFF);
#pragma unroll
      for (int s = 0; s < KC - 1; ++s) { dist[s] = dist[s + 1]; idx[s] = idx[s + 1]; }
      dist[KC - 1] = 3.4e38f;
      idx[KC - 1] = 0;
      if (++popc == KC) ovf = 1;
    }
  }
#pragma unroll
  for (int s = 1; s < 32; s <<= 1) ovf |= __shfl_xor(ovf, s, 64);
  if ((ovf || !done) && sl == 0) {
    int s = atomicAdd(fb_count, 1);
    fb_list[s] = qs;
  }
}

// ---------------------------------------------------------------- brute-force fallback (slots)
__global__ __launch_bounds__(256) void knn_fb_kernel(const float4* __restrict__ sorted4,
                                                     const int* __restrict__ fb_list,
                                                     const int* __restrict__ fb_count,
                                                     int* __restrict__ nbr) {
  __shared__ unsigned long long lists[256 * KG];
  __shared__ unsigned long long heads[256];
  __shared__ unsigned long long winner;
  int tid = threadIdx.x;
  int cnt = *fb_count;
  for (int qi = blockIdx.x; qi < cnt; qi += gridDim.x) {
    int t = fb_list[qi];
    float4 p = sorted4[t];
    float dist[KG];
    int idx[KG];
#pragma unroll
    for (int i = 0; i < KG; ++i) { dist[i] = 3.4e38f; idx[i] = 0; }
    int j0 = tid * 64;
    for (int j = j0; j < j0 + 64; ++j) {
      float4 c = sorted4[j];
      float dx = c.x - p.x, dy = c.y - p.y, dz = c.z - p.z;
      float d2 = dx * dx + dy * dy + dz * dz;
      KNN_INSERT(d2, j);
    }
#pragma unroll
    for (int i = 0; i < KG; ++i)
      lists[tid * KG + i] = ((unsigned long long)__float_as_uint(dist[i]) << 22) |
                            ((unsigned long long)(unsigned)idx[i] << 8) |
                            (unsigned long long)tid;
    int hp = 0;
    __syncthreads();
    for (int round = 0; round < KG; ++round) {
      heads[tid] = (hp < KG) ? lists[tid * KG + hp] : ~0ull;
      __syncthreads();
      if (tid < 64) {
        unsigned long long m = heads[tid];
        unsigned long long o = heads[tid + 64];  if (o < m) m = o;
        o = heads[tid + 128]; if (o < m) m = o;
        o = heads[tid + 192]; if (o < m) m = o;
#pragma unroll
        for (int s = 32; s > 0; s >>= 1) {
          unsigned long long x = __shfl_xor(m, s, 64);
          if (x < m) m = x;
        }
        if (tid == 0) winner = m;
      }
      __syncthreads();
      unsigned long long w = winner;
      if (tid == (int)(w & 0xFF)) hp++;
      if (tid == 0) nbr[(size_t)t * KG + round] = (int)((w >> 8) & 0x3FFF);
      __syncthreads();
    }
  }
}

// ---------------------------------------------------- basis (sorted space, f32)
__global__ __launch_bounds__(256) void basis_kernel(const float4* __restrict__ sorted4,
                                                    const int* __restrict__ nbr,
                                                    float4* __restrict__ xb4,
                                                    float4* __restrict__ yb4) {
  int n = blockIdx.x * 256 + threadIdx.x;
  if (n >= NPTS) return;
  float4 p = sorted4[n];
  float c00 = 0, c01 = 0, c02 = 0, c11 = 0, c12 = 0, c22 = 0;
  for (int k = 0; k < KN; ++k) {
    int m = nbr[(size_t)n * KG + k];
    float4 pm = sorted4[m];
    float dx = pm.x - p.x, dy = pm.y - p.y, dz = pm.z - p.z;
    c00 += dx * dx; c01 += dx * dy; c02 += dx * dz;
    c11 += dy * dy; c12 += dy * dz; c22 += dz * dz;
  }
  float nx = 0.f, ny = 0.f, nz = 1.f;
  float p1 = c01 * c01 + c02 * c02 + c12 * c12;
  float qm = (c00 + c11 + c22) * (1.f / 3.f);
  float g0 = c00 - qm, g1 = c11 - qm, g2 = c22 - qm;
  float p2 = g0 * g0 + g1 * g1 + g2 * g2 + 2.f * p1;
  if (p2 > 1e-16f) {
    float pp = sqrtf(p2 * (1.f / 6.f));
    float inv = 1.f / pp;
    float b00 = g0 * inv, b11 = g1 * inv, b22 = g2 * inv;
    float b01 = c01 * inv, b02 = c02 * inv, b12 = c12 * inv;
    float detB = b00 * (b11 * b22 - b12 * b12) - b01 * (b01 * b22 - b12 * b02) +
                 b02 * (b01 * b12 - b11 * b02);
    float r = 0.5f * detB;
    r = fminf(1.f, fmaxf(-1.f, r));
    float phi = acosf(r) * (1.f / 3.f);
    float e1 = qm + 2.f * pp * __cosf(phi);
    float e3 = qm + 2.f * pp * __cosf(phi + 2.0943951023931953f);
    float e2 = 3.f * qm - e1 - e3;
    float a00 = c00 - e1, a11 = c11 - e1, a22 = c22 - e1;
    float f00 = c00 - e2, f11 = c11 - e2, f22 = c22 - e2;
    float u0 = a00 * f00 + c01 * c01 + c02 * c02;
    float u1 = c01 * f00 + a11 * c01 + c12 * c02;
    float u2 = c02 * f00 + c12 * c01 + a22 * c02;
    float v0 = a00 * c01 + c01 * f11 + c02 * c12;
    float v1 = c01 * c01 + a11 * f11 + c12 * c12;
    float v2 = c02 * c01 + c12 * f11 + a22 * c12;
    float w0 = a00 * c02 + c01 * c12 + c02 * f22;
    float w1 = c01 * c02 + a11 * c12 + c12 * f22;
    float w2 = c02 * c02 + c12 * c12 + a22 * f22;
    float nu = u0 * u0 + u1 * u1 + u2 * u2;
    float nv = v0 * v0 + v1 * v1 + v2 * v2;
    float nw = w0 * w0 + w1 * w1 + w2 * w2;
    float bx = u0, by = u1, bz = u2, bn = nu;
    if (nv > bn) { bx = v0; by = v1; bz = v2; bn = nv; }
    if (nw > bn) { bx = w0; by = w1; bz = w2; bn = nw; }
    if (bn > 1e-30f) {
      float s = 1.f / sqrtf(bn);
      nx = bx * s; ny = by * s; nz = bz * s;
    }
  }
  float dotp = nx * p.x + ny * p.y + nz * p.z;
  if (dotp < 0.f) { nx = -nx; ny = -ny; nz = -nz; }
  float ax = fabsf(nx), ay = fabsf(ny), az = fabsf(nz);
  float ex = 0.f, ey = 0.f, ez = 0.f;
  if (ax <= ay && ax <= az) ex = 1.f;
  else if (ay <= az) ey = 1.f;
  else ez = 1.f;
  float tx = ny * ez - nz * ey, ty = nz * ex - nx * ez, tz = nx * ey - ny * ex;
  float tn = 1.f / sqrtf(tx * tx + ty * ty + tz * tz);
  tx *= tn; ty *= tn; tz *= tn;
  float ux = ny * tz - nz * ty, uy = nz * tx - nx * tz, uz = nx * ty - ny * tx;
  xb4[n] = make_float4(tx, ty, tz, 0.f);
  yb4[n] = make_float4(ux, uy, uz, 0.f);
}

// --------------------------- Gx/Gy + C2 + v0 = grad(pos) (sorted space, f32)
__global__ __launch_bounds__(256) void graddiv_kernel(const float4* __restrict__ sorted4,
                                                      const int* __restrict__ nbr,
                                                      const float4* __restrict__ xb4,
                                                      const float4* __restrict__ yb4,
                                                      float* __restrict__ Gx,
                                                      float* __restrict__ Gy,
                                                      float2* __restrict__ C2,
                                                      float* __restrict__ v0) {
  int n = blockIdx.x * 256 + threadIdx.x;
  if (n >= NPTS) return;
  float4 p = sorted4[n], xb = xb4[n], yb = yb4[n];
  float u[KG], vv[KG], w[KG];
  int mm[KG];
  float hsum = 0.f;
#pragma unroll
  for (int k = 0; k < KG; ++k) {
    int m = nbr[(size_t)n * KG + k];
    mm[k] = m;
    float4 pm = sorted4[m];
    float rx = pm.x - p.x, ry = pm.y - p.y, rz = pm.z - p.z;
    u[k] = rx * xb.x + ry * xb.y + rz * xb.z;
    vv[k] = rx * yb.x + ry * yb.y + rz * yb.z;
    float dd = sqrtf(rx * rx + ry * ry + rz * rz + EPSF);
    w[k] = dd; hsum += dd;
  }
  float h = hsum * (1.f / KG);
  float invden = 1.f / (h * h + EPSF);
  float A00 = 0, A01 = 0, A02 = 0, A11 = 0, A12 = 0, A22 = 0;
#pragma unroll
  for (int k = 0; k < KG; ++k) {
    float wk = __expf(-(w[k] * w[k]) * invden);
    w[k] = wk;
    A00 += wk; A01 += wk * u[k]; A02 += wk * vv[k];
    A11 += wk * u[k] * u[k]; A12 += wk * u[k] * vv[k];
    A22 += wk * vv[k] * vv[k];
  }
  A00 += 0.001f; A11 += 0.001f; A22 += 0.001f;
  float det = A00 * (A11 * A22 - A12 * A12) - A01 * (A01 * A22 - A12 * A02) +
              A02 * (A01 * A12 - A11 * A02);
  float idet = 1.f / det;
  float i10 = (A02 * A12 - A01 * A22) * idet;
  float i11 = (A00 * A22 - A02 * A02) * idet;
  float i12 = (A01 * A02 - A00 * A12) * idet;
  float i20 = (A01 * A12 - A02 * A11) * idet;
  float i21 = i12;
  float i22 = (A00 * A11 - A01 * A01) * idet;
  float a0x = 0, a0y = 0, a0z = 0, a1x = 0, a1y = 0, a1z = 0;
#pragma unroll
  for (int k = 0; k < KG; ++k) {
    float gx = w[k] * (i10 + i11 * u[k] + i12 * vv[k]);
    float gy = w[k] * (i20 + i21 * u[k] + i22 * vv[k]);
    Gx[(size_t)n * KG + k] = gx;
    Gy[(size_t)n * KG + k] = gy;
    int m = mm[k];
    float4 pm = sorted4[m];
    a0x += gx * pm.x; a0y += gx * pm.y; a0z += gx * pm.z;
    a1x += gy * pm.x; a1y += gy * pm.y; a1z += gy * pm.z;
    float4 xm = xb4[m], ym = yb4[m];
    float g3x = gx * xb.x + gy * yb.x;
    float g3y = gx * xb.y + gy * yb.y;
    float g3z = gx * xb.z + gy * yb.z;
    float ca = g3x * xm.x + g3y * xm.y + g3z * xm.z;
    float cb = g3x * ym.x + g3y * ym.y + g3z * ym.z;
    C2[(size_t)n * KG + k] = make_float2(ca, cb);
  }
  v0[((size_t)n * 2 + 0) * 3 + 0] = a0x;
  v0[((size_t)n * 2 + 0) * 3 + 1] = a0y;
  v0[((size_t)n * 2 + 0) * 3 + 2] = a0z;
  v0[((size_t)n * 2 + 1) * 3 + 0] = a1x;
  v0[((size_t)n * 2 + 1) * 3 + 1] = a1y;
  v0[((size_t)n * 2 + 1) * 3 + 2] = a1z;
}

// ------------------------------------------------- feat scalar (layer 0, cin=3, f32 in)
template <int CENTRAL>
__global__ __launch_bounds__(256) void feat16_kernel(const float* __restrict__ x, int ldx,
                                                     int cin,
                                                     const float* __restrict__ v,
                                                     const int* __restrict__ nbr,
                                                     const float2* __restrict__ C2,
                                                     unsigned short* __restrict__ feat, int Kp) {
  int per = Kp - 2 * cin;
  int gid = blockIdx.x * 256 + threadIdx.x;
  if (gid >= NPTS * per) return;
  int n = gid / per;
  int c = gid - n * per;
  size_t fb = (size_t)n * Kp;
  if (c >= cin) {  // pad column
    feat[fb + 3 * cin + (c - cin)] = 0;
    return;
  }
  float xc = x[(size_t)n * ldx + c];
  float xmax = -3.4e38f, dv = 0.f, cv = 0.f;
  for (int k = 0; k < KG; ++k) {
    int m = nbr[(size_t)n * KG + k];
    float2 cc = C2[(size_t)n * KG + k];
    float xm = x[(size_t)m * ldx + c];
    xmax = fmaxf(xmax, CENTRAL ? (xm - xc) : xm);
    float va = v[((size_t)m * 2 + 0) * cin + c];
    float vb = v[((size_t)m * 2 + 1) * cin + c];
    dv += cc.x * va + cc.y * vb;
    cv += cc.y * va - cc.x * vb;
  }
  feat[fb + c] = f2bf(xmax);
  feat[fb + cin + c] = f2bf(dv);
  feat[fb + 2 * cin + c] = f2bf(cv);
}

// ----------------------- feat vectorized: bf16 x/v mirrors, 8 channels/thread
__global__ __launch_bounds__(256) void feat16v8_kernel(const unsigned short* __restrict__ x,
                                                       int cin,
                                                       const unsigned short* __restrict__ v,
                                                       const int* __restrict__ nbr,
                                                       const float2* __restrict__ C2,
                                                       unsigned short* __restrict__ feat) {
  int per = cin >> 3;
  int gid = blockIdx.x * 256 + threadIdx.x;
  if (gid >= NPTS * per) return;
  int n = gid / per;
  int c8 = (gid - n * per) << 3;
  float xmax[8], dv[8], cv[8];
#pragma unroll
  for (int i = 0; i < 8; ++i) { xmax[i] = -3.4e38f; dv[i] = 0.f; cv[i] = 0.f; }
  const int* nrow = nbr + (size_t)n * KG;
  const float2* crow = C2 + (size_t)n * KG;
#pragma unroll 4
  for (int k = 0; k < KG; ++k) {
    int m = nrow[k];
    float2 cc = crow[k];
    short8v xm = *reinterpret_cast<const short8v*>(x + (size_t)m * cin + c8);
    short8v va = *reinterpret_cast<const short8v*>(v + ((size_t)m * 2 + 0) * cin + c8);
    short8v vb = *reinterpret_cast<const short8v*>(v + ((size_t)m * 2 + 1) * cin + c8);
#pragma unroll
    for (int i = 0; i < 8; ++i) {
      float xf = bf2f((unsigned short)xm[i]);
      float af = bf2f((unsigned short)va[i]);
      float bf = bf2f((unsigned short)vb[i]);
      xmax[i] = fmaxf(xmax[i], xf);
      dv[i] += cc.x * af + cc.y * bf;
      cv[i] += cc.y * af - cc.x * bf;
    }
  }
  size_t fb = (size_t)n * (3 * cin);
  short8v o0, o1, o2;
#pragma unroll
  for (int i = 0; i < 8; ++i) {
    o0[i] = (short)f2bf(xmax[i]);
    o1[i] = (short)f2bf(dv[i]);
    o2[i] = (short)f2bf(cv[i]);
  }
  *reinterpret_cast<short8v*>(&feat[fb + c8]) = o0;
  *reinterpret_cast<short8v*>(&feat[fb + cin + c8]) = o1;
  *reinterpret_cast<short8v*>(&feat[fb + 2 * cin + c8]) = o2;
}

// ------------------------------------------------- vin scalar (layer 0, Kp=96, cin=3)
__global__ __launch_bounds__(256) void vin16_kernel(const float* __restrict__ v, int cin,
                                                    const unsigned short* __restrict__ xout,
                                                    int cout,
                                                    const int* __restrict__ nbr,
                                                    const float* __restrict__ Gx,
                                                    const float* __restrict__ Gy,
                                                    unsigned short* __restrict__ vinb, int Kp,
                                                    int total) {
  int gid = blockIdx.x * 256 + threadIdx.x;
  if (gid >= total) return;
  int n = gid / Kp;
  int c = gid - n * Kp;
  int K = cin + cout;
  unsigned short o0, o1;
  if (c < cin) {
    o0 = f2bf(v[((size_t)n * 2 + 0) * cin + c]);
    o1 = f2bf(v[((size_t)n * 2 + 1) * cin + c]);
  } else if (c < K) {
    int cc = c - cin;
    float a0 = 0.f, a1 = 0.f;
    for (int k = 0; k < KG; ++k) {
      int m = nbr[(size_t)n * KG + k];
      float f = bf2f(xout[(size_t)m * cout + cc]);
      a0 += Gx[(size_t)n * KG + k] * f;
      a1 += Gy[(size_t)n * KG + k] * f;
    }
    o0 = f2bf(a0);
    o1 = f2bf(a1);
  } else {
    o0 = 0; o1 = 0;
  }
  vinb[((size_t)n * 2 + 0) * Kp + c] = o0;
  vinb[((size_t)n * 2 + 1) * Kp + c] = o1;
}

// ----------------------- vin vectorized: bf16 v + bf16 xout mirror, 8 ch/thread
__global__ __launch_bounds__(256) void vin16v8_kernel(const unsigned short* __restrict__ v,
                                                      int cin,
                                                      const unsigned short* __restrict__ xout,
                                                      int cout,
                                                      const int* __restrict__ nbr,
                                                      const float* __restrict__ Gx,
                                                      const float* __restrict__ Gy,
                                                      unsigned short* __restrict__ vinb,
                                                      int Kp) {
  int per = Kp >> 3;
  int gid = blockIdx.x * 256 + threadIdx.x;
  if (gid >= NPTS * per) return;
  int n = gid / per;
  int c8 = (gid - n * per) << 3;
  short8v o0, o1;
  if (c8 < cin) {
    o0 = *reinterpret_cast<const short8v*>(v + ((size_t)n * 2 + 0) * cin + c8);
    o1 = *reinterpret_cast<const short8v*>(v + ((size_t)n * 2 + 1) * cin + c8);
  } else {
    int cc8 = c8 - cin;
    float a0[8], a1[8];
#pragma unroll
    for (int i = 0; i < 8; ++i) { a0[i] = 0.f; a1[i] = 0.f; }
    const int* nrow = nbr + (size_t)n * KG;
    const float* gxr = Gx + (size_t)n * KG;
    const float* gyr = Gy + (size_t)n * KG;
#pragma unroll 4
    for (int k = 0; k < KG; ++k) {
      int m = nrow[k];
      float gx = gxr[k], gy = gyr[k];
      short8v f = *reinterpret_cast<const short8v*>(xout + (size_t)m * cout + cc8);
#pragma unroll
      for (int i = 0; i < 8; ++i) {
        float ff = bf2f((unsigned short)f[i]);
        a0[i] += gx * ff;
        a1[i] += gy * ff;
      }
    }
#pragma unroll
    for (int i = 0; i < 8; ++i) {
      o0[i] = (short)f2bf(a0[i]);
      o1[i] = (short)f2bf(a1[i]);
    }
  }
  *reinterpret_cast<short8v*>(&vinb[((size_t)n * 2 + 0) * Kp + c8]) = o0;
  *reinterpret_cast<short8v*>(&vinb[((size_t)n * 2 + 1) * Kp + c8]) = o1;
}

// --------------------- weight prep, all 5 weights fused into one launch
__device__ __forceinline__ void wprep_one(const float* W, unsigned short* Wt, int K, int Kp,
                                          int N, int i) {
  int n = i / Kp, k = i - n * Kp;
  Wt[i] = (k < K) ? f2bf(W[(size_t)k * N + n]) : (unsigned short)0;
}

__global__ __launch_bounds__(256) void wprep_all_kernel(const float* __restrict__ Ws0,
                                                        const float* __restrict__ Wv0,
                                                        const float* __restrict__ Ws1,
                                                        const float* __restrict__ Wv1,
                                                        const float* __restrict__ Ws2,
                                                        unsigned short* __restrict__ Wt_s0,
                                                        unsigned short* __restrict__ Wt_v0,
                                                        unsigned short* __restrict__ Wt_s1,
                                                        unsigned short* __restrict__ Wt_v1,
                                                        unsigned short* __restrict__ Wt_s2) {
  int gid = blockIdx.x * 256 + threadIdx.x;
  if (gid < 2048) wprep_one(Ws0, Wt_s0, 9, 32, 64, gid);
  else if (gid < 8192) wprep_one(Wv0, Wt_v0, 67, 96, 64, gid - 2048);
  else if (gid < 32768) wprep_one(Ws1, Wt_s1, 192, 192, 128, gid - 8192);
  else if (gid < 57344) wprep_one(Wv1, Wt_v1, 192, 192, 128, gid - 32768);
  else if (gid < 155648) wprep_one(Ws2, Wt_s2, 384, 384, 256, gid - 57344);
}

// ------------------------------------------------- bf16 MFMA GEMM
// MODE 0: Cf[rowmap[row]] = relu(A@B+bias) f32 (+ optional bf16 mirror Cb[row], sorted).
// MODE 1: normgate over row pairs, bf16 output to Cb only (sorted rows).
template <int MODE>
__global__ __launch_bounds__(256) void gemm16_kernel(const unsigned short* __restrict__ A,
                                                     const unsigned short* __restrict__ Bt,
                                                     const float* __restrict__ bias,
                                                     float* __restrict__ Cf,
                                                     unsigned short* __restrict__ Cb,
                                                     const int* __restrict__ rowmap,
                                                     int Kp, int Ncol) {
  int lane = threadIdx.x & 63;
  int wave = threadIdx.x >> 6;
  int rowBase = blockIdx.y * 64 + wave * 16;
  int colBase = blockIdx.x * 64;
  int lr = lane & 15;
  int kg = (lane >> 4) * 8;
  floatx4 acc0 = {0.f, 0.f, 0.f, 0.f};
  floatx4 acc1 = acc0, acc2 = acc0, acc3 = acc0;
  const unsigned short* arow = A + (size_t)(rowBase + lr) * Kp + kg;
  const unsigned short* b0p = Bt + (size_t)(colBase + lr) * Kp + kg;
  for (int k0 = 0; k0 < Kp; k0 += 32) {
    short8v a = *reinterpret_cast<const short8v*>(arow + k0);
    short8v b0 = *reinterpret_cast<const short8v*>(b0p + k0);
    short8v b1 = *reinterpret_cast<const short8v*>(b0p + (size_t)16 * Kp + k0);
    short8v b2 = *reinterpret_cast<const short8v*>(b0p + (size_t)32 * Kp + k0);
    short8v b3 = *reinterpret_cast<const short8v*>(b0p + (size_t)48 * Kp + k0);
    acc0 = __builtin_amdgcn_mfma_f32_16x16x32_bf16(a, b0, acc0, 0, 0, 0);
    acc1 = __builtin_amdgcn_mfma_f32_16x16x32_bf16(a, b1, acc1, 0, 0, 0);
    acc2 = __builtin_amdgcn_mfma_f32_16x16x32_bf16(a, b2, acc2, 0, 0, 0);
    acc3 = __builtin_amdgcn_mfma_f32_16x16x32_bf16(a, b3, acc3, 0, 0, 0);
  }
  int rsub = (lane >> 4) * 4;
  floatx4 accs[4] = {acc0, acc1, acc2, acc3};
  int orow[4];
  if (MODE == 0) {
#pragma unroll
    for (int r = 0; r < 4; ++r) orow[r] = rowmap[rowBase + rsub + r];
  }
#pragma unroll
  for (int nb = 0; nb < 4; ++nb) {
    int col = colBase + nb * 16 + lr;
    float bb = bias[col];
    if (MODE == 0) {
#pragma unroll
      for (int r = 0; r < 4; ++r) {
        int row = rowBase + rsub + r;
        float val = fmaxf(accs[nb][r] + bb, 0.f);
        Cf[(size_t)orow[r] * Ncol + col] = val;
        if (Cb) Cb[(size_t)row * Ncol + col] = f2bf(val);
      }
    } else {
#pragma unroll
      for (int pr = 0; pr < 2; ++pr) {
        float a0 = accs[nb][2 * pr], a1 = accs[nb][2 * pr + 1];
        float nrm = sqrtf(a0 * a0 + a1 * a1 + EPSF);
        float s = fmaxf(nrm + bb, 0.f) / (nrm + EPSF);
        int row = rowBase + rsub + 2 * pr;
        Cb[(size_t)row * Ncol + col] = f2bf(a0 * s);
        Cb[(size_t)(row + 1) * Ncol + col] = f2bf(a1 * s);
      }
    }
  }
}

// ---------------------------------------------------------------- launch
extern "C" void kernel_launch(void* const* d_in, const int* in_sizes, int n_in,
                              void* d_out, int out_size, void* d_ws, size_t ws_size,
                              hipStream_t stream) {
  const float* pts = (const float*)d_in[0];
  const float* als = (const float*)d_in[1];
  const float* Ws0 = (const float*)d_in[2];
  const float* bs0 = (const float*)d_in[3];
  const float* Wv0 = (const float*)d_in[4];
  const float* bv0 = (const float*)d_in[5];
  const float* Ws1 = (const float*)d_in[6];
  const float* bs1 = (const float*)d_in[7];
  const float* Wv1 = (const float*)d_in[8];
  const float* bv1 = (const float*)d_in[9];
  const float* Ws2 = (const float*)d_in[10];
  const float* bs2 = (const float*)d_in[11];

  char* ws = (char*)d_ws;
  float4* pos4 = (float4*)(ws + 0);               //  256 KB (original order, staging)
  int* nbr = (int*)(ws + 262144);                 // 1.31 MB (sorted-slot space)
  float4* xb4 = (float4*)(ws + 1572864);          //  256 KB (sorted)
  float4* yb4 = (float4*)(ws + 1835008);          //  256 KB (sorted)
  float* Gx = (float*)(ws + 2097152);             // 1.31 MB (sorted)
  float* Gy = (float*)(ws + 3407872);             // 1.31 MB (sorted)
  float2* C2 = (float2*)(ws + 4718592);           // 2.62 MB (sorted)
  float* v0f = (float*)(ws + 7340032);            //  393 KB (sorted)
  unsigned short* vb_a = (unsigned short*)(ws + 8388608);    // 8.39 MB (sorted)
  unsigned short* vb_b = (unsigned short*)(ws + 17825792);   // 4.19 MB (sorted)
  unsigned short* xb0m = (unsigned short*)(ws + 23068672);   // 2.10 MB (sorted)
  unsigned short* xb1m = (unsigned short*)(ws + 26214400);   // 4.19 MB (sorted)
  unsigned short* stg = (unsigned short*)(ws + 31457280);    // 12.6 MB (sorted)
  char* wtb = ws + 45088768;                      // transposed bf16 weights (~311 KB)
  unsigned short* Wt_s0 = (unsigned short*)(wtb + 0);
  unsigned short* Wt_v0 = (unsigned short*)(wtb + 4096);
  unsigned short* Wt_s1 = (unsigned short*)(wtb + 16384);
  unsigned short* Wt_v1 = (unsigned short*)(wtb + 65536);
  unsigned short* Wt_s2 = (unsigned short*)(wtb + 114688);

  char* gws = ws + 46137344;                      // knn scratch
  int* cell_count = (int*)(gws + 0);              // 128 KB
  int* fb_count = (int*)(gws + 131072);           // 4 B (memset together with cell_count)
  int* cell_start = (int*)(gws + 135168);         // 128 KB
  int* cell_cursor = (int*)(gws + 266240);        // 128 KB
  int* pt_cell = (int*)(gws + 397312);            // 64 KB
  int* fb_list = (int*)(gws + 462848);            // 64 KB
  int* bcur = (int*)(gws + 528384);               // 256 B (occupancy bucket cursors)
  float4* sorted4 = (float4*)(gws + 532480);      // 256 KB
  int* sortmap = (int*)(gws + 794624);            // 64 KB (slot -> original row)
  int* qorder = (int*)(gws + 860160);             // 64 KB (sparse-first slot order)

  float* out0 = (float*)d_out;             // (N,64) original order
  float* out1 = out0 + (size_t)NPTS * 64;  // (N,128)
  float* out2 = out1 + (size_t)NPTS * 128; // (N,256)

  hipMemsetAsync(cell_count, 0, 131072 + 4, stream);  // cell_count + fb_count
  posbin_kernel<<<64, 256, 0, stream>>>(pts, als, pos4, cell_count, pt_cell);
  scan_kernel<<<1, 1024, 0, stream>>>(cell_count, cell_start, cell_cursor);
  scatter_kernel<<<64, 256, 0, stream>>>(pos4, pt_cell, cell_cursor, sorted4, sortmap);
  qhist_kernel<<<1, 256, 0, stream>>>(sorted4, cell_count, bcur);
  qorder_kernel<<<64, 256, 0, stream>>>(sorted4, cell_count, bcur, qorder);
  knn_grid_kernel<<<NPTS / 8, 256, 0, stream>>>(sorted4, cell_start, cell_count, qorder, nbr,
                                                fb_list, fb_count);
  knn_fb_kernel<<<128, 256, 0, stream>>>(sorted4, fb_list, fb_count, nbr);

  basis_kernel<<<64, 256, 0, stream>>>(sorted4, nbr, xb4, yb4);
  graddiv_kernel<<<64, 256, 0, stream>>>(sorted4, nbr, xb4, yb4, Gx, Gy, C2, v0f);

  wprep_all_kernel<<<608, 256, 0, stream>>>(Ws0, Wv0, Ws1, Wv1, Ws2, Wt_s0, Wt_v0, Wt_s1,
                                            Wt_v1, Wt_s2);

  // ---- layer 0 (cin=3 -> cout=64, centralized), all in sorted space
  feat16_kernel<1><<<(NPTS * 26 + 255) / 256, 256, 0, stream>>>((const float*)sorted4, 4, 3,
                                                                v0f, nbr, C2, stg, 32);
  gemm16_kernel<0><<<dim3(1, 256), 256, 0, stream>>>(stg, Wt_s0, bs0, out0, xb0m, sortmap, 32,
                                                     64);
  vin16_kernel<<<(NPTS * 96 + 255) / 256, 256, 0, stream>>>(v0f, 3, xb0m, 64, nbr, Gx, Gy, stg,
                                                            96, NPTS * 96);
  gemm16_kernel<1><<<dim3(1, 512), 256, 0, stream>>>(stg, Wt_v0, bv0, nullptr, vb_b, nullptr,
                                                     96, 64);

  // ---- layer 1 (cin=64 -> cout=128)
  feat16v8_kernel<<<NPTS * 8 / 256, 256, 0, stream>>>(xb0m, 64, vb_b, nbr, C2, stg);
  gemm16_kernel<0><<<dim3(2, 256), 256, 0, stream>>>(stg, Wt_s1, bs1, out1, xb1m, sortmap, 192,
                                                     128);
  vin16v8_kernel<<<NPTS * 24 / 256, 256, 0, stream>>>(vb_b, 64, xb1m, 128, nbr, Gx, Gy, stg,
                                                      192);
  gemm16_kernel<1><<<dim3(2, 512), 256, 0, stream>>>(stg, Wt_v1, bv1, nullptr, vb_a, nullptr,
                                                     192, 128);

  // ---- layer 2 (cin=128 -> cout=256, no vector update)
  feat16v8_kernel<<<NPTS * 16 / 256, 256, 0, stream>>>(xb1m, 128, vb_a, nbr, C2, stg);
  gemm16_kernel<0><<<dim3(4, 256), 256, 0, stream>>>(stg, Wt_s2, bs2, out2, nullptr, sortmap,
                                                     384, 256);
}

// Round 15
// 291.955 us; speedup vs baseline: 1.4346x; 1.4346x over previous
//
#include <hip/hip_runtime.h>
#include <math.h>

#define NPTS 16384
#define KG 20
#define KN 10
#define KC 6
#define EPSF 1e-8f

#define GDIM 32
#define GL 4.75f
#define CW 0.296875f
#define GINV 3.3684210526f
#define RMAX 6

typedef __attribute__((ext_vector_type(8))) short short8v;
typedef __attribute__((ext_vector_type(4))) float floatx4;

__device__ __forceinline__ unsigned short f2bf(float v) {
  union { float f; unsigned u; } x;
  x.f = v;
  unsigned r = x.u + 0x7FFFu + ((x.u >> 16) & 1u);  // RNE (finite inputs)
  return (unsigned short)(r >> 16);
}

__device__ __forceinline__ float bf2f(unsigned short u) {
  union { unsigned u32; float f; } x;
  x.u32 = (unsigned)u << 16;
  return x.f;
}

// sorted insert into KG-register list (strict <, stable by scan order)
#define KNN_INSERT(d2v, iv)                                                 \
  if ((d2v) < dist[KG - 1]) {                                               \
    dist[KG - 1] = (d2v); idx[KG - 1] = (iv);                               \
    _Pragma("unroll")                                                       \
    for (int s_ = KG - 1; s_ > 0; --s_) {                                   \
      if (dist[s_] < dist[s_ - 1]) {                                        \
        float td_ = dist[s_]; dist[s_] = dist[s_ - 1]; dist[s_ - 1] = td_;  \
        int ti_ = idx[s_]; idx[s_] = idx[s_ - 1]; idx[s_ - 1] = ti_;        \
      }                                                                     \
    }                                                                       \
  }

// sorted insert into KC-register list
#define KNN_INSERTC(d2v, iv)                                                \
  if ((d2v) < dist[KC - 1]) {                                               \
    dist[KC - 1] = (d2v); idx[KC - 1] = (iv);                               \
    _Pragma("unroll")                                                       \
    for (int s_ = KC - 1; s_ > 0; --s_) {                                   \
      if (dist[s_] < dist[s_ - 1]) {                                        \
        float td_ = dist[s_]; dist[s_] = dist[s_ - 1]; dist[s_ - 1] = td_;  \
        int ti_ = idx[s_]; idx[s_] = idx[s_ - 1]; idx[s_ - 1] = ti_;        \
      }                                                                     \
    }                                                                       \
  }

__device__ __forceinline__ int cell_of(float x) {
  int c = (int)floorf((x + GL) * GINV);
  return min(max(c, 0), GDIM - 1);
}

// ---------------------------------------------------------------- pos concat + bin (fused)
__global__ __launch_bounds__(256) void posbin_kernel(const float* __restrict__ pts,
                                                     const float* __restrict__ als,
                                                     float4* __restrict__ pos4,
                                                     int* __restrict__ cell_count,
                                                     int* __restrict__ pt_cell) {
  int n = blockIdx.x * 256 + threadIdx.x;
  if (n >= NPTS) return;
  const float* src = (n < 8192) ? (pts + (size_t)n * 3) : (als + (size_t)(n - 8192) * 3);
  float x = src[0], y = src[1], z = src[2];
  pos4[n] = make_float4(x, y, z, 0.f);
  int c = (cell_of(z) * GDIM + cell_of(y)) * GDIM + cell_of(x);
  pt_cell[n] = c;
  atomicAdd(&cell_count[c], 1);
}

__global__ __launch_bounds__(1024) void scan_kernel(const int* __restrict__ cell_count,
                                                    int* __restrict__ cell_start,
                                                    int* __restrict__ cell_cursor) {
  __shared__ int s[1024];
  int tid = threadIdx.x;
  int base = tid * 32;
  int local[32];
  int sum = 0;
#pragma unroll
  for (int i = 0; i < 32; ++i) { local[i] = cell_count[base + i]; sum += local[i]; }
  s[tid] = sum;
  __syncthreads();
  for (int off = 1; off < 1024; off <<= 1) {
    int v = (tid >= off) ? s[tid - off] : 0;
    __syncthreads();
    s[tid] += v;
    __syncthreads();
  }
  int run = s[tid] - sum;  // exclusive prefix
#pragma unroll
  for (int i = 0; i < 32; ++i) {
    cell_start[base + i] = run;
    cell_cursor[base + i] = run;
    run += local[i];
  }
}

// scatter into sorted order; sortmap[slot] = original index
__global__ __launch_bounds__(256) void scatter_kernel(const float4* __restrict__ pos4,
                                                      const int* __restrict__ pt_cell,
                                                      int* __restrict__ cell_cursor,
                                                      float4* __restrict__ sorted4,
                                                      int* __restrict__ sortmap) {
  int i = blockIdx.x * 256 + threadIdx.x;
  if (i >= NPTS) return;
  int c = pt_cell[i];
  int dst = atomicAdd(&cell_cursor[c], 1);
  float4 p = pos4[i];
  p.w = __int_as_float(i);
  sorted4[dst] = p;
  sortmap[dst] = i;
}

// --------- grid knn in SORTED-SLOT space: 2 queries/wave, 32 lanes each, cap-KC.
__global__ __launch_bounds__(256) void knn_grid_kernel(const float4* __restrict__ sorted4,
                                                       const int* __restrict__ cell_start,
                                                       const int* __restrict__ cell_count,
                                                       int* __restrict__ nbr,
                                                       int* __restrict__ fb_list,
                                                       int* __restrict__ fb_count) {
  int lane = threadIdx.x & 63;
  int sub = lane >> 5;   // 2 query subgroups per wave
  int sl = lane & 31;    // lane within subgroup
  int qs = blockIdx.x * 8 + (threadIdx.x >> 6) * 2 + sub;  // sorted-order query slot
  if (qs >= NPTS) return;
  float4 p = sorted4[qs];
  int cx = cell_of(p.x), cy = cell_of(p.y), cz = cell_of(p.z);
  float dist[KC];
  int idx[KC];
#pragma unroll
  for (int i = 0; i < KC; ++i) { dist[i] = 3.4e38f; idx[i] = 0; }

  // ---- phase 1: full box r<=1 (continuous round-robin over 32 lanes)
  {
    int tot = 0;
    int x0 = max(cx - 1, 0), x1 = min(cx + 1, GDIM - 1);
    int zlo = max(cz - 1, 0), zhi = min(cz + 1, GDIM - 1);
    int ylo = max(cy - 1, 0), yhi = min(cy + 1, GDIM - 1);
    for (int z = zlo; z <= zhi; ++z) {
      for (int y = ylo; y <= yhi; ++y) {
        int c0 = (z * GDIM + y) * GDIM + x0;
        int c1 = (z * GDIM + y) * GDIM + x1;
        int beg = cell_start[c0];
        int end = cell_start[c1] + cell_count[c1];
        int off = (sl - tot) & 31;
        for (int j = beg + off; j < end; j += 32) {
          float4 sp = sorted4[j];
          float dx = sp.x - p.x, dy = sp.y - p.y, dz = sp.z - p.z;
          float d2 = dx * dx + dy * dy + dz * dz;
          KNN_INSERTC(d2, j);
        }
        tot += end - beg;
      }
    }
  }
  int done;
  {
    float b2 = CW * CW;
    int cnt = 0;
#pragma unroll
    for (int i = 0; i < KC; ++i) cnt += (dist[i] <= b2) ? 1 : 0;
#pragma unroll
    for (int s = 1; s < 32; s <<= 1) cnt += __shfl_xor(cnt, s, 64);
    done = (cnt >= KG) ? 1 : 0;
  }

  // ---- phase 2: rings r=2..RMAX, lane-per-segment over 32 lanes
  for (int r = 2; r <= RMAX && !done; ++r) {
    int side = 2 * r + 1;
    int nt = side * side;
    float rcp = 1.0f / (float)side;
    for (int t = sl; t < nt; t += 32) {
      int qz = (int)(((float)t + 0.5f) * rcp);  // exact floor(t/side) for t<169
      int dz = qz - r;
      int dy = t - qz * side - r;
      int z = cz + dz, y = cy + dy;
      if (z < 0 || z >= GDIM || y < 0 || y >= GDIM) continue;
      int rowbase = (z * GDIM + y) * GDIM;
      if (dz == -r || dz == r || dy == -r || dy == r) {
        int xa = max(cx - r, 0), xb = min(cx + r, GDIM - 1);
        int beg = cell_start[rowbase + xa];
        int end = cell_start[rowbase + xb] + cell_count[rowbase + xb];
        for (int j = beg; j < end; ++j) {
          float4 sp = sorted4[j];
          float ddx = sp.x - p.x, ddy = sp.y - p.y, ddz = sp.z - p.z;
          float d2 = ddx * ddx + ddy * ddy + ddz * ddz;
          KNN_INSERTC(d2, j);
        }
      } else {
        int x = cx - r;
        if (x >= 0) {
          int c = rowbase + x;
          int beg = cell_start[c], end = beg + cell_count[c];
          for (int j = beg; j < end; ++j) {
            float4 sp = sorted4[j];
            float ddx = sp.x - p.x, ddy = sp.y - p.y, ddz = sp.z - p.z;
            float d2 = ddx * ddx + ddy * ddy + ddz * ddz;
            KNN_INSERTC(d2, j);
          }
        }
        x = cx + r;
        if (x < GDIM) {
          int c = rowbase + x;
          int beg = cell_start[c], end = beg + cell_count[c];
          for (int j = beg; j < end; ++j) {
            float4 sp = sorted4[j];
            float ddx = sp.x - p.x, ddy = sp.y - p.y, ddz = sp.z - p.z;
            float d2 = ddx * ddx + ddy * ddy + ddz * ddz;
            KNN_INSERTC(d2, j);
          }
        }
      }
    }
    float b = CW * (float)r;
    float b2 = b * b;
    int cnt = 0;
#pragma unroll
    for (int i = 0; i < KC; ++i) cnt += (dist[i] <= b2) ? 1 : 0;
#pragma unroll
    for (int s = 1; s < 32; s <<= 1) cnt += __shfl_xor(cnt, s, 64);
    if (cnt >= KG) done = 1;
  }

  // 32-way merge: 20 rounds of subgroup argmin over packed (d2,slot) keys.
  // Exactness guard: lane pops all KC entries OR rings exhausted -> exact fallback.
  int popc = 0, ovf = 0;
  for (int round = 0; round < KG; ++round) {
    unsigned long long key = ((unsigned long long)__float_as_uint(dist[0]) << 14) |
                             (unsigned long long)(unsigned)idx[0];
    unsigned long long m = key;
#pragma unroll
    for (int s = 1; s < 32; s <<= 1) {
      unsigned long long o = __shfl_xor(m, s, 64);
      if (o < m) m = o;
    }
    if (key == m) {
      nbr[(size_t)qs * KG + round] = (int)(m & 0x3FFF);
#pragma unroll
      for (int s = 0; s < KC - 1; ++s) { dist[s] = dist[s + 1]; idx[s] = idx[s + 1]; }
      dist[KC - 1] = 3.4e38f;
      idx[KC - 1] = 0;
      if (++popc == KC) ovf = 1;
    }
  }
#pragma unroll
  for (int s = 1; s < 32; s <<= 1) ovf |= __shfl_xor(ovf, s, 64);
  if ((ovf || !done) && sl == 0) {
    int s = atomicAdd(fb_count, 1);
    fb_list[s] = qs;
  }
}

// ---------------------------------------------------------------- brute-force fallback (slots)
__global__ __launch_bounds__(256) void knn_fb_kernel(const float4* __restrict__ sorted4,
                                                     const int* __restrict__ fb_list,
                                                     const int* __restrict__ fb_count,
                                                     int* __restrict__ nbr) {
  __shared__ unsigned long long lists[256 * KG];
  __shared__ unsigned long long heads[256];
  __shared__ unsigned long long winner;
  int tid = threadIdx.x;
  int cnt = *fb_count;
  for (int qi = blockIdx.x; qi < cnt; qi += gridDim.x) {
    int t = fb_list[qi];
    float4 p = sorted4[t];
    float dist[KG];
    int idx[KG];
#pragma unroll
    for (int i = 0; i < KG; ++i) { dist[i] = 3.4e38f; idx[i] = 0; }
    int j0 = tid * 64;
    for (int j = j0; j < j0 + 64; ++j) {
      float4 c = sorted4[j];
      float dx = c.x - p.x, dy = c.y - p.y, dz = c.z - p.z;
      float d2 = dx * dx + dy * dy + dz * dz;
      KNN_INSERT(d2, j);
    }
#pragma unroll
    for (int i = 0; i < KG; ++i)
      lists[tid * KG + i] = ((unsigned long long)__float_as_uint(dist[i]) << 22) |
                            ((unsigned long long)(unsigned)idx[i] << 8) |
                            (unsigned long long)tid;
    int hp = 0;
    __syncthreads();
    for (int round = 0; round < KG; ++round) {
      heads[tid] = (hp < KG) ? lists[tid * KG + hp] : ~0ull;
      __syncthreads();
      if (tid < 64) {
        unsigned long long m = heads[tid];
        unsigned long long o = heads[tid + 64];  if (o < m) m = o;
        o = heads[tid + 128]; if (o < m) m = o;
        o = heads[tid + 192]; if (o < m) m = o;
#pragma unroll
        for (int s = 32; s > 0; s >>= 1) {
          unsigned long long x = __shfl_xor(m, s, 64);
          if (x < m) m = x;
        }
        if (tid == 0) winner = m;
      }
      __syncthreads();
      unsigned long long w = winner;
      if (tid == (int)(w & 0xFF)) hp++;
      if (tid == 0) nbr[(size_t)t * KG + round] = (int)((w >> 8) & 0x3FFF);
      __syncthreads();
    }
  }
}

// ---------------------------------------------------- basis (sorted space, f32)
__global__ __launch_bounds__(256) void basis_kernel(const float4* __restrict__ sorted4,
                                                    const int* __restrict__ nbr,
                                                    float4* __restrict__ xb4,
                                                    float4* __restrict__ yb4) {
  int n = blockIdx.x * 256 + threadIdx.x;
  if (n >= NPTS) return;
  float4 p = sorted4[n];
  float c00 = 0, c01 = 0, c02 = 0, c11 = 0, c12 = 0, c22 = 0;
  for (int k = 0; k < KN; ++k) {
    int m = nbr[(size_t)n * KG + k];
    float4 pm = sorted4[m];
    float dx = pm.x - p.x, dy = pm.y - p.y, dz = pm.z - p.z;
    c00 += dx * dx; c01 += dx * dy; c02 += dx * dz;
    c11 += dy * dy; c12 += dy * dz; c22 += dz * dz;
  }
  float nx = 0.f, ny = 0.f, nz = 1.f;
  float p1 = c01 * c01 + c02 * c02 + c12 * c12;
  float qm = (c00 + c11 + c22) * (1.f / 3.f);
  float g0 = c00 - qm, g1 = c11 - qm, g2 = c22 - qm;
  float p2 = g0 * g0 + g1 * g1 + g2 * g2 + 2.f * p1;
  if (p2 > 1e-16f) {
    float pp = sqrtf(p2 * (1.f / 6.f));
    float inv = 1.f / pp;
    float b00 = g0 * inv, b11 = g1 * inv, b22 = g2 * inv;
    float b01 = c01 * inv, b02 = c02 * inv, b12 = c12 * inv;
    float detB = b00 * (b11 * b22 - b12 * b12) - b01 * (b01 * b22 - b12 * b02) +
                 b02 * (b01 * b12 - b11 * b02);
    float r = 0.5f * detB;
    r = fminf(1.f, fmaxf(-1.f, r));
    float phi = acosf(r) * (1.f / 3.f);
    float e1 = qm + 2.f * pp * __cosf(phi);
    float e3 = qm + 2.f * pp * __cosf(phi + 2.0943951023931953f);
    float e2 = 3.f * qm - e1 - e3;
    float a00 = c00 - e1, a11 = c11 - e1, a22 = c22 - e1;
    float f00 = c00 - e2, f11 = c11 - e2, f22 = c22 - e2;
    float u0 = a00 * f00 + c01 * c01 + c02 * c02;
    float u1 = c01 * f00 + a11 * c01 + c12 * c02;
    float u2 = c02 * f00 + c12 * c01 + a22 * c02;
    float v0 = a00 * c01 + c01 * f11 + c02 * c12;
    float v1 = c01 * c01 + a11 * f11 + c12 * c12;
    float v2 = c02 * c01 + c12 * f11 + a22 * c12;
    float w0 = a00 * c02 + c01 * c12 + c02 * f22;
    float w1 = c01 * c02 + a11 * c12 + c12 * f22;
    float w2 = c02 * c02 + c12 * c12 + a22 * f22;
    float nu = u0 * u0 + u1 * u1 + u2 * u2;
    float nv = v0 * v0 + v1 * v1 + v2 * v2;
    float nw = w0 * w0 + w1 * w1 + w2 * w2;
    float bx = u0, by = u1, bz = u2, bn = nu;
    if (nv > bn) { bx = v0; by = v1; bz = v2; bn = nv; }
    if (nw > bn) { bx = w0; by = w1; bz = w2; bn = nw; }
    if (bn > 1e-30f) {
      float s = 1.f / sqrtf(bn);
      nx = bx * s; ny = by * s; nz = bz * s;
    }
  }
  float dotp = nx * p.x + ny * p.y + nz * p.z;
  if (dotp < 0.f) { nx = -nx; ny = -ny; nz = -nz; }
  float ax = fabsf(nx), ay = fabsf(ny), az = fabsf(nz);
  float ex = 0.f, ey = 0.f, ez = 0.f;
  if (ax <= ay && ax <= az) ex = 1.f;
  else if (ay <= az) ey = 1.f;
  else ez = 1.f;
  float tx = ny * ez - nz * ey, ty = nz * ex - nx * ez, tz = nx * ey - ny * ex;
  float tn = 1.f / sqrtf(tx * tx + ty * ty + tz * tz);
  tx *= tn; ty *= tn; tz *= tn;
  float ux = ny * tz - nz * ty, uy = nz * tx - nx * tz, uz = nx * ty - ny * tx;
  xb4[n] = make_float4(tx, ty, tz, 0.f);
  yb4[n] = make_float4(ux, uy, uz, 0.f);
}

// --------------------------- Gx/Gy + C2 + v0 = grad(pos) (sorted space, f32)
__global__ __launch_bounds__(256) void graddiv_kernel(const float4* __restrict__ sorted4,
                                                      const int* __restrict__ nbr,
                                                      const float4* __restrict__ xb4,
                                                      const float4* __restrict__ yb4,
                                                      float* __restrict__ Gx,
                                                      float* __restrict__ Gy,
                                                      float2* __restrict__ C2,
                                                      float* __restrict__ v0) {
  int n = blockIdx.x * 256 + threadIdx.x;
  if (n >= NPTS) return;
  float4 p = sorted4[n], xb = xb4[n], yb = yb4[n];
  float u[KG], vv[KG], w[KG];
  int mm[KG];
  float hsum = 0.f;
#pragma unroll
  for (int k = 0; k < KG; ++k) {
    int m = nbr[(size_t)n * KG + k];
    mm[k] = m;
    float4 pm = sorted4[m];
    float rx = pm.x - p.x, ry = pm.y - p.y, rz = pm.z - p.z;
    u[k] = rx * xb.x + ry * xb.y + rz * xb.z;
    vv[k] = rx * yb.x + ry * yb.y + rz * yb.z;
    float dd = sqrtf(rx * rx + ry * ry + rz * rz + EPSF);
    w[k] = dd; hsum += dd;
  }
  float h = hsum * (1.f / KG);
  float invden = 1.f / (h * h + EPSF);
  float A00 = 0, A01 = 0, A02 = 0, A11 = 0, A12 = 0, A22 = 0;
#pragma unroll
  for (int k = 0; k < KG; ++k) {
    float wk = __expf(-(w[k] * w[k]) * invden);
    w[k] = wk;
    A00 += wk; A01 += wk * u[k]; A02 += wk * vv[k];
    A11 += wk * u[k] * u[k]; A12 += wk * u[k] * vv[k];
    A22 += wk * vv[k] * vv[k];
  }
  A00 += 0.001f; A11 += 0.001f; A22 += 0.001f;
  float det = A00 * (A11 * A22 - A12 * A12) - A01 * (A01 * A22 - A12 * A02) +
              A02 * (A01 * A12 - A11 * A02);
  float idet = 1.f / det;
  float i10 = (A02 * A12 - A01 * A22) * idet;
  float i11 = (A00 * A22 - A02 * A02) * idet;
  float i12 = (A01 * A02 - A00 * A12) * idet;
  float i20 = (A01 * A12 - A02 * A11) * idet;
  float i21 = i12;
  float i22 = (A00 * A11 - A01 * A01) * idet;
  float a0x = 0, a0y = 0, a0z = 0, a1x = 0, a1y = 0, a1z = 0;
#pragma unroll
  for (int k = 0; k < KG; ++k) {
    float gx = w[k] * (i10 + i11 * u[k] + i12 * vv[k]);
    float gy = w[k] * (i20 + i21 * u[k] + i22 * vv[k]);
    Gx[(size_t)n * KG + k] = gx;
    Gy[(size_t)n * KG + k] = gy;
    int m = mm[k];
    float4 pm = sorted4[m];
    a0x += gx * pm.x; a0y += gx * pm.y; a0z += gx * pm.z;
    a1x += gy * pm.x; a1y += gy * pm.y; a1z += gy * pm.z;
    float4 xm = xb4[m], ym = yb4[m];
    float g3x = gx * xb.x + gy * yb.x;
    float g3y = gx * xb.y + gy * yb.y;
    float g3z = gx * xb.z + gy * yb.z;
    float ca = g3x * xm.x + g3y * xm.y + g3z * xm.z;
    float cb = g3x * ym.x + g3y * ym.y + g3z * ym.z;
    C2[(size_t)n * KG + k] = make_float2(ca, cb);
  }
  v0[((size_t)n * 2 + 0) * 3 + 0] = a0x;
  v0[((size_t)n * 2 + 0) * 3 + 1] = a0y;
  v0[((size_t)n * 2 + 0) * 3 + 2] = a0z;
  v0[((size_t)n * 2 + 1) * 3 + 0] = a1x;
  v0[((size_t)n * 2 + 1) * 3 + 1] = a1y;
  v0[((size_t)n * 2 + 1) * 3 + 2] = a1z;
}

// ------------------------------------------------- feat scalar (layer 0, cin=3, f32 in)
template <int CENTRAL>
__global__ __launch_bounds__(256) void feat16_kernel(const float* __restrict__ x, int ldx,
                                                     int cin,
                                                     const float* __restrict__ v,
                                                     const int* __restrict__ nbr,
                                                     const float2* __restrict__ C2,
                                                     unsigned short* __restrict__ feat, int Kp) {
  int per = Kp - 2 * cin;
  int gid = blockIdx.x * 256 + threadIdx.x;
  if (gid >= NPTS * per) return;
  int n = gid / per;
  int c = gid - n * per;
  size_t fb = (size_t)n * Kp;
  if (c >= cin) {  // pad column
    feat[fb + 3 * cin + (c - cin)] = 0;
    return;
  }
  float xc = x[(size_t)n * ldx + c];
  float xmax = -3.4e38f, dv = 0.f, cv = 0.f;
  for (int k = 0; k < KG; ++k) {
    int m = nbr[(size_t)n * KG + k];
    float2 cc = C2[(size_t)n * KG + k];
    float xm = x[(size_t)m * ldx + c];
    xmax = fmaxf(xmax, CENTRAL ? (xm - xc) : xm);
    float va = v[((size_t)m * 2 + 0) * cin + c];
    float vb = v[((size_t)m * 2 + 1) * cin + c];
    dv += cc.x * va + cc.y * vb;
    cv += cc.y * va - cc.x * vb;
  }
  feat[fb + c] = f2bf(xmax);
  feat[fb + cin + c] = f2bf(dv);
  feat[fb + 2 * cin + c] = f2bf(cv);
}

// ----------------------- feat vectorized: bf16 x/v mirrors, 8 channels/thread
__global__ __launch_bounds__(256) void feat16v8_kernel(const unsigned short* __restrict__ x,
                                                       int cin,
                                                       const unsigned short* __restrict__ v,
                                                       const int* __restrict__ nbr,
                                                       const float2* __restrict__ C2,
                                                       unsigned short* __restrict__ feat) {
  int per = cin >> 3;
  int gid = blockIdx.x * 256 + threadIdx.x;
  if (gid >= NPTS * per) return;
  int n = gid / per;
  int c8 = (gid - n * per) << 3;
  float xmax[8], dv[8], cv[8];
#pragma unroll
  for (int i = 0; i < 8; ++i) { xmax[i] = -3.4e38f; dv[i] = 0.f; cv[i] = 0.f; }
  const int* nrow = nbr + (size_t)n * KG;
  const float2* crow = C2 + (size_t)n * KG;
#pragma unroll 4
  for (int k = 0; k < KG; ++k) {
    int m = nrow[k];
    float2 cc = crow[k];
    short8v xm = *reinterpret_cast<const short8v*>(x + (size_t)m * cin + c8);
    short8v va = *reinterpret_cast<const short8v*>(v + ((size_t)m * 2 + 0) * cin + c8);
    short8v vb = *reinterpret_cast<const short8v*>(v + ((size_t)m * 2 + 1) * cin + c8);
#pragma unroll
    for (int i = 0; i < 8; ++i) {
      float xf = bf2f((unsigned short)xm[i]);
      float af = bf2f((unsigned short)va[i]);
      float bf = bf2f((unsigned short)vb[i]);
      xmax[i] = fmaxf(xmax[i], xf);
      dv[i] += cc.x * af + cc.y * bf;
      cv[i] += cc.y * af - cc.x * bf;
    }
  }
  size_t fb = (size_t)n * (3 * cin);
  short8v o0, o1, o2;
#pragma unroll
  for (int i = 0; i < 8; ++i) {
    o0[i] = (short)f2bf(xmax[i]);
    o1[i] = (short)f2bf(dv[i]);
    o2[i] = (short)f2bf(cv[i]);
  }
  *reinterpret_cast<short8v*>(&feat[fb + c8]) = o0;
  *reinterpret_cast<short8v*>(&feat[fb + cin + c8]) = o1;
  *reinterpret_cast<short8v*>(&feat[fb + 2 * cin + c8]) = o2;
}

// ------------------------------------------------- vin scalar (layer 0, Kp=96, cin=3)
__global__ __launch_bounds__(256) void vin16_kernel(const float* __restrict__ v, int cin,
                                                    const unsigned short* __restrict__ xout,
                                                    int cout,
                                                    const int* __restrict__ nbr,
                                                    const float* __restrict__ Gx,
                                                    const float* __restrict__ Gy,
                                                    unsigned short* __restrict__ vinb, int Kp,
                                                    int total) {
  int gid = blockIdx.x * 256 + threadIdx.x;
  if (gid >= total) return;
  int n = gid / Kp;
  int c = gid - n * Kp;
  int K = cin + cout;
  unsigned short o0, o1;
  if (c < cin) {
    o0 = f2bf(v[((size_t)n * 2 + 0) * cin + c]);
    o1 = f2bf(v[((size_t)n * 2 + 1) * cin + c]);
  } else if (c < K) {
    int cc = c - cin;
    float a0 = 0.f, a1 = 0.f;
    for (int k = 0; k < KG; ++k) {
      int m = nbr[(size_t)n * KG + k];
      float f = bf2f(xout[(size_t)m * cout + cc]);
      a0 += Gx[(size_t)n * KG + k] * f;
      a1 += Gy[(size_t)n * KG + k] * f;
    }
    o0 = f2bf(a0);
    o1 = f2bf(a1);
  } else {
    o0 = 0; o1 = 0;
  }
  vinb[((size_t)n * 2 + 0) * Kp + c] = o0;
  vinb[((size_t)n * 2 + 1) * Kp + c] = o1;
}

// ----------------------- vin vectorized: bf16 v + bf16 xout mirror, 8 ch/thread
__global__ __launch_bounds__(256) void vin16v8_kernel(const unsigned short* __restrict__ v,
                                                      int cin,
                                                      const unsigned short* __restrict__ xout,
                                                      int cout,
                                                      const int* __restrict__ nbr,
                                                      const float* __restrict__ Gx,
                                                      const float* __restrict__ Gy,
                                                      unsigned short* __restrict__ vinb,
                                                      int Kp) {
  int per = Kp >> 3;
  int gid = blockIdx.x * 256 + threadIdx.x;
  if (gid >= NPTS * per) return;
  int n = gid / per;
  int c8 = (gid - n * per) << 3;
  short8v o0, o1;
  if (c8 < cin) {
    o0 = *reinterpret_cast<const short8v*>(v + ((size_t)n * 2 + 0) * cin + c8);
    o1 = *reinterpret_cast<const short8v*>(v + ((size_t)n * 2 + 1) * cin + c8);
  } else {
    int cc8 = c8 - cin;
    float a0[8], a1[8];
#pragma unroll
    for (int i = 0; i < 8; ++i) { a0[i] = 0.f; a1[i] = 0.f; }
    const int* nrow = nbr + (size_t)n * KG;
    const float* gxr = Gx + (size_t)n * KG;
    const float* gyr = Gy + (size_t)n * KG;
#pragma unroll 4
    for (int k = 0; k < KG; ++k) {
      int m = nrow[k];
      float gx = gxr[k], gy = gyr[k];
      short8v f = *reinterpret_cast<const short8v*>(xout + (size_t)m * cout + cc8);
#pragma unroll
      for (int i = 0; i < 8; ++i) {
        float ff = bf2f((unsigned short)f[i]);
        a0[i] += gx * ff;
        a1[i] += gy * ff;
      }
    }
#pragma unroll
    for (int i = 0; i < 8; ++i) {
      o0[i] = (short)f2bf(a0[i]);
      o1[i] = (short)f2bf(a1[i]);
    }
  }
  *reinterpret_cast<short8v*>(&vinb[((size_t)n * 2 + 0) * Kp + c8]) = o0;
  *reinterpret_cast<short8v*>(&vinb[((size_t)n * 2 + 1) * Kp + c8]) = o1;
}

// --------------------- weight prep, all 5 weights fused into one launch
__device__ __forceinline__ void wprep_one(const float* W, unsigned short* Wt, int K, int Kp,
                                          int N, int i) {
  int n = i / Kp, k = i - n * Kp;
  Wt[i] = (k < K) ? f2bf(W[(size_t)k * N + n]) : (unsigned short)0;
}

__global__ __launch_bounds__(256) void wprep_all_kernel(const float* __restrict__ Ws0,
                                                        const float* __restrict__ Wv0,
                                                        const float* __restrict__ Ws1,
                                                        const float* __restrict__ Wv1,
                                                        const float* __restrict__ Ws2,
                                                        unsigned short* __restrict__ Wt_s0,
                                                        unsigned short* __restrict__ Wt_v0,
                                                        unsigned short* __restrict__ Wt_s1,
                                                        unsigned short* __restrict__ Wt_v1,
                                                        unsigned short* __restrict__ Wt_s2) {
  int gid = blockIdx.x * 256 + threadIdx.x;
  if (gid < 2048) wprep_one(Ws0, Wt_s0, 9, 32, 64, gid);
  else if (gid < 8192) wprep_one(Wv0, Wt_v0, 67, 96, 64, gid - 2048);
  else if (gid < 32768) wprep_one(Ws1, Wt_s1, 192, 192, 128, gid - 8192);
  else if (gid < 57344) wprep_one(Wv1, Wt_v1, 192, 192, 128, gid - 32768);
  else if (gid < 155648) wprep_one(Ws2, Wt_s2, 384, 384, 256, gid - 57344);
}

// ------------------------------------------------- bf16 MFMA GEMM
// MODE 0: Cf[rowmap[row]] = relu(A@B+bias) f32 (+ optional bf16 mirror Cb[row], sorted).
// MODE 1: normgate over row pairs, bf16 output to Cb only (sorted rows).
template <int MODE>
__global__ __launch_bounds__(256) void gemm16_kernel(const unsigned short* __restrict__ A,
                                                     const unsigned short* __restrict__ Bt,
                                                     const float* __restrict__ bias,
                                                     float* __restrict__ Cf,
                                                     unsigned short* __restrict__ Cb,
                                                     const int* __restrict__ rowmap,
                                                     int Kp, int Ncol) {
  int lane = threadIdx.x & 63;
  int wave = threadIdx.x >> 6;
  int rowBase = blockIdx.y * 64 + wave * 16;
  int colBase = blockIdx.x * 64;
  int lr = lane & 15;
  int kg = (lane >> 4) * 8;
  floatx4 acc0 = {0.f, 0.f, 0.f, 0.f};
  floatx4 acc1 = acc0, acc2 = acc0, acc3 = acc0;
  const unsigned short* arow = A + (size_t)(rowBase + lr) * Kp + kg;
  const unsigned short* b0p = Bt + (size_t)(colBase + lr) * Kp + kg;
  for (int k0 = 0; k0 < Kp; k0 += 32) {
    short8v a = *reinterpret_cast<const short8v*>(arow + k0);
    short8v b0 = *reinterpret_cast<const short8v*>(b0p + k0);
    short8v b1 = *reinterpret_cast<const short8v*>(b0p + (size_t)16 * Kp + k0);
    short8v b2 = *reinterpret_cast<const short8v*>(b0p + (size_t)32 * Kp + k0);
    short8v b3 = *reinterpret_cast<const short8v*>(b0p + (size_t)48 * Kp + k0);
    acc0 = __builtin_amdgcn_mfma_f32_16x16x32_bf16(a, b0, acc0, 0, 0, 0);
    acc1 = __builtin_amdgcn_mfma_f32_16x16x32_bf16(a, b1, acc1, 0, 0, 0);
    acc2 = __builtin_amdgcn_mfma_f32_16x16x32_bf16(a, b2, acc2, 0, 0, 0);
    acc3 = __builtin_amdgcn_mfma_f32_16x16x32_bf16(a, b3, acc3, 0, 0, 0);
  }
  int rsub = (lane >> 4) * 4;
  floatx4 accs[4] = {acc0, acc1, acc2, acc3};
  int orow[4];
  if (MODE == 0) {
#pragma unroll
    for (int r = 0; r < 4; ++r) orow[r] = rowmap[rowBase + rsub + r];
  }
#pragma unroll
  for (int nb = 0; nb < 4; ++nb) {
    int col = colBase + nb * 16 + lr;
    float bb = bias[col];
    if (MODE == 0) {
#pragma unroll
      for (int r = 0; r < 4; ++r) {
        int row = rowBase + rsub + r;
        float val = fmaxf(accs[nb][r] + bb, 0.f);
        Cf[(size_t)orow[r] * Ncol + col] = val;
        if (Cb) Cb[(size_t)row * Ncol + col] = f2bf(val);
      }
    } else {
#pragma unroll
      for (int pr = 0; pr < 2; ++pr) {
        float a0 = accs[nb][2 * pr], a1 = accs[nb][2 * pr + 1];
        float nrm = sqrtf(a0 * a0 + a1 * a1 + EPSF);
        float s = fmaxf(nrm + bb, 0.f) / (nrm + EPSF);
        int row = rowBase + rsub + 2 * pr;
        Cb[(size_t)row * Ncol + col] = f2bf(a0 * s);
        Cb[(size_t)(row + 1) * Ncol + col] = f2bf(a1 * s);
      }
    }
  }
}

// ---------------------------------------------------------------- launch
extern "C" void kernel_launch(void* const* d_in, const int* in_sizes, int n_in,
                              void* d_out, int out_size, void* d_ws, size_t ws_size,
                              hipStream_t stream) {
  const float* pts = (const float*)d_in[0];
  const float* als = (const float*)d_in[1];
  const float* Ws0 = (const float*)d_in[2];
  const float* bs0 = (const float*)d_in[3];
  const float* Wv0 = (const float*)d_in[4];
  const float* bv0 = (const float*)d_in[5];
  const float* Ws1 = (const float*)d_in[6];
  const float* bs1 = (const float*)d_in[7];
  const float* Wv1 = (const float*)d_in[8];
  const float* bv1 = (const float*)d_in[9];
  const float* Ws2 = (const float*)d_in[10];
  const float* bs2 = (const float*)d_in[11];

  char* ws = (char*)d_ws;
  float4* pos4 = (float4*)(ws + 0);               //  256 KB (original order, staging)
  int* nbr = (int*)(ws + 262144);                 // 1.31 MB (sorted-slot space)
  float4* xb4 = (float4*)(ws + 1572864);          //  256 KB (sorted)
  float4* yb4 = (float4*)(ws + 1835008);          //  256 KB (sorted)
  float* Gx = (float*)(ws + 2097152);             // 1.31 MB (sorted)
  float* Gy = (float*)(ws + 3407872);             // 1.31 MB (sorted)
  float2* C2 = (float2*)(ws + 4718592);           // 2.62 MB (sorted)
  float* v0f = (float*)(ws + 7340032);            //  393 KB (sorted)
  unsigned short* vb_a = (unsigned short*)(ws + 8388608);    // 8.39 MB (sorted)
  unsigned short* vb_b = (unsigned short*)(ws + 17825792);   // 4.19 MB (sorted)
  unsigned short* xb0m = (unsigned short*)(ws + 23068672);   // 2.10 MB (sorted)
  unsigned short* xb1m = (unsigned short*)(ws + 26214400);   // 4.19 MB (sorted)
  unsigned short* stg = (unsigned short*)(ws + 31457280);    // 12.6 MB (sorted)
  char* wtb = ws + 45088768;                      // transposed bf16 weights (~311 KB)
  unsigned short* Wt_s0 = (unsigned short*)(wtb + 0);
  unsigned short* Wt_v0 = (unsigned short*)(wtb + 4096);
  unsigned short* Wt_s1 = (unsigned short*)(wtb + 16384);
  unsigned short* Wt_v1 = (unsigned short*)(wtb + 65536);
  unsigned short* Wt_s2 = (unsigned short*)(wtb + 114688);

  char* gws = ws + 46137344;                      // knn scratch
  int* cell_count = (int*)(gws + 0);              // 128 KB
  int* fb_count = (int*)(gws + 131072);           // 4 B (memset together with cell_count)
  int* cell_start = (int*)(gws + 135168);         // 128 KB
  int* cell_cursor = (int*)(gws + 266240);        // 128 KB
  int* pt_cell = (int*)(gws + 397312);            // 64 KB
  int* fb_list = (int*)(gws + 462848);            // 64 KB
  float4* sorted4 = (float4*)(gws + 532480);      // 256 KB
  int* sortmap = (int*)(gws + 794624);            // 64 KB (slot -> original row)

  float* out0 = (float*)d_out;             // (N,64) original order
  float* out1 = out0 + (size_t)NPTS * 64;  // (N,128)
  float* out2 = out1 + (size_t)NPTS * 128; // (N,256)

  hipMemsetAsync(cell_count, 0, 131072 + 4, stream);  // cell_count + fb_count
  posbin_kernel<<<64, 256, 0, stream>>>(pts, als, pos4, cell_count, pt_cell);
  scan_kernel<<<1, 1024, 0, stream>>>(cell_count, cell_start, cell_cursor);
  scatter_kernel<<<64, 256, 0, stream>>>(pos4, pt_cell, cell_cursor, sorted4, sortmap);
  knn_grid_kernel<<<NPTS / 8, 256, 0, stream>>>(sorted4, cell_start, cell_count, nbr, fb_list,
                                                fb_count);
  knn_fb_kernel<<<128, 256, 0, stream>>>(sorted4, fb_list, fb_count, nbr);

  basis_kernel<<<64, 256, 0, stream>>>(sorted4, nbr, xb4, yb4);
  graddiv_kernel<<<64, 256, 0, stream>>>(sorted4, nbr, xb4, yb4, Gx, Gy, C2, v0f);

  wprep_all_kernel<<<608, 256, 0, stream>>>(Ws0, Wv0, Ws1, Wv1, Ws2, Wt_s0, Wt_v0, Wt_s1,
                                            Wt_v1, Wt_s2);

  // ---- layer 0 (cin=3 -> cout=64, centralized), all in sorted space
  feat16_kernel<1><<<(NPTS * 26 + 255) / 256, 256, 0, stream>>>((const float*)sorted4, 4, 3,
                                                                v0f, nbr, C2, stg, 32);
  gemm16_kernel<0><<<dim3(1, 256), 256, 0, stream>>>(stg, Wt_s0, bs0, out0, xb0m, sortmap, 32,
                                                     64);
  vin16_kernel<<<(NPTS * 96 + 255) / 256, 256, 0, stream>>>(v0f, 3, xb0m, 64, nbr, Gx, Gy, stg,
                                                            96, NPTS * 96);
  gemm16_kernel<1><<<dim3(1, 512), 256, 0, stream>>>(stg, Wt_v0, bv0, nullptr, vb_b, nullptr,
                                                     96, 64);

  // ---- layer 1 (cin=64 -> cout=128)
  feat16v8_kernel<<<NPTS * 8 / 256, 256, 0, stream>>>(xb0m, 64, vb_b, nbr, C2, stg);
  gemm16_kernel<0><<<dim3(2, 256), 256, 0, stream>>>(stg, Wt_s1, bs1, out1, xb1m, sortmap, 192,
                                                     128);
  vin16v8_kernel<<<NPTS * 24 / 256, 256, 0, stream>>>(vb_b, 64, xb1m, 128, nbr, Gx, Gy, stg,
                                                      192);
  gemm16_kernel<1><<<dim3(2, 512), 256, 0, stream>>>(stg, Wt_v1, bv1, nullptr, vb_a, nullptr,
                                                     192, 128);

  // ---- layer 2 (cin=128 -> cout=256, no vector update)
  feat16v8_kernel<<<NPTS * 16 / 256, 256, 0, stream>>>(xb1m, 128, vb_a, nbr, C2, stg);
  gemm16_kernel<0><<<dim3(4, 256), 256, 0, stream>>>(stg, Wt_s2, bs2, out2, nullptr, sortmap,
                                                     384, 256);
}

// Round 16
// 288.246 us; speedup vs baseline: 1.4531x; 1.0129x over previous
//
#include <hip/hip_runtime.h>
#include <math.h>

#define NPTS 16384
#define KG 20
#define KN 10
#define KC 6
#define EPSF 1e-8f

#define GDIM 32
#define GL 4.75f
#define CW 0.296875f
#define GINV 3.3684210526f
#define RMAX 6

typedef __attribute__((ext_vector_type(8))) short short8v;
typedef __attribute__((ext_vector_type(4))) float floatx4;

__device__ __forceinline__ unsigned short f2bf(float v) {
  union { float f; unsigned u; } x;
  x.f = v;
  unsigned r = x.u + 0x7FFFu + ((x.u >> 16) & 1u);  // RNE (finite inputs)
  return (unsigned short)(r >> 16);
}

__device__ __forceinline__ float bf2f(unsigned short u) {
  union { unsigned u32; float f; } x;
  x.u32 = (unsigned)u << 16;
  return x.f;
}

// sorted insert into KG-register list (strict <, stable by scan order)
#define KNN_INSERT(d2v, iv)                                                 \
  if ((d2v) < dist[KG - 1]) {                                               \
    dist[KG - 1] = (d2v); idx[KG - 1] = (iv);                               \
    _Pragma("unroll")                                                       \
    for (int s_ = KG - 1; s_ > 0; --s_) {                                   \
      if (dist[s_] < dist[s_ - 1]) {                                        \
        float td_ = dist[s_]; dist[s_] = dist[s_ - 1]; dist[s_ - 1] = td_;  \
        int ti_ = idx[s_]; idx[s_] = idx[s_ - 1]; idx[s_ - 1] = ti_;        \
      }                                                                     \
    }                                                                       \
  }

// sorted insert into KC-register list
#define KNN_INSERTC(d2v, iv)                                                \
  if ((d2v) < dist[KC - 1]) {                                               \
    dist[KC - 1] = (d2v); idx[KC - 1] = (iv);                               \
    _Pragma("unroll")                                                       \
    for (int s_ = KC - 1; s_ > 0; --s_) {                                   \
      if (dist[s_] < dist[s_ - 1]) {                                        \
        float td_ = dist[s_]; dist[s_] = dist[s_ - 1]; dist[s_ - 1] = td_;  \
        int ti_ = idx[s_]; idx[s_] = idx[s_ - 1]; idx[s_ - 1] = ti_;        \
      }                                                                     \
    }                                                                       \
  }

__device__ __forceinline__ int cell_of(float x) {
  int c = (int)floorf((x + GL) * GINV);
  return min(max(c, 0), GDIM - 1);
}

// ---------------- pos concat + bin (blocks 0..63) fused with weight prep (blocks 64..671)
__device__ __forceinline__ void wprep_one(const float* W, unsigned short* Wt, int K, int Kp,
                                          int N, int i) {
  int n = i / Kp, k = i - n * Kp;
  Wt[i] = (k < K) ? f2bf(W[(size_t)k * N + n]) : (unsigned short)0;
}

__global__ __launch_bounds__(256) void posbin_wprep_kernel(
    const float* __restrict__ pts, const float* __restrict__ als, float4* __restrict__ pos4,
    int* __restrict__ cell_count, int* __restrict__ pt_cell,
    const float* __restrict__ Ws0, const float* __restrict__ Wv0,
    const float* __restrict__ Ws1, const float* __restrict__ Wv1,
    const float* __restrict__ Ws2, unsigned short* __restrict__ Wt_s0,
    unsigned short* __restrict__ Wt_v0, unsigned short* __restrict__ Wt_s1,
    unsigned short* __restrict__ Wt_v1, unsigned short* __restrict__ Wt_s2) {
  if (blockIdx.x < 64) {
    int n = blockIdx.x * 256 + threadIdx.x;
    if (n >= NPTS) return;
    const float* src = (n < 8192) ? (pts + (size_t)n * 3) : (als + (size_t)(n - 8192) * 3);
    float x = src[0], y = src[1], z = src[2];
    pos4[n] = make_float4(x, y, z, 0.f);
    int c = (cell_of(z) * GDIM + cell_of(y)) * GDIM + cell_of(x);
    pt_cell[n] = c;
    atomicAdd(&cell_count[c], 1);
  } else {
    int gid = (blockIdx.x - 64) * 256 + threadIdx.x;
    if (gid < 2048) wprep_one(Ws0, Wt_s0, 9, 32, 64, gid);
    else if (gid < 8192) wprep_one(Wv0, Wt_v0, 67, 96, 64, gid - 2048);
    else if (gid < 32768) wprep_one(Ws1, Wt_s1, 192, 192, 128, gid - 8192);
    else if (gid < 57344) wprep_one(Wv1, Wt_v1, 192, 192, 128, gid - 32768);
    else if (gid < 155648) wprep_one(Ws2, Wt_s2, 384, 384, 256, gid - 57344);
  }
}

__global__ __launch_bounds__(1024) void scan_kernel(const int* __restrict__ cell_count,
                                                    int* __restrict__ cell_start,
                                                    int* __restrict__ cell_cursor) {
  __shared__ int s[1024];
  int tid = threadIdx.x;
  int base = tid * 32;
  int local[32];
  int sum = 0;
#pragma unroll
  for (int i = 0; i < 32; ++i) { local[i] = cell_count[base + i]; sum += local[i]; }
  s[tid] = sum;
  __syncthreads();
  for (int off = 1; off < 1024; off <<= 1) {
    int v = (tid >= off) ? s[tid - off] : 0;
    __syncthreads();
    s[tid] += v;
    __syncthreads();
  }
  int run = s[tid] - sum;  // exclusive prefix
#pragma unroll
  for (int i = 0; i < 32; ++i) {
    cell_start[base + i] = run;
    cell_cursor[base + i] = run;
    run += local[i];
  }
}

// scatter into sorted order; sortmap[slot] = original index
__global__ __launch_bounds__(256) void scatter_kernel(const float4* __restrict__ pos4,
                                                      const int* __restrict__ pt_cell,
                                                      int* __restrict__ cell_cursor,
                                                      float4* __restrict__ sorted4,
                                                      int* __restrict__ sortmap) {
  int i = blockIdx.x * 256 + threadIdx.x;
  if (i >= NPTS) return;
  int c = pt_cell[i];
  int dst = atomicAdd(&cell_cursor[c], 1);
  float4 p = pos4[i];
  p.w = __int_as_float(i);
  sorted4[dst] = p;
  sortmap[dst] = i;
}

// --------- grid knn in SORTED-SLOT space: 2 queries/wave, 32 lanes each, cap-KC.
__global__ __launch_bounds__(256) void knn_grid_kernel(const float4* __restrict__ sorted4,
                                                       const int* __restrict__ cell_start,
                                                       const int* __restrict__ cell_count,
                                                       int* __restrict__ nbr,
                                                       int* __restrict__ fb_list,
                                                       int* __restrict__ fb_count) {
  int lane = threadIdx.x & 63;
  int sub = lane >> 5;   // 2 query subgroups per wave
  int sl = lane & 31;    // lane within subgroup
  int qs = blockIdx.x * 8 + (threadIdx.x >> 6) * 2 + sub;  // sorted-order query slot
  if (qs >= NPTS) return;
  float4 p = sorted4[qs];
  int cx = cell_of(p.x), cy = cell_of(p.y), cz = cell_of(p.z);
  float dist[KC];
  int idx[KC];
#pragma unroll
  for (int i = 0; i < KC; ++i) { dist[i] = 3.4e38f; idx[i] = 0; }

  // ---- phase 1: full box r<=1, continuous round-robin, 2-way unrolled for ILP
  {
    int tot = 0;
    int x0 = max(cx - 1, 0), x1 = min(cx + 1, GDIM - 1);
    int zlo = max(cz - 1, 0), zhi = min(cz + 1, GDIM - 1);
    int ylo = max(cy - 1, 0), yhi = min(cy + 1, GDIM - 1);
    for (int z = zlo; z <= zhi; ++z) {
      for (int y = ylo; y <= yhi; ++y) {
        int c0 = (z * GDIM + y) * GDIM + x0;
        int c1 = (z * GDIM + y) * GDIM + x1;
        int beg = cell_start[c0];
        int end = cell_start[c1] + cell_count[c1];
        int off = (sl - tot) & 31;
        for (int j = beg + off; j < end; j += 64) {
          int j1 = j + 32;
          float4 sp0 = sorted4[j];
          float4 sp1 = sorted4[(j1 < end) ? j1 : j];
          float dx0 = sp0.x - p.x, dy0 = sp0.y - p.y, dz0 = sp0.z - p.z;
          float d20 = dx0 * dx0 + dy0 * dy0 + dz0 * dz0;
          float dx1 = sp1.x - p.x, dy1 = sp1.y - p.y, dz1 = sp1.z - p.z;
          float d21 = dx1 * dx1 + dy1 * dy1 + dz1 * dz1;
          KNN_INSERTC(d20, j);
          if (j1 < end) { KNN_INSERTC(d21, j1); }
        }
        tot += end - beg;
      }
    }
  }
  int done;
  {
    float b2 = CW * CW;
    int cnt = 0;
#pragma unroll
    for (int i = 0; i < KC; ++i) cnt += (dist[i] <= b2) ? 1 : 0;
#pragma unroll
    for (int s = 1; s < 32; s <<= 1) cnt += __shfl_xor(cnt, s, 64);
    done = (cnt >= KG) ? 1 : 0;
  }

  // ---- phase 2: rings r=2..RMAX, lane-per-segment over 32 lanes
  for (int r = 2; r <= RMAX && !done; ++r) {
    int side = 2 * r + 1;
    int nt = side * side;
    float rcp = 1.0f / (float)side;
    for (int t = sl; t < nt; t += 32) {
      int qz = (int)(((float)t + 0.5f) * rcp);  // exact floor(t/side) for t<169
      int dz = qz - r;
      int dy = t - qz * side - r;
      int z = cz + dz, y = cy + dy;
      if (z < 0 || z >= GDIM || y < 0 || y >= GDIM) continue;
      int rowbase = (z * GDIM + y) * GDIM;
      if (dz == -r || dz == r || dy == -r || dy == r) {
        int xa = max(cx - r, 0), xb = min(cx + r, GDIM - 1);
        int beg = cell_start[rowbase + xa];
        int end = cell_start[rowbase + xb] + cell_count[rowbase + xb];
        for (int j = beg; j < end; ++j) {
          float4 sp = sorted4[j];
          float ddx = sp.x - p.x, ddy = sp.y - p.y, ddz = sp.z - p.z;
          float d2 = ddx * ddx + ddy * ddy + ddz * ddz;
          KNN_INSERTC(d2, j);
        }
      } else {
        int x = cx - r;
        if (x >= 0) {
          int c = rowbase + x;
          int beg = cell_start[c], end = beg + cell_count[c];
          for (int j = beg; j < end; ++j) {
            float4 sp = sorted4[j];
            float ddx = sp.x - p.x, ddy = sp.y - p.y, ddz = sp.z - p.z;
            float d2 = ddx * ddx + ddy * ddy + ddz * ddz;
            KNN_INSERTC(d2, j);
          }
        }
        x = cx + r;
        if (x < GDIM) {
          int c = rowbase + x;
          int beg = cell_start[c], end = beg + cell_count[c];
          for (int j = beg; j < end; ++j) {
            float4 sp = sorted4[j];
            float ddx = sp.x - p.x, ddy = sp.y - p.y, ddz = sp.z - p.z;
            float d2 = ddx * ddx + ddy * ddy + ddz * ddz;
            KNN_INSERTC(d2, j);
          }
        }
      }
    }
    float b = CW * (float)r;
    float b2 = b * b;
    int cnt = 0;
#pragma unroll
    for (int i = 0; i < KC; ++i) cnt += (dist[i] <= b2) ? 1 : 0;
#pragma unroll
    for (int s = 1; s < 32; s <<= 1) cnt += __shfl_xor(cnt, s, 64);
    if (cnt >= KG) done = 1;
  }

  // 32-way merge: 20 rounds of subgroup argmin over packed (d2,slot) keys.
  // Exactness guard: lane pops all KC entries OR rings exhausted -> exact fallback.
  int popc = 0, ovf = 0;
  for (int round = 0; round < KG; ++round) {
    unsigned long long key = ((unsigned long long)__float_as_uint(dist[0]) << 14) |
                             (unsigned long long)(unsigned)idx[0];
    unsigned long long m = key;
#pragma unroll
    for (int s = 1; s < 32; s <<= 1) {
      unsigned long long o = __shfl_xor(m, s, 64);
      if (o < m) m = o;
    }
    if (key == m) {
      nbr[(size_t)qs * KG + round] = (int)(m & 0x3FFF);
#pragma unroll
      for (int s = 0; s < KC - 1; ++s) { dist[s] = dist[s + 1]; idx[s] = idx[s + 1]; }
      dist[KC - 1] = 3.4e38f;
      idx[KC - 1] = 0;
      if (++popc == KC) ovf = 1;
    }
  }
#pragma unroll
  for (int s = 1; s < 32; s <<= 1) ovf |= __shfl_xor(ovf, s, 64);
  if ((ovf || !done) && sl == 0) {
    int s = atomicAdd(fb_count, 1);
    fb_list[s] = qs;
  }
}

// ---------------------------------------------------------------- brute-force fallback (slots)
__global__ __launch_bounds__(256) void knn_fb_kernel(const float4* __restrict__ sorted4,
                                                     const int* __restrict__ fb_list,
                                                     const int* __restrict__ fb_count,
                                                     int* __restrict__ nbr) {
  __shared__ unsigned long long lists[256 * KG];
  __shared__ unsigned long long heads[256];
  __shared__ unsigned long long winner;
  int tid = threadIdx.x;
  int cnt = *fb_count;
  for (int qi = blockIdx.x; qi < cnt; qi += gridDim.x) {
    int t = fb_list[qi];
    float4 p = sorted4[t];
    float dist[KG];
    int idx[KG];
#pragma unroll
    for (int i = 0; i < KG; ++i) { dist[i] = 3.4e38f; idx[i] = 0; }
    int j0 = tid * 64;
    for (int j = j0; j < j0 + 64; ++j) {
      float4 c = sorted4[j];
      float dx = c.x - p.x, dy = c.y - p.y, dz = c.z - p.z;
      float d2 = dx * dx + dy * dy + dz * dz;
      KNN_INSERT(d2, j);
    }
#pragma unroll
    for (int i = 0; i < KG; ++i)
      lists[tid * KG + i] = ((unsigned long long)__float_as_uint(dist[i]) << 22) |
                            ((unsigned long long)(unsigned)idx[i] << 8) |
                            (unsigned long long)tid;
    int hp = 0;
    __syncthreads();
    for (int round = 0; round < KG; ++round) {
      heads[tid] = (hp < KG) ? lists[tid * KG + hp] : ~0ull;
      __syncthreads();
      if (tid < 64) {
        unsigned long long m = heads[tid];
        unsigned long long o = heads[tid + 64];  if (o < m) m = o;
        o = heads[tid + 128]; if (o < m) m = o;
        o = heads[tid + 192]; if (o < m) m = o;
#pragma unroll
        for (int s = 32; s > 0; s >>= 1) {
          unsigned long long x = __shfl_xor(m, s, 64);
          if (x < m) m = x;
        }
        if (tid == 0) winner = m;
      }
      __syncthreads();
      unsigned long long w = winner;
      if (tid == (int)(w & 0xFF)) hp++;
      if (tid == 0) nbr[(size_t)t * KG + round] = (int)((w >> 8) & 0x3FFF);
      __syncthreads();
    }
  }
}

// ---------------------------------------------------- basis (sorted space, f32)
__global__ __launch_bounds__(256) void basis_kernel(const float4* __restrict__ sorted4,
                                                    const int* __restrict__ nbr,
                                                    float4* __restrict__ xb4,
                                                    float4* __restrict__ yb4) {
  int n = blockIdx.x * 256 + threadIdx.x;
  if (n >= NPTS) return;
  float4 p = sorted4[n];
  float c00 = 0, c01 = 0, c02 = 0, c11 = 0, c12 = 0, c22 = 0;
  for (int k = 0; k < KN; ++k) {
    int m = nbr[(size_t)n * KG + k];
    float4 pm = sorted4[m];
    float dx = pm.x - p.x, dy = pm.y - p.y, dz = pm.z - p.z;
    c00 += dx * dx; c01 += dx * dy; c02 += dx * dz;
    c11 += dy * dy; c12 += dy * dz; c22 += dz * dz;
  }
  float nx = 0.f, ny = 0.f, nz = 1.f;
  float p1 = c01 * c01 + c02 * c02 + c12 * c12;
  float qm = (c00 + c11 + c22) * (1.f / 3.f);
  float g0 = c00 - qm, g1 = c11 - qm, g2 = c22 - qm;
  float p2 = g0 * g0 + g1 * g1 + g2 * g2 + 2.f * p1;
  if (p2 > 1e-16f) {
    float pp = sqrtf(p2 * (1.f / 6.f));
    float inv = 1.f / pp;
    float b00 = g0 * inv, b11 = g1 * inv, b22 = g2 * inv;
    float b01 = c01 * inv, b02 = c02 * inv, b12 = c12 * inv;
    float detB = b00 * (b11 * b22 - b12 * b12) - b01 * (b01 * b22 - b12 * b02) +
                 b02 * (b01 * b12 - b11 * b02);
    float r = 0.5f * detB;
    r = fminf(1.f, fmaxf(-1.f, r));
    float phi = acosf(r) * (1.f / 3.f);
    float e1 = qm + 2.f * pp * __cosf(phi);
    float e3 = qm + 2.f * pp * __cosf(phi + 2.0943951023931953f);
    float e2 = 3.f * qm - e1 - e3;
    float a00 = c00 - e1, a11 = c11 - e1, a22 = c22 - e1;
    float f00 = c00 - e2, f11 = c11 - e2, f22 = c22 - e2;
    float u0 = a00 * f00 + c01 * c01 + c02 * c02;
    float u1 = c01 * f00 + a11 * c01 + c12 * c02;
    float u2 = c02 * f00 + c12 * c01 + a22 * c02;
    float v0 = a00 * c01 + c01 * f11 + c02 * c12;
    float v1 = c01 * c01 + a11 * f11 + c12 * c12;
    float v2 = c02 * c01 + c12 * f11 + a22 * c12;
    float w0 = a00 * c02 + c01 * c12 + c02 * f22;
    float w1 = c01 * c02 + a11 * c12 + c12 * f22;
    float w2 = c02 * c02 + c12 * c12 + a22 * f22;
    float nu = u0 * u0 + u1 * u1 + u2 * u2;
    float nv = v0 * v0 + v1 * v1 + v2 * v2;
    float nw = w0 * w0 + w1 * w1 + w2 * w2;
    float bx = u0, by = u1, bz = u2, bn = nu;
    if (nv > bn) { bx = v0; by = v1; bz = v2; bn = nv; }
    if (nw > bn) { bx = w0; by = w1; bz = w2; bn = nw; }
    if (bn > 1e-30f) {
      float s = 1.f / sqrtf(bn);
      nx = bx * s; ny = by * s; nz = bz * s;
    }
  }
  float dotp = nx * p.x + ny * p.y + nz * p.z;
  if (dotp < 0.f) { nx = -nx; ny = -ny; nz = -nz; }
  float ax = fabsf(nx), ay = fabsf(ny), az = fabsf(nz);
  float ex = 0.f, ey = 0.f, ez = 0.f;
  if (ax <= ay && ax <= az) ex = 1.f;
  else if (ay <= az) ey = 1.f;
  else ez = 1.f;
  float tx = ny * ez - nz * ey, ty = nz * ex - nx * ez, tz = nx * ey - ny * ex;
  float tn = 1.f / sqrtf(tx * tx + ty * ty + tz * tz);
  tx *= tn; ty *= tn; tz *= tn;
  float ux = ny * tz - nz * ty, uy = nz * tx - nx * tz, uz = nx * ty - ny * tx;
  xb4[n] = make_float4(tx, ty, tz, 0.f);
  yb4[n] = make_float4(ux, uy, uz, 0.f);
}

// --------------------------- Gx/Gy + C2 + v0 = grad(pos) (sorted space, f32)
__global__ __launch_bounds__(256) void graddiv_kernel(const float4* __restrict__ sorted4,
                                                      const int* __restrict__ nbr,
                                                      const float4* __restrict__ xb4,
                                                      const float4* __restrict__ yb4,
                                                      float* __restrict__ Gx,
                                                      float* __restrict__ Gy,
                                                      float2* __restrict__ C2,
                                                      float* __restrict__ v0) {
  int n = blockIdx.x * 256 + threadIdx.x;
  if (n >= NPTS) return;
  float4 p = sorted4[n], xb = xb4[n], yb = yb4[n];
  float u[KG], vv[KG], w[KG];
  int mm[KG];
  float hsum = 0.f;
#pragma unroll
  for (int k = 0; k < KG; ++k) {
    int m = nbr[(size_t)n * KG + k];
    mm[k] = m;
    float4 pm = sorted4[m];
    float rx = pm.x - p.x, ry = pm.y - p.y, rz = pm.z - p.z;
    u[k] = rx * xb.x + ry * xb.y + rz * xb.z;
    vv[k] = rx * yb.x + ry * yb.y + rz * yb.z;
    float dd = sqrtf(rx * rx + ry * ry + rz * rz + EPSF);
    w[k] = dd; hsum += dd;
  }
  float h = hsum * (1.f / KG);
  float invden = 1.f / (h * h + EPSF);
  float A00 = 0, A01 = 0, A02 = 0, A11 = 0, A12 = 0, A22 = 0;
#pragma unroll
  for (int k = 0; k < KG; ++k) {
    float wk = __expf(-(w[k] * w[k]) * invden);
    w[k] = wk;
    A00 += wk; A01 += wk * u[k]; A02 += wk * vv[k];
    A11 += wk * u[k] * u[k]; A12 += wk * u[k] * vv[k];
    A22 += wk * vv[k] * vv[k];
  }
  A00 += 0.001f; A11 += 0.001f; A22 += 0.001f;
  float det = A00 * (A11 * A22 - A12 * A12) - A01 * (A01 * A22 - A12 * A02) +
              A02 * (A01 * A12 - A11 * A02);
  float idet = 1.f / det;
  float i10 = (A02 * A12 - A01 * A22) * idet;
  float i11 = (A00 * A22 - A02 * A02) * idet;
  float i12 = (A01 * A02 - A00 * A12) * idet;
  float i20 = (A01 * A12 - A02 * A11) * idet;
  float i21 = i12;
  float i22 = (A00 * A11 - A01 * A01) * idet;
  float a0x = 0, a0y = 0, a0z = 0, a1x = 0, a1y = 0, a1z = 0;
#pragma unroll
  for (int k = 0; k < KG; ++k) {
    float gx = w[k] * (i10 + i11 * u[k] + i12 * vv[k]);
    float gy = w[k] * (i20 + i21 * u[k] + i22 * vv[k]);
    Gx[(size_t)n * KG + k] = gx;
    Gy[(size_t)n * KG + k] = gy;
    int m = mm[k];
    float4 pm = sorted4[m];
    a0x += gx * pm.x; a0y += gx * pm.y; a0z += gx * pm.z;
    a1x += gy * pm.x; a1y += gy * pm.y; a1z += gy * pm.z;
    float4 xm = xb4[m], ym = yb4[m];
    float g3x = gx * xb.x + gy * yb.x;
    float g3y = gx * xb.y + gy * yb.y;
    float g3z = gx * xb.z + gy * yb.z;
    float ca = g3x * xm.x + g3y * xm.y + g3z * xm.z;
    float cb = g3x * ym.x + g3y * ym.y + g3z * ym.z;
    C2[(size_t)n * KG + k] = make_float2(ca, cb);
  }
  v0[((size_t)n * 2 + 0) * 3 + 0] = a0x;
  v0[((size_t)n * 2 + 0) * 3 + 1] = a0y;
  v0[((size_t)n * 2 + 0) * 3 + 2] = a0z;
  v0[((size_t)n * 2 + 1) * 3 + 0] = a1x;
  v0[((size_t)n * 2 + 1) * 3 + 1] = a1y;
  v0[((size_t)n * 2 + 1) * 3 + 2] = a1z;
}

// ------------------------------------------------- feat scalar (layer 0, cin=3, f32 in)
template <int CENTRAL>
__global__ __launch_bounds__(256) void feat16_kernel(const float* __restrict__ x, int ldx,
                                                     int cin,
                                                     const float* __restrict__ v,
                                                     const int* __restrict__ nbr,
                                                     const float2* __restrict__ C2,
                                                     unsigned short* __restrict__ feat, int Kp) {
  int per = Kp - 2 * cin;
  int gid = blockIdx.x * 256 + threadIdx.x;
  if (gid >= NPTS * per) return;
  int n = gid / per;
  int c = gid - n * per;
  size_t fb = (size_t)n * Kp;
  if (c >= cin) {  // pad column
    feat[fb + 3 * cin + (c - cin)] = 0;
    return;
  }
  float xc = x[(size_t)n * ldx + c];
  float xmax = -3.4e38f, dv = 0.f, cv = 0.f;
  for (int k = 0; k < KG; ++k) {
    int m = nbr[(size_t)n * KG + k];
    float2 cc = C2[(size_t)n * KG + k];
    float xm = x[(size_t)m * ldx + c];
    xmax = fmaxf(xmax, CENTRAL ? (xm - xc) : xm);
    float va = v[((size_t)m * 2 + 0) * cin + c];
    float vb = v[((size_t)m * 2 + 1) * cin + c];
    dv += cc.x * va + cc.y * vb;
    cv += cc.y * va - cc.x * vb;
  }
  feat[fb + c] = f2bf(xmax);
  feat[fb + cin + c] = f2bf(dv);
  feat[fb + 2 * cin + c] = f2bf(cv);
}

// ----------------------- feat vectorized: bf16 x/v mirrors, 8 ch/thread,
// per-point nbr+C2 staged in LDS once per block (cin/8 divides 256 -> whole points per block)
__global__ __launch_bounds__(256) void feat16v8_kernel(const unsigned short* __restrict__ x,
                                                       int cin,
                                                       const unsigned short* __restrict__ v,
                                                       const int* __restrict__ nbr,
                                                       const float2* __restrict__ C2,
                                                       unsigned short* __restrict__ feat) {
  __shared__ int s_nbr[32 * KG];
  __shared__ float2 s_c2[32 * KG];
  int per = cin >> 3;            // 8 (cin=64) or 16 (cin=128)
  int ppb = 256 / per;           // 32 or 16 points per block (divides NPTS)
  int pbase = blockIdx.x * ppb;
  for (int i = threadIdx.x; i < ppb * KG; i += 256) {
    int pl = i / KG;
    int kk = i - pl * KG;
    size_t src = (size_t)(pbase + pl) * KG + kk;
    s_nbr[i] = nbr[src];
    s_c2[i] = C2[src];
  }
  __syncthreads();
  int nl = threadIdx.x / per;    // local point
  int n = pbase + nl;
  int c8 = (threadIdx.x - nl * per) << 3;
  float xmax[8], dv[8], cv[8];
#pragma unroll
  for (int i = 0; i < 8; ++i) { xmax[i] = -3.4e38f; dv[i] = 0.f; cv[i] = 0.f; }
  const int* nrow = s_nbr + nl * KG;
  const float2* crow = s_c2 + nl * KG;
#pragma unroll 4
  for (int k = 0; k < KG; ++k) {
    int m = nrow[k];
    float2 cc = crow[k];
    short8v xm = *reinterpret_cast<const short8v*>(x + (size_t)m * cin + c8);
    short8v va = *reinterpret_cast<const short8v*>(v + ((size_t)m * 2 + 0) * cin + c8);
    short8v vb = *reinterpret_cast<const short8v*>(v + ((size_t)m * 2 + 1) * cin + c8);
#pragma unroll
    for (int i = 0; i < 8; ++i) {
      float xf = bf2f((unsigned short)xm[i]);
      float af = bf2f((unsigned short)va[i]);
      float bf = bf2f((unsigned short)vb[i]);
      xmax[i] = fmaxf(xmax[i], xf);
      dv[i] += cc.x * af + cc.y * bf;
      cv[i] += cc.y * af - cc.x * bf;
    }
  }
  size_t fb = (size_t)n * (3 * cin);
  short8v o0, o1, o2;
#pragma unroll
  for (int i = 0; i < 8; ++i) {
    o0[i] = (short)f2bf(xmax[i]);
    o1[i] = (short)f2bf(dv[i]);
    o2[i] = (short)f2bf(cv[i]);
  }
  *reinterpret_cast<short8v*>(&feat[fb + c8]) = o0;
  *reinterpret_cast<short8v*>(&feat[fb + cin + c8]) = o1;
  *reinterpret_cast<short8v*>(&feat[fb + 2 * cin + c8]) = o2;
}

// ------------------------------------------------- vin scalar (layer 0, Kp=96, cin=3)
__global__ __launch_bounds__(256) void vin16_kernel(const float* __restrict__ v, int cin,
                                                    const unsigned short* __restrict__ xout,
                                                    int cout,
                                                    const int* __restrict__ nbr,
                                                    const float* __restrict__ Gx,
                                                    const float* __restrict__ Gy,
                                                    unsigned short* __restrict__ vinb, int Kp,
                                                    int total) {
  int gid = blockIdx.x * 256 + threadIdx.x;
  if (gid >= total) return;
  int n = gid / Kp;
  int c = gid - n * Kp;
  int K = cin + cout;
  unsigned short o0, o1;
  if (c < cin) {
    o0 = f2bf(v[((size_t)n * 2 + 0) * cin + c]);
    o1 = f2bf(v[((size_t)n * 2 + 1) * cin + c]);
  } else if (c < K) {
    int cc = c - cin;
    float a0 = 0.f, a1 = 0.f;
    for (int k = 0; k < KG; ++k) {
      int m = nbr[(size_t)n * KG + k];
      float f = bf2f(xout[(size_t)m * cout + cc]);
      a0 += Gx[(size_t)n * KG + k] * f;
      a1 += Gy[(size_t)n * KG + k] * f;
    }
    o0 = f2bf(a0);
    o1 = f2bf(a1);
  } else {
    o0 = 0; o1 = 0;
  }
  vinb[((size_t)n * 2 + 0) * Kp + c] = o0;
  vinb[((size_t)n * 2 + 1) * Kp + c] = o1;
}

// ----------------------- vin vectorized: bf16 v + bf16 xout mirror, 8 ch/thread
__global__ __launch_bounds__(256) void vin16v8_kernel(const unsigned short* __restrict__ v,
                                                      int cin,
                                                      const unsigned short* __restrict__ xout,
                                                      int cout,
                                                      const int* __restrict__ nbr,
                                                      const float* __restrict__ Gx,
                                                      const float* __restrict__ Gy,
                                                      unsigned short* __restrict__ vinb,
                                                      int Kp) {
  int per = Kp >> 3;
  int gid = blockIdx.x * 256 + threadIdx.x;
  if (gid >= NPTS * per) return;
  int n = gid / per;
  int c8 = (gid - n * per) << 3;
  short8v o0, o1;
  if (c8 < cin) {
    o0 = *reinterpret_cast<const short8v*>(v + ((size_t)n * 2 + 0) * cin + c8);
    o1 = *reinterpret_cast<const short8v*>(v + ((size_t)n * 2 + 1) * cin + c8);
  } else {
    int cc8 = c8 - cin;
    float a0[8], a1[8];
#pragma unroll
    for (int i = 0; i < 8; ++i) { a0[i] = 0.f; a1[i] = 0.f; }
    const int* nrow = nbr + (size_t)n * KG;
    const float* gxr = Gx + (size_t)n * KG;
    const float* gyr = Gy + (size_t)n * KG;
#pragma unroll 4
    for (int k = 0; k < KG; ++k) {
      int m = nrow[k];
      float gx = gxr[k], gy = gyr[k];
      short8v f = *reinterpret_cast<const short8v*>(xout + (size_t)m * cout + cc8);
#pragma unroll
      for (int i = 0; i < 8; ++i) {
        float ff = bf2f((unsigned short)f[i]);
        a0[i] += gx * ff;
        a1[i] += gy * ff;
      }
    }
#pragma unroll
    for (int i = 0; i < 8; ++i) {
      o0[i] = (short)f2bf(a0[i]);
      o1[i] = (short)f2bf(a1[i]);
    }
  }
  *reinterpret_cast<short8v*>(&vinb[((size_t)n * 2 + 0) * Kp + c8]) = o0;
  *reinterpret_cast<short8v*>(&vinb[((size_t)n * 2 + 1) * Kp + c8]) = o1;
}

// ------------------------------------------------- bf16 MFMA GEMM
// MODE 0: Cf[rowmap[row]] = relu(A@B+bias) f32 (+ optional bf16 mirror Cb[row], sorted).
// MODE 1: normgate over row pairs, bf16 output to Cb only (sorted rows).
template <int MODE>
__global__ __launch_bounds__(256) void gemm16_kernel(const unsigned short* __restrict__ A,
                                                     const unsigned short* __restrict__ Bt,
                                                     const float* __restrict__ bias,
                                                     float* __restrict__ Cf,
                                                     unsigned short* __restrict__ Cb,
                                                     const int* __restrict__ rowmap,
                                                     int Kp, int Ncol) {
  int lane = threadIdx.x & 63;
  int wave = threadIdx.x >> 6;
  int rowBase = blockIdx.y * 64 + wave * 16;
  int colBase = blockIdx.x * 64;
  int lr = lane & 15;
  int kg = (lane >> 4) * 8;
  floatx4 acc0 = {0.f, 0.f, 0.f, 0.f};
  floatx4 acc1 = acc0, acc2 = acc0, acc3 = acc0;
  const unsigned short* arow = A + (size_t)(rowBase + lr) * Kp + kg;
  const unsigned short* b0p = Bt + (size_t)(colBase + lr) * Kp + kg;
  for (int k0 = 0; k0 < Kp; k0 += 32) {
    short8v a = *reinterpret_cast<const short8v*>(arow + k0);
    short8v b0 = *reinterpret_cast<const short8v*>(b0p + k0);
    short8v b1 = *reinterpret_cast<const short8v*>(b0p + (size_t)16 * Kp + k0);
    short8v b2 = *reinterpret_cast<const short8v*>(b0p + (size_t)32 * Kp + k0);
    short8v b3 = *reinterpret_cast<const short8v*>(b0p + (size_t)48 * Kp + k0);
    acc0 = __builtin_amdgcn_mfma_f32_16x16x32_bf16(a, b0, acc0, 0, 0, 0);
    acc1 = __builtin_amdgcn_mfma_f32_16x16x32_bf16(a, b1, acc1, 0, 0, 0);
    acc2 = __builtin_amdgcn_mfma_f32_16x16x32_bf16(a, b2, acc2, 0, 0, 0);
    acc3 = __builtin_amdgcn_mfma_f32_16x16x32_bf16(a, b3, acc3, 0, 0, 0);
  }
  int rsub = (lane >> 4) * 4;
  floatx4 accs[4] = {acc0, acc1, acc2, acc3};
  int orow[4];
  if (MODE == 0) {
#pragma unroll
    for (int r = 0; r < 4; ++r) orow[r] = rowmap[rowBase + rsub + r];
  }
#pragma unroll
  for (int nb = 0; nb < 4; ++nb) {
    int col = colBase + nb * 16 + lr;
    float bb = bias[col];
    if (MODE == 0) {
#pragma unroll
      for (int r = 0; r < 4; ++r) {
        int row = rowBase + rsub + r;
        float val = fmaxf(accs[nb][r] + bb, 0.f);
        Cf[(size_t)orow[r] * Ncol + col] = val;
        if (Cb) Cb[(size_t)row * Ncol + col] = f2bf(val);
      }
    } else {
#pragma unroll
      for (int pr = 0; pr < 2; ++pr) {
        float a0 = accs[nb][2 * pr], a1 = accs[nb][2 * pr + 1];
        float nrm = sqrtf(a0 * a0 + a1 * a1 + EPSF);
        float s = fmaxf(nrm + bb, 0.f) / (nrm + EPSF);
        int row = rowBase + rsub + 2 * pr;
        Cb[(size_t)row * Ncol + col] = f2bf(a0 * s);
        Cb[(size_t)(row + 1) * Ncol + col] = f2bf(a1 * s);
      }
    }
  }
}

// ---------------------------------------------------------------- launch
extern "C" void kernel_launch(void* const* d_in, const int* in_sizes, int n_in,
                              void* d_out, int out_size, void* d_ws, size_t ws_size,
                              hipStream_t stream) {
  const float* pts = (const float*)d_in[0];
  const float* als = (const float*)d_in[1];
  const float* Ws0 = (const float*)d_in[2];
  const float* bs0 = (const float*)d_in[3];
  const float* Wv0 = (const float*)d_in[4];
  const float* bv0 = (const float*)d_in[5];
  const float* Ws1 = (const float*)d_in[6];
  const float* bs1 = (const float*)d_in[7];
  const float* Wv1 = (const float*)d_in[8];
  const float* bv1 = (const float*)d_in[9];
  const float* Ws2 = (const float*)d_in[10];
  const float* bs2 = (const float*)d_in[11];

  char* ws = (char*)d_ws;
  float4* pos4 = (float4*)(ws + 0);               //  256 KB (original order, staging)
  int* nbr = (int*)(ws + 262144);                 // 1.31 MB (sorted-slot space)
  float4* xb4 = (float4*)(ws + 1572864);          //  256 KB (sorted)
  float4* yb4 = (float4*)(ws + 1835008);          //  256 KB (sorted)
  float* Gx = (float*)(ws + 2097152);             // 1.31 MB (sorted)
  float* Gy = (float*)(ws + 3407872);             // 1.31 MB (sorted)
  float2* C2 = (float2*)(ws + 4718592);           // 2.62 MB (sorted)
  float* v0f = (float*)(ws + 7340032);            //  393 KB (sorted)
  unsigned short* vb_a = (unsigned short*)(ws + 8388608);    // 8.39 MB (sorted)
  unsigned short* vb_b = (unsigned short*)(ws + 17825792);   // 4.19 MB (sorted)
  unsigned short* xb0m = (unsigned short*)(ws + 23068672);   // 2.10 MB (sorted)
  unsigned short* xb1m = (unsigned short*)(ws + 26214400);   // 4.19 MB (sorted)
  unsigned short* stg = (unsigned short*)(ws + 31457280);    // 12.6 MB (sorted)
  char* wtb = ws + 45088768;                      // transposed bf16 weights (~311 KB)
  unsigned short* Wt_s0 = (unsigned short*)(wtb + 0);
  unsigned short* Wt_v0 = (unsigned short*)(wtb + 4096);
  unsigned short* Wt_s1 = (unsigned short*)(wtb + 16384);
  unsigned short* Wt_v1 = (unsigned short*)(wtb + 65536);
  unsigned short* Wt_s2 = (unsigned short*)(wtb + 114688);

  char* gws = ws + 46137344;                      // knn scratch
  int* cell_count = (int*)(gws + 0);              // 128 KB
  int* fb_count = (int*)(gws + 131072);           // 4 B (memset together with cell_count)
  int* cell_start = (int*)(gws + 135168);         // 128 KB
  int* cell_cursor = (int*)(gws + 266240);        // 128 KB
  int* pt_cell = (int*)(gws + 397312);            // 64 KB
  int* fb_list = (int*)(gws + 462848);            // 64 KB
  float4* sorted4 = (float4*)(gws + 532480);      // 256 KB
  int* sortmap = (int*)(gws + 794624);            // 64 KB (slot -> original row)

  float* out0 = (float*)d_out;             // (N,64) original order
  float* out1 = out0 + (size_t)NPTS * 64;  // (N,128)
  float* out2 = out1 + (size_t)NPTS * 128; // (N,256)

  hipMemsetAsync(cell_count, 0, 131072 + 4, stream);  // cell_count + fb_count
  posbin_wprep_kernel<<<672, 256, 0, stream>>>(pts, als, pos4, cell_count, pt_cell, Ws0, Wv0,
                                               Ws1, Wv1, Ws2, Wt_s0, Wt_v0, Wt_s1, Wt_v1,
                                               Wt_s2);
  scan_kernel<<<1, 1024, 0, stream>>>(cell_count, cell_start, cell_cursor);
  scatter_kernel<<<64, 256, 0, stream>>>(pos4, pt_cell, cell_cursor, sorted4, sortmap);
  knn_grid_kernel<<<NPTS / 8, 256, 0, stream>>>(sorted4, cell_start, cell_count, nbr, fb_list,
                                                fb_count);
  knn_fb_kernel<<<128, 256, 0, stream>>>(sorted4, fb_list, fb_count, nbr);

  basis_kernel<<<64, 256, 0, stream>>>(sorted4, nbr, xb4, yb4);
  graddiv_kernel<<<64, 256, 0, stream>>>(sorted4, nbr, xb4, yb4, Gx, Gy, C2, v0f);

  // ---- layer 0 (cin=3 -> cout=64, centralized), all in sorted space
  feat16_kernel<1><<<(NPTS * 26 + 255) / 256, 256, 0, stream>>>((const float*)sorted4, 4, 3,
                                                                v0f, nbr, C2, stg, 32);
  gemm16_kernel<0><<<dim3(1, 256), 256, 0, stream>>>(stg, Wt_s0, bs0, out0, xb0m, sortmap, 32,
                                                     64);
  vin16_kernel<<<(NPTS * 96 + 255) / 256, 256, 0, stream>>>(v0f, 3, xb0m, 64, nbr, Gx, Gy, stg,
                                                            96, NPTS * 96);
  gemm16_kernel<1><<<dim3(1, 512), 256, 0, stream>>>(stg, Wt_v0, bv0, nullptr, vb_b, nullptr,
                                                     96, 64);

  // ---- layer 1 (cin=64 -> cout=128)
  feat16v8_kernel<<<NPTS * 8 / 256, 256, 0, stream>>>(xb0m, 64, vb_b, nbr, C2, stg);
  gemm16_kernel<0><<<dim3(2, 256), 256, 0, stream>>>(stg, Wt_s1, bs1, out1, xb1m, sortmap, 192,
                                                     128);
  vin16v8_kernel<<<NPTS * 24 / 256, 256, 0, stream>>>(vb_b, 64, xb1m, 128, nbr, Gx, Gy, stg,
                                                      192);
  gemm16_kernel<1><<<dim3(2, 512), 256, 0, stream>>>(stg, Wt_v1, bv1, nullptr, vb_a, nullptr,
                                                     192, 128);

  // ---- layer 2 (cin=128 -> cout=256, no vector update)
  feat16v8_kernel<<<NPTS * 16 / 256, 256, 0, stream>>>(xb1m, 128, vb_a, nbr, C2, stg);
  gemm16_kernel<0><<<dim3(4, 256), 256, 0, stream>>>(stg, Wt_s2, bs2, out2, nullptr, sortmap,
                                                     384, 256);
}

// Round 17
// 285.292 us; speedup vs baseline: 1.4682x; 1.0104x over previous
//
#include <hip/hip_runtime.h>
#include <math.h>

#define NPTS 16384
#define KG 20
#define KN 10
#define KC 6
#define EPSF 1e-8f

#define GDIM 32
#define GL 4.75f
#define CW 0.296875f
#define GINV 3.3684210526f
#define RMAX 6

typedef __attribute__((ext_vector_type(8))) short short8v;
typedef __attribute__((ext_vector_type(4))) float floatx4;

__device__ __forceinline__ unsigned short f2bf(float v) {
  union { float f; unsigned u; } x;
  x.f = v;
  unsigned r = x.u + 0x7FFFu + ((x.u >> 16) & 1u);  // RNE (finite inputs)
  return (unsigned short)(r >> 16);
}

__device__ __forceinline__ float bf2f(unsigned short u) {
  union { unsigned u32; float f; } x;
  x.u32 = (unsigned)u << 16;
  return x.f;
}

// sorted insert into KG-register list (strict <, stable by scan order)
#define KNN_INSERT(d2v, iv)                                                 \
  if ((d2v) < dist[KG - 1]) {                                               \
    dist[KG - 1] = (d2v); idx[KG - 1] = (iv);                               \
    _Pragma("unroll")                                                       \
    for (int s_ = KG - 1; s_ > 0; --s_) {                                   \
      if (dist[s_] < dist[s_ - 1]) {                                        \
        float td_ = dist[s_]; dist[s_] = dist[s_ - 1]; dist[s_ - 1] = td_;  \
        int ti_ = idx[s_]; idx[s_] = idx[s_ - 1]; idx[s_ - 1] = ti_;        \
      }                                                                     \
    }                                                                       \
  }

// sorted insert into KC-register list
#define KNN_INSERTC(d2v, iv)                                                \
  if ((d2v) < dist[KC - 1]) {                                               \
    dist[KC - 1] = (d2v); idx[KC - 1] = (iv);                               \
    _Pragma("unroll")                                                       \
    for (int s_ = KC - 1; s_ > 0; --s_) {                                   \
      if (dist[s_] < dist[s_ - 1]) {                                        \
        float td_ = dist[s_]; dist[s_] = dist[s_ - 1]; dist[s_ - 1] = td_;  \
        int ti_ = idx[s_]; idx[s_] = idx[s_ - 1]; idx[s_ - 1] = ti_;        \
      }                                                                     \
    }                                                                       \
  }

__device__ __forceinline__ int cell_of(float x) {
  int c = (int)floorf((x + GL) * GINV);
  return min(max(c, 0), GDIM - 1);
}

// ---------------- pos concat + bin (blocks 0..63) fused with weight prep (blocks 64..671)
__device__ __forceinline__ void wprep_one(const float* W, unsigned short* Wt, int K, int Kp,
                                          int N, int i) {
  int n = i / Kp, k = i - n * Kp;
  Wt[i] = (k < K) ? f2bf(W[(size_t)k * N + n]) : (unsigned short)0;
}

__global__ __launch_bounds__(256) void posbin_wprep_kernel(
    const float* __restrict__ pts, const float* __restrict__ als, float4* __restrict__ pos4,
    int* __restrict__ cell_count, int* __restrict__ pt_cell,
    const float* __restrict__ Ws0, const float* __restrict__ Wv0,
    const float* __restrict__ Ws1, const float* __restrict__ Wv1,
    const float* __restrict__ Ws2, unsigned short* __restrict__ Wt_s0,
    unsigned short* __restrict__ Wt_v0, unsigned short* __restrict__ Wt_s1,
    unsigned short* __restrict__ Wt_v1, unsigned short* __restrict__ Wt_s2) {
  if (blockIdx.x < 64) {
    int n = blockIdx.x * 256 + threadIdx.x;
    if (n >= NPTS) return;
    const float* src = (n < 8192) ? (pts + (size_t)n * 3) : (als + (size_t)(n - 8192) * 3);
    float x = src[0], y = src[1], z = src[2];
    pos4[n] = make_float4(x, y, z, 0.f);
    int c = (cell_of(z) * GDIM + cell_of(y)) * GDIM + cell_of(x);
    pt_cell[n] = c;
    atomicAdd(&cell_count[c], 1);
  } else {
    int gid = (blockIdx.x - 64) * 256 + threadIdx.x;
    if (gid < 2048) wprep_one(Ws0, Wt_s0, 9, 32, 64, gid);
    else if (gid < 8192) wprep_one(Wv0, Wt_v0, 67, 96, 64, gid - 2048);
    else if (gid < 32768) wprep_one(Ws1, Wt_s1, 192, 192, 128, gid - 8192);
    else if (gid < 57344) wprep_one(Wv1, Wt_v1, 192, 192, 128, gid - 32768);
    else if (gid < 155648) wprep_one(Ws2, Wt_s2, 384, 384, 256, gid - 57344);
  }
}

__global__ __launch_bounds__(1024) void scan_kernel(const int* __restrict__ cell_count,
                                                    int* __restrict__ cell_start,
                                                    int* __restrict__ cell_cursor) {
  __shared__ int s[1024];
  int tid = threadIdx.x;
  int base = tid * 32;
  int local[32];
  int sum = 0;
#pragma unroll
  for (int i = 0; i < 32; ++i) { local[i] = cell_count[base + i]; sum += local[i]; }
  s[tid] = sum;
  __syncthreads();
  for (int off = 1; off < 1024; off <<= 1) {
    int v = (tid >= off) ? s[tid - off] : 0;
    __syncthreads();
    s[tid] += v;
    __syncthreads();
  }
  int run = s[tid] - sum;  // exclusive prefix
#pragma unroll
  for (int i = 0; i < 32; ++i) {
    cell_start[base + i] = run;
    cell_cursor[base + i] = run;
    run += local[i];
  }
}

// scatter into sorted order; sortmap[slot] = original index
__global__ __launch_bounds__(256) void scatter_kernel(const float4* __restrict__ pos4,
                                                      const int* __restrict__ pt_cell,
                                                      int* __restrict__ cell_cursor,
                                                      float4* __restrict__ sorted4,
                                                      int* __restrict__ sortmap) {
  int i = blockIdx.x * 256 + threadIdx.x;
  if (i >= NPTS) return;
  int c = pt_cell[i];
  int dst = atomicAdd(&cell_cursor[c], 1);
  float4 p = pos4[i];
  p.w = __int_as_float(i);
  sorted4[dst] = p;
  sortmap[dst] = i;
}

// --------- grid knn in SORTED-SLOT space: 2 queries/wave, 32 lanes each, cap-KC.
__global__ __launch_bounds__(256) void knn_grid_kernel(const float4* __restrict__ sorted4,
                                                       const int* __restrict__ cell_start,
                                                       const int* __restrict__ cell_count,
                                                       int* __restrict__ nbr,
                                                       int* __restrict__ fb_list,
                                                       int* __restrict__ fb_count) {
  int lane = threadIdx.x & 63;
  int sub = lane >> 5;   // 2 query subgroups per wave
  int sl = lane & 31;    // lane within subgroup
  int qs = blockIdx.x * 8 + (threadIdx.x >> 6) * 2 + sub;  // sorted-order query slot
  if (qs >= NPTS) return;
  float4 p = sorted4[qs];
  int cx = cell_of(p.x), cy = cell_of(p.y), cz = cell_of(p.z);
  float dist[KC];
  int idx[KC];
#pragma unroll
  for (int i = 0; i < KC; ++i) { dist[i] = 3.4e38f; idx[i] = 0; }

  // ---- phase 1: full box r<=1, continuous round-robin, 2-way unrolled for ILP
  {
    int tot = 0;
    int x0 = max(cx - 1, 0), x1 = min(cx + 1, GDIM - 1);
    int zlo = max(cz - 1, 0), zhi = min(cz + 1, GDIM - 1);
    int ylo = max(cy - 1, 0), yhi = min(cy + 1, GDIM - 1);
    for (int z = zlo; z <= zhi; ++z) {
      for (int y = ylo; y <= yhi; ++y) {
        int c0 = (z * GDIM + y) * GDIM + x0;
        int c1 = (z * GDIM + y) * GDIM + x1;
        int beg = cell_start[c0];
        int end = cell_start[c1] + cell_count[c1];
        int off = (sl - tot) & 31;
        for (int j = beg + off; j < end; j += 64) {
          int j1 = j + 32;
          float4 sp0 = sorted4[j];
          float4 sp1 = sorted4[(j1 < end) ? j1 : j];
          float dx0 = sp0.x - p.x, dy0 = sp0.y - p.y, dz0 = sp0.z - p.z;
          float d20 = dx0 * dx0 + dy0 * dy0 + dz0 * dz0;
          float dx1 = sp1.x - p.x, dy1 = sp1.y - p.y, dz1 = sp1.z - p.z;
          float d21 = dx1 * dx1 + dy1 * dy1 + dz1 * dz1;
          KNN_INSERTC(d20, j);
          if (j1 < end) { KNN_INSERTC(d21, j1); }
        }
        tot += end - beg;
      }
    }
  }
  int done;
  {
    float b2 = CW * CW;
    int cnt = 0;
#pragma unroll
    for (int i = 0; i < KC; ++i) cnt += (dist[i] <= b2) ? 1 : 0;
#pragma unroll
    for (int s = 1; s < 32; s <<= 1) cnt += __shfl_xor(cnt, s, 64);
    done = (cnt >= KG) ? 1 : 0;
  }

  // ---- phase 2: rings r=2..RMAX, lane-per-segment over 32 lanes
  for (int r = 2; r <= RMAX && !done; ++r) {
    int side = 2 * r + 1;
    int nt = side * side;
    float rcp = 1.0f / (float)side;
    for (int t = sl; t < nt; t += 32) {
      int qz = (int)(((float)t + 0.5f) * rcp);  // exact floor(t/side) for t<169
      int dz = qz - r;
      int dy = t - qz * side - r;
      int z = cz + dz, y = cy + dy;
      if (z < 0 || z >= GDIM || y < 0 || y >= GDIM) continue;
      int rowbase = (z * GDIM + y) * GDIM;
      if (dz == -r || dz == r || dy == -r || dy == r) {
        int xa = max(cx - r, 0), xb = min(cx + r, GDIM - 1);
        int beg = cell_start[rowbase + xa];
        int end = cell_start[rowbase + xb] + cell_count[rowbase + xb];
        for (int j = beg; j < end; ++j) {
          float4 sp = sorted4[j];
          float ddx = sp.x - p.x, ddy = sp.y - p.y, ddz = sp.z - p.z;
          float d2 = ddx * ddx + ddy * ddy + ddz * ddz;
          KNN_INSERTC(d2, j);
        }
      } else {
        int x = cx - r;
        if (x >= 0) {
          int c = rowbase + x;
          int beg = cell_start[c], end = beg + cell_count[c];
          for (int j = beg; j < end; ++j) {
            float4 sp = sorted4[j];
            float ddx = sp.x - p.x, ddy = sp.y - p.y, ddz = sp.z - p.z;
            float d2 = ddx * ddx + ddy * ddy + ddz * ddz;
            KNN_INSERTC(d2, j);
          }
        }
        x = cx + r;
        if (x < GDIM) {
          int c = rowbase + x;
          int beg = cell_start[c], end = beg + cell_count[c];
          for (int j = beg; j < end; ++j) {
            float4 sp = sorted4[j];
            float ddx = sp.x - p.x, ddy = sp.y - p.y, ddz = sp.z - p.z;
            float d2 = ddx * ddx + ddy * ddy + ddz * ddz;
            KNN_INSERTC(d2, j);
          }
        }
      }
    }
    float b = CW * (float)r;
    float b2 = b * b;
    int cnt = 0;
#pragma unroll
    for (int i = 0; i < KC; ++i) cnt += (dist[i] <= b2) ? 1 : 0;
#pragma unroll
    for (int s = 1; s < 32; s <<= 1) cnt += __shfl_xor(cnt, s, 64);
    if (cnt >= KG) done = 1;
  }

  // 32-way merge: 20 rounds of f32 min-reduce + ballot winner (lowest lane pops & writes).
  // Tie-break = lowest lane (deterministic; differs from slot order only on exact f32 ties).
  // Exactness guard: lane pops all KC entries OR rings exhausted -> exact fallback.
  int popc = 0, ovf = 0;
  for (int round = 0; round < KG; ++round) {
    float m = dist[0];
#pragma unroll
    for (int s = 1; s < 32; s <<= 1) m = fminf(m, __shfl_xor(m, s, 64));
    unsigned long long vote = __ballot(dist[0] == m);
    unsigned msk = (unsigned)(vote >> (sub << 5));
    int wl = __ffs(msk) - 1;
    if (sl == wl) {
      nbr[(size_t)qs * KG + round] = idx[0];
#pragma unroll
      for (int s = 0; s < KC - 1; ++s) { dist[s] = dist[s + 1]; idx[s] = idx[s + 1]; }
      dist[KC - 1] = 3.4e38f;
      idx[KC - 1] = 0;
      if (++popc == KC) ovf = 1;
    }
  }
#pragma unroll
  for (int s = 1; s < 32; s <<= 1) ovf |= __shfl_xor(ovf, s, 64);
  if ((ovf || !done) && sl == 0) {
    int s = atomicAdd(fb_count, 1);
    fb_list[s] = qs;
  }
}

// ---------------------------------------------------------------- brute-force fallback (slots)
__global__ __launch_bounds__(256) void knn_fb_kernel(const float4* __restrict__ sorted4,
                                                     const int* __restrict__ fb_list,
                                                     const int* __restrict__ fb_count,
                                                     int* __restrict__ nbr) {
  __shared__ unsigned long long lists[256 * KG];
  __shared__ unsigned long long heads[256];
  __shared__ unsigned long long winner;
  int tid = threadIdx.x;
  int cnt = *fb_count;
  for (int qi = blockIdx.x; qi < cnt; qi += gridDim.x) {
    int t = fb_list[qi];
    float4 p = sorted4[t];
    float dist[KG];
    int idx[KG];
#pragma unroll
    for (int i = 0; i < KG; ++i) { dist[i] = 3.4e38f; idx[i] = 0; }
    int j0 = tid * 64;
    for (int j = j0; j < j0 + 64; ++j) {
      float4 c = sorted4[j];
      float dx = c.x - p.x, dy = c.y - p.y, dz = c.z - p.z;
      float d2 = dx * dx + dy * dy + dz * dz;
      KNN_INSERT(d2, j);
    }
#pragma unroll
    for (int i = 0; i < KG; ++i)
      lists[tid * KG + i] = ((unsigned long long)__float_as_uint(dist[i]) << 22) |
                            ((unsigned long long)(unsigned)idx[i] << 8) |
                            (unsigned long long)tid;
    int hp = 0;
    __syncthreads();
    for (int round = 0; round < KG; ++round) {
      heads[tid] = (hp < KG) ? lists[tid * KG + hp] : ~0ull;
      __syncthreads();
      if (tid < 64) {
        unsigned long long m = heads[tid];
        unsigned long long o = heads[tid + 64];  if (o < m) m = o;
        o = heads[tid + 128]; if (o < m) m = o;
        o = heads[tid + 192]; if (o < m) m = o;
#pragma unroll
        for (int s = 32; s > 0; s >>= 1) {
          unsigned long long x = __shfl_xor(m, s, 64);
          if (x < m) m = x;
        }
        if (tid == 0) winner = m;
      }
      __syncthreads();
      unsigned long long w = winner;
      if (tid == (int)(w & 0xFF)) hp++;
      if (tid == 0) nbr[(size_t)t * KG + round] = (int)((w >> 8) & 0x3FFF);
      __syncthreads();
    }
  }
}

// ---------------------------------------------------- basis (sorted space, f32)
__global__ __launch_bounds__(256) void basis_kernel(const float4* __restrict__ sorted4,
                                                    const int* __restrict__ nbr,
                                                    float4* __restrict__ xb4,
                                                    float4* __restrict__ yb4) {
  int n = blockIdx.x * 256 + threadIdx.x;
  if (n >= NPTS) return;
  float4 p = sorted4[n];
  float c00 = 0, c01 = 0, c02 = 0, c11 = 0, c12 = 0, c22 = 0;
  for (int k = 0; k < KN; ++k) {
    int m = nbr[(size_t)n * KG + k];
    float4 pm = sorted4[m];
    float dx = pm.x - p.x, dy = pm.y - p.y, dz = pm.z - p.z;
    c00 += dx * dx; c01 += dx * dy; c02 += dx * dz;
    c11 += dy * dy; c12 += dy * dz; c22 += dz * dz;
  }
  float nx = 0.f, ny = 0.f, nz = 1.f;
  float p1 = c01 * c01 + c02 * c02 + c12 * c12;
  float qm = (c00 + c11 + c22) * (1.f / 3.f);
  float g0 = c00 - qm, g1 = c11 - qm, g2 = c22 - qm;
  float p2 = g0 * g0 + g1 * g1 + g2 * g2 + 2.f * p1;
  if (p2 > 1e-16f) {
    float pp = sqrtf(p2 * (1.f / 6.f));
    float inv = 1.f / pp;
    float b00 = g0 * inv, b11 = g1 * inv, b22 = g2 * inv;
    float b01 = c01 * inv, b02 = c02 * inv, b12 = c12 * inv;
    float detB = b00 * (b11 * b22 - b12 * b12) - b01 * (b01 * b22 - b12 * b02) +
                 b02 * (b01 * b12 - b11 * b02);
    float r = 0.5f * detB;
    r = fminf(1.f, fmaxf(-1.f, r));
    float phi = acosf(r) * (1.f / 3.f);
    float e1 = qm + 2.f * pp * __cosf(phi);
    float e3 = qm + 2.f * pp * __cosf(phi + 2.0943951023931953f);
    float e2 = 3.f * qm - e1 - e3;
    float a00 = c00 - e1, a11 = c11 - e1, a22 = c22 - e1;
    float f00 = c00 - e2, f11 = c11 - e2, f22 = c22 - e2;
    float u0 = a00 * f00 + c01 * c01 + c02 * c02;
    float u1 = c01 * f00 + a11 * c01 + c12 * c02;
    float u2 = c02 * f00 + c12 * c01 + a22 * c02;
    float v0 = a00 * c01 + c01 * f11 + c02 * c12;
    float v1 = c01 * c01 + a11 * f11 + c12 * c12;
    float v2 = c02 * c01 + c12 * f11 + a22 * c12;
    float w0 = a00 * c02 + c01 * c12 + c02 * f22;
    float w1 = c01 * c02 + a11 * c12 + c12 * f22;
    float w2 = c02 * c02 + c12 * c12 + a22 * f22;
    float nu = u0 * u0 + u1 * u1 + u2 * u2;
    float nv = v0 * v0 + v1 * v1 + v2 * v2;
    float nw = w0 * w0 + w1 * w1 + w2 * w2;
    float bx = u0, by = u1, bz = u2, bn = nu;
    if (nv > bn) { bx = v0; by = v1; bz = v2; bn = nv; }
    if (nw > bn) { bx = w0; by = w1; bz = w2; bn = nw; }
    if (bn > 1e-30f) {
      float s = 1.f / sqrtf(bn);
      nx = bx * s; ny = by * s; nz = bz * s;
    }
  }
  float dotp = nx * p.x + ny * p.y + nz * p.z;
  if (dotp < 0.f) { nx = -nx; ny = -ny; nz = -nz; }
  float ax = fabsf(nx), ay = fabsf(ny), az = fabsf(nz);
  float ex = 0.f, ey = 0.f, ez = 0.f;
  if (ax <= ay && ax <= az) ex = 1.f;
  else if (ay <= az) ey = 1.f;
  else ez = 1.f;
  float tx = ny * ez - nz * ey, ty = nz * ex - nx * ez, tz = nx * ey - ny * ex;
  float tn = 1.f / sqrtf(tx * tx + ty * ty + tz * tz);
  tx *= tn; ty *= tn; tz *= tn;
  float ux = ny * tz - nz * ty, uy = nz * tx - nx * tz, uz = nx * ty - ny * tx;
  xb4[n] = make_float4(tx, ty, tz, 0.f);
  yb4[n] = make_float4(ux, uy, uz, 0.f);
}

// --------------------------- Gx/Gy + C2 + v0 = grad(pos) (sorted space, f32)
__global__ __launch_bounds__(256) void graddiv_kernel(const float4* __restrict__ sorted4,
                                                      const int* __restrict__ nbr,
                                                      const float4* __restrict__ xb4,
                                                      const float4* __restrict__ yb4,
                                                      float* __restrict__ Gx,
                                                      float* __restrict__ Gy,
                                                      float2* __restrict__ C2,
                                                      float* __restrict__ v0) {
  int n = blockIdx.x * 256 + threadIdx.x;
  if (n >= NPTS) return;
  float4 p = sorted4[n], xb = xb4[n], yb = yb4[n];
  float u[KG], vv[KG], w[KG];
  int mm[KG];
  float hsum = 0.f;
#pragma unroll
  for (int k = 0; k < KG; ++k) {
    int m = nbr[(size_t)n * KG + k];
    mm[k] = m;
    float4 pm = sorted4[m];
    float rx = pm.x - p.x, ry = pm.y - p.y, rz = pm.z - p.z;
    u[k] = rx * xb.x + ry * xb.y + rz * xb.z;
    vv[k] = rx * yb.x + ry * yb.y + rz * yb.z;
    float dd = sqrtf(rx * rx + ry * ry + rz * rz + EPSF);
    w[k] = dd; hsum += dd;
  }
  float h = hsum * (1.f / KG);
  float invden = 1.f / (h * h + EPSF);
  float A00 = 0, A01 = 0, A02 = 0, A11 = 0, A12 = 0, A22 = 0;
#pragma unroll
  for (int k = 0; k < KG; ++k) {
    float wk = __expf(-(w[k] * w[k]) * invden);
    w[k] = wk;
    A00 += wk; A01 += wk * u[k]; A02 += wk * vv[k];
    A11 += wk * u[k] * u[k]; A12 += wk * u[k] * vv[k];
    A22 += wk * vv[k] * vv[k];
  }
  A00 += 0.001f; A11 += 0.001f; A22 += 0.001f;
  float det = A00 * (A11 * A22 - A12 * A12) - A01 * (A01 * A22 - A12 * A02) +
              A02 * (A01 * A12 - A11 * A02);
  float idet = 1.f / det;
  float i10 = (A02 * A12 - A01 * A22) * idet;
  float i11 = (A00 * A22 - A02 * A02) * idet;
  float i12 = (A01 * A02 - A00 * A12) * idet;
  float i20 = (A01 * A12 - A02 * A11) * idet;
  float i21 = i12;
  float i22 = (A00 * A11 - A01 * A01) * idet;
  float a0x = 0, a0y = 0, a0z = 0, a1x = 0, a1y = 0, a1z = 0;
#pragma unroll
  for (int k = 0; k < KG; ++k) {
    float gx = w[k] * (i10 + i11 * u[k] + i12 * vv[k]);
    float gy = w[k] * (i20 + i21 * u[k] + i22 * vv[k]);
    Gx[(size_t)n * KG + k] = gx;
    Gy[(size_t)n * KG + k] = gy;
    int m = mm[k];
    float4 pm = sorted4[m];
    a0x += gx * pm.x; a0y += gx * pm.y; a0z += gx * pm.z;
    a1x += gy * pm.x; a1y += gy * pm.y; a1z += gy * pm.z;
    float4 xm = xb4[m], ym = yb4[m];
    float g3x = gx * xb.x + gy * yb.x;
    float g3y = gx * xb.y + gy * yb.y;
    float g3z = gx * xb.z + gy * yb.z;
    float ca = g3x * xm.x + g3y * xm.y + g3z * xm.z;
    float cb = g3x * ym.x + g3y * ym.y + g3z * ym.z;
    C2[(size_t)n * KG + k] = make_float2(ca, cb);
  }
  v0[((size_t)n * 2 + 0) * 3 + 0] = a0x;
  v0[((size_t)n * 2 + 0) * 3 + 1] = a0y;
  v0[((size_t)n * 2 + 0) * 3 + 2] = a0z;
  v0[((size_t)n * 2 + 1) * 3 + 0] = a1x;
  v0[((size_t)n * 2 + 1) * 3 + 1] = a1y;
  v0[((size_t)n * 2 + 1) * 3 + 2] = a1z;
}

// ------------------------------------------------- feat scalar (layer 0, cin=3, f32 in)
template <int CENTRAL>
__global__ __launch_bounds__(256) void feat16_kernel(const float* __restrict__ x, int ldx,
                                                     int cin,
                                                     const float* __restrict__ v,
                                                     const int* __restrict__ nbr,
                                                     const float2* __restrict__ C2,
                                                     unsigned short* __restrict__ feat, int Kp) {
  int per = Kp - 2 * cin;
  int gid = blockIdx.x * 256 + threadIdx.x;
  if (gid >= NPTS * per) return;
  int n = gid / per;
  int c = gid - n * per;
  size_t fb = (size_t)n * Kp;
  if (c >= cin) {  // pad column
    feat[fb + 3 * cin + (c - cin)] = 0;
    return;
  }
  float xc = x[(size_t)n * ldx + c];
  float xmax = -3.4e38f, dv = 0.f, cv = 0.f;
  for (int k = 0; k < KG; ++k) {
    int m = nbr[(size_t)n * KG + k];
    float2 cc = C2[(size_t)n * KG + k];
    float xm = x[(size_t)m * ldx + c];
    xmax = fmaxf(xmax, CENTRAL ? (xm - xc) : xm);
    float va = v[((size_t)m * 2 + 0) * cin + c];
    float vb = v[((size_t)m * 2 + 1) * cin + c];
    dv += cc.x * va + cc.y * vb;
    cv += cc.y * va - cc.x * vb;
  }
  feat[fb + c] = f2bf(xmax);
  feat[fb + cin + c] = f2bf(dv);
  feat[fb + 2 * cin + c] = f2bf(cv);
}

// ----------------------- feat vectorized: bf16 x/v mirrors, 8 ch/thread,
// per-point nbr+C2 staged in LDS once per block (cin/8 divides 256 -> whole points per block)
__global__ __launch_bounds__(256) void feat16v8_kernel(const unsigned short* __restrict__ x,
                                                       int cin,
                                                       const unsigned short* __restrict__ v,
                                                       const int* __restrict__ nbr,
                                                       const float2* __restrict__ C2,
                                                       unsigned short* __restrict__ feat) {
  __shared__ int s_nbr[32 * KG];
  __shared__ float2 s_c2[32 * KG];
  int per = cin >> 3;            // 8 (cin=64) or 16 (cin=128)
  int ppb = 256 / per;           // 32 or 16 points per block (divides NPTS)
  int pbase = blockIdx.x * ppb;
  for (int i = threadIdx.x; i < ppb * KG; i += 256) {
    int pl = i / KG;
    int kk = i - pl * KG;
    size_t src = (size_t)(pbase + pl) * KG + kk;
    s_nbr[i] = nbr[src];
    s_c2[i] = C2[src];
  }
  __syncthreads();
  int nl = threadIdx.x / per;    // local point
  int n = pbase + nl;
  int c8 = (threadIdx.x - nl * per) << 3;
  float xmax[8], dv[8], cv[8];
#pragma unroll
  for (int i = 0; i < 8; ++i) { xmax[i] = -3.4e38f; dv[i] = 0.f; cv[i] = 0.f; }
  const int* nrow = s_nbr + nl * KG;
  const float2* crow = s_c2 + nl * KG;
#pragma unroll 4
  for (int k = 0; k < KG; ++k) {
    int m = nrow[k];
    float2 cc = crow[k];
    short8v xm = *reinterpret_cast<const short8v*>(x + (size_t)m * cin + c8);
    short8v va = *reinterpret_cast<const short8v*>(v + ((size_t)m * 2 + 0) * cin + c8);
    short8v vb = *reinterpret_cast<const short8v*>(v + ((size_t)m * 2 + 1) * cin + c8);
#pragma unroll
    for (int i = 0; i < 8; ++i) {
      float xf = bf2f((unsigned short)xm[i]);
      float af = bf2f((unsigned short)va[i]);
      float bf = bf2f((unsigned short)vb[i]);
      xmax[i] = fmaxf(xmax[i], xf);
      dv[i] += cc.x * af + cc.y * bf;
      cv[i] += cc.y * af - cc.x * bf;
    }
  }
  size_t fb = (size_t)n * (3 * cin);
  short8v o0, o1, o2;
#pragma unroll
  for (int i = 0; i < 8; ++i) {
    o0[i] = (short)f2bf(xmax[i]);
    o1[i] = (short)f2bf(dv[i]);
    o2[i] = (short)f2bf(cv[i]);
  }
  *reinterpret_cast<short8v*>(&feat[fb + c8]) = o0;
  *reinterpret_cast<short8v*>(&feat[fb + cin + c8]) = o1;
  *reinterpret_cast<short8v*>(&feat[fb + 2 * cin + c8]) = o2;
}

// ------------------------------------------------- vin scalar (layer 0, Kp=96, cin=3)
__global__ __launch_bounds__(256) void vin16_kernel(const float* __restrict__ v, int cin,
                                                    const unsigned short* __restrict__ xout,
                                                    int cout,
                                                    const int* __restrict__ nbr,
                                                    const float* __restrict__ Gx,
                                                    const float* __restrict__ Gy,
                                                    unsigned short* __restrict__ vinb, int Kp,
                                                    int total) {
  int gid = blockIdx.x * 256 + threadIdx.x;
  if (gid >= total) return;
  int n = gid / Kp;
  int c = gid - n * Kp;
  int K = cin + cout;
  unsigned short o0, o1;
  if (c < cin) {
    o0 = f2bf(v[((size_t)n * 2 + 0) * cin + c]);
    o1 = f2bf(v[((size_t)n * 2 + 1) * cin + c]);
  } else if (c < K) {
    int cc = c - cin;
    float a0 = 0.f, a1 = 0.f;
    for (int k = 0; k < KG; ++k) {
      int m = nbr[(size_t)n * KG + k];
      float f = bf2f(xout[(size_t)m * cout + cc]);
      a0 += Gx[(size_t)n * KG + k] * f;
      a1 += Gy[(size_t)n * KG + k] * f;
    }
    o0 = f2bf(a0);
    o1 = f2bf(a1);
  } else {
    o0 = 0; o1 = 0;
  }
  vinb[((size_t)n * 2 + 0) * Kp + c] = o0;
  vinb[((size_t)n * 2 + 1) * Kp + c] = o1;
}

// ----------------------- vin vectorized: bf16 v + bf16 xout mirror, 8 ch/thread
__global__ __launch_bounds__(256) void vin16v8_kernel(const unsigned short* __restrict__ v,
                                                      int cin,
                                                      const unsigned short* __restrict__ xout,
                                                      int cout,
                                                      const int* __restrict__ nbr,
                                                      const float* __restrict__ Gx,
                                                      const float* __restrict__ Gy,
                                                      unsigned short* __restrict__ vinb,
                                                      int Kp) {
  int per = Kp >> 3;
  int gid = blockIdx.x * 256 + threadIdx.x;
  if (gid >= NPTS * per) return;
  int n = gid / per;
  int c8 = (gid - n * per) << 3;
  short8v o0, o1;
  if (c8 < cin) {
    o0 = *reinterpret_cast<const short8v*>(v + ((size_t)n * 2 + 0) * cin + c8);
    o1 = *reinterpret_cast<const short8v*>(v + ((size_t)n * 2 + 1) * cin + c8);
  } else {
    int cc8 = c8 - cin;
    float a0[8], a1[8];
#pragma unroll
    for (int i = 0; i < 8; ++i) { a0[i] = 0.f; a1[i] = 0.f; }
    const int* nrow = nbr + (size_t)n * KG;
    const float* gxr = Gx + (size_t)n * KG;
    const float* gyr = Gy + (size_t)n * KG;
#pragma unroll 4
    for (int k = 0; k < KG; ++k) {
      int m = nrow[k];
      float gx = gxr[k], gy = gyr[k];
      short8v f = *reinterpret_cast<const short8v*>(xout + (size_t)m * cout + cc8);
#pragma unroll
      for (int i = 0; i < 8; ++i) {
        float ff = bf2f((unsigned short)f[i]);
        a0[i] += gx * ff;
        a1[i] += gy * ff;
      }
    }
#pragma unroll
    for (int i = 0; i < 8; ++i) {
      o0[i] = (short)f2bf(a0[i]);
      o1[i] = (short)f2bf(a1[i]);
    }
  }
  *reinterpret_cast<short8v*>(&vinb[((size_t)n * 2 + 0) * Kp + c8]) = o0;
  *reinterpret_cast<short8v*>(&vinb[((size_t)n * 2 + 1) * Kp + c8]) = o1;
}

// ------------------------------------------------- bf16 MFMA GEMM
// MODE 0: Cf[rowmap[row]] = relu(A@B+bias) f32 (+ optional bf16 mirror Cb[row], sorted).
// MODE 1: normgate over row pairs, bf16 output to Cb only (sorted rows).
template <int MODE>
__global__ __launch_bounds__(256) void gemm16_kernel(const unsigned short* __restrict__ A,
                                                     const unsigned short* __restrict__ Bt,
                                                     const float* __restrict__ bias,
                                                     float* __restrict__ Cf,
                                                     unsigned short* __restrict__ Cb,
                                                     const int* __restrict__ rowmap,
                                                     int Kp, int Ncol) {
  int lane = threadIdx.x & 63;
  int wave = threadIdx.x >> 6;
  int rowBase = blockIdx.y * 64 + wave * 16;
  int colBase = blockIdx.x * 64;
  int lr = lane & 15;
  int kg = (lane >> 4) * 8;
  floatx4 acc0 = {0.f, 0.f, 0.f, 0.f};
  floatx4 acc1 = acc0, acc2 = acc0, acc3 = acc0;
  const unsigned short* arow = A + (size_t)(rowBase + lr) * Kp + kg;
  const unsigned short* b0p = Bt + (size_t)(colBase + lr) * Kp + kg;
  for (int k0 = 0; k0 < Kp; k0 += 32) {
    short8v a = *reinterpret_cast<const short8v*>(arow + k0);
    short8v b0 = *reinterpret_cast<const short8v*>(b0p + k0);
    short8v b1 = *reinterpret_cast<const short8v*>(b0p + (size_t)16 * Kp + k0);
    short8v b2 = *reinterpret_cast<const short8v*>(b0p + (size_t)32 * Kp + k0);
    short8v b3 = *reinterpret_cast<const short8v*>(b0p + (size_t)48 * Kp + k0);
    acc0 = __builtin_amdgcn_mfma_f32_16x16x32_bf16(a, b0, acc0, 0, 0, 0);
    acc1 = __builtin_amdgcn_mfma_f32_16x16x32_bf16(a, b1, acc1, 0, 0, 0);
    acc2 = __builtin_amdgcn_mfma_f32_16x16x32_bf16(a, b2, acc2, 0, 0, 0);
    acc3 = __builtin_amdgcn_mfma_f32_16x16x32_bf16(a, b3, acc3, 0, 0, 0);
  }
  int rsub = (lane >> 4) * 4;
  floatx4 accs[4] = {acc0, acc1, acc2, acc3};
  int orow[4];
  if (MODE == 0) {
#pragma unroll
    for (int r = 0; r < 4; ++r) orow[r] = rowmap[rowBase + rsub + r];
  }
#pragma unroll
  for (int nb = 0; nb < 4; ++nb) {
    int col = colBase + nb * 16 + lr;
    float bb = bias[col];
    if (MODE == 0) {
#pragma unroll
      for (int r = 0; r < 4; ++r) {
        int row = rowBase + rsub + r;
        float val = fmaxf(accs[nb][r] + bb, 0.f);
        Cf[(size_t)orow[r] * Ncol + col] = val;
        if (Cb) Cb[(size_t)row * Ncol + col] = f2bf(val);
      }
    } else {
#pragma unroll
      for (int pr = 0; pr < 2; ++pr) {
        float a0 = accs[nb][2 * pr], a1 = accs[nb][2 * pr + 1];
        float nrm = sqrtf(a0 * a0 + a1 * a1 + EPSF);
        float s = fmaxf(nrm + bb, 0.f) / (nrm + EPSF);
        int row = rowBase + rsub + 2 * pr;
        Cb[(size_t)row * Ncol + col] = f2bf(a0 * s);
        Cb[(size_t)(row + 1) * Ncol + col] = f2bf(a1 * s);
      }
    }
  }
}

// ---------------------------------------------------------------- launch
extern "C" void kernel_launch(void* const* d_in, const int* in_sizes, int n_in,
                              void* d_out, int out_size, void* d_ws, size_t ws_size,
                              hipStream_t stream) {
  const float* pts = (const float*)d_in[0];
  const float* als = (const float*)d_in[1];
  const float* Ws0 = (const float*)d_in[2];
  const float* bs0 = (const float*)d_in[3];
  const float* Wv0 = (const float*)d_in[4];
  const float* bv0 = (const float*)d_in[5];
  const float* Ws1 = (const float*)d_in[6];
  const float* bs1 = (const float*)d_in[7];
  const float* Wv1 = (const float*)d_in[8];
  const float* bv1 = (const float*)d_in[9];
  const float* Ws2 = (const float*)d_in[10];
  const float* bs2 = (const float*)d_in[11];

  char* ws = (char*)d_ws;
  float4* pos4 = (float4*)(ws + 0);               //  256 KB (original order, staging)
  int* nbr = (int*)(ws + 262144);                 // 1.31 MB (sorted-slot space)
  float4* xb4 = (float4*)(ws + 1572864);          //  256 KB (sorted)
  float4* yb4 = (float4*)(ws + 1835008);          //  256 KB (sorted)
  float* Gx = (float*)(ws + 2097152);             // 1.31 MB (sorted)
  float* Gy = (float*)(ws + 3407872);             // 1.31 MB (sorted)
  float2* C2 = (float2*)(ws + 4718592);           // 2.62 MB (sorted)
  float* v0f = (float*)(ws + 7340032);            //  393 KB (sorted)
  unsigned short* vb_a = (unsigned short*)(ws + 8388608);    // 8.39 MB (sorted)
  unsigned short* vb_b = (unsigned short*)(ws + 17825792);   // 4.19 MB (sorted)
  unsigned short* xb0m = (unsigned short*)(ws + 23068672);   // 2.10 MB (sorted)
  unsigned short* xb1m = (unsigned short*)(ws + 26214400);   // 4.19 MB (sorted)
  unsigned short* stg = (unsigned short*)(ws + 31457280);    // 12.6 MB (sorted)
  char* wtb = ws + 45088768;                      // transposed bf16 weights (~311 KB)
  unsigned short* Wt_s0 = (unsigned short*)(wtb + 0);
  unsigned short* Wt_v0 = (unsigned short*)(wtb + 4096);
  unsigned short* Wt_s1 = (unsigned short*)(wtb + 16384);
  unsigned short* Wt_v1 = (unsigned short*)(wtb + 65536);
  unsigned short* Wt_s2 = (unsigned short*)(wtb + 114688);

  char* gws = ws + 46137344;                      // knn scratch
  int* cell_count = (int*)(gws + 0);              // 128 KB
  int* fb_count = (int*)(gws + 131072);           // 4 B (memset together with cell_count)
  int* cell_start = (int*)(gws + 135168);         // 128 KB
  int* cell_cursor = (int*)(gws + 266240);        // 128 KB
  int* pt_cell = (int*)(gws + 397312);            // 64 KB
  int* fb_list = (int*)(gws + 462848);            // 64 KB
  float4* sorted4 = (float4*)(gws + 532480);      // 256 KB
  int* sortmap = (int*)(gws + 794624);            // 64 KB (slot -> original row)

  float* out0 = (float*)d_out;             // (N,64) original order
  float* out1 = out0 + (size_t)NPTS * 64;  // (N,128)
  float* out2 = out1 + (size_t)NPTS * 128; // (N,256)

  hipMemsetAsync(cell_count, 0, 131072 + 4, stream);  // cell_count + fb_count
  posbin_wprep_kernel<<<672, 256, 0, stream>>>(pts, als, pos4, cell_count, pt_cell, Ws0, Wv0,
                                               Ws1, Wv1, Ws2, Wt_s0, Wt_v0, Wt_s1, Wt_v1,
                                               Wt_s2);
  scan_kernel<<<1, 1024, 0, stream>>>(cell_count, cell_start, cell_cursor);
  scatter_kernel<<<64, 256, 0, stream>>>(pos4, pt_cell, cell_cursor, sorted4, sortmap);
  knn_grid_kernel<<<NPTS / 8, 256, 0, stream>>>(sorted4, cell_start, cell_count, nbr, fb_list,
                                                fb_count);
  knn_fb_kernel<<<128, 256, 0, stream>>>(sorted4, fb_list, fb_count, nbr);

  basis_kernel<<<64, 256, 0, stream>>>(sorted4, nbr, xb4, yb4);
  graddiv_kernel<<<64, 256, 0, stream>>>(sorted4, nbr, xb4, yb4, Gx, Gy, C2, v0f);

  // ---- layer 0 (cin=3 -> cout=64, centralized), all in sorted space
  feat16_kernel<1><<<(NPTS * 26 + 255) / 256, 256, 0, stream>>>((const float*)sorted4, 4, 3,
                                                                v0f, nbr, C2, stg, 32);
  gemm16_kernel<0><<<dim3(1, 256), 256, 0, stream>>>(stg, Wt_s0, bs0, out0, xb0m, sortmap, 32,
                                                     64);
  vin16_kernel<<<(NPTS * 96 + 255) / 256, 256, 0, stream>>>(v0f, 3, xb0m, 64, nbr, Gx, Gy, stg,
                                                            96, NPTS * 96);
  gemm16_kernel<1><<<dim3(1, 512), 256, 0, stream>>>(stg, Wt_v0, bv0, nullptr, vb_b, nullptr,
                                                     96, 64);

  // ---- layer 1 (cin=64 -> cout=128)
  feat16v8_kernel<<<NPTS * 8 / 256, 256, 0, stream>>>(xb0m, 64, vb_b, nbr, C2, stg);
  gemm16_kernel<0><<<dim3(2, 256), 256, 0, stream>>>(stg, Wt_s1, bs1, out1, xb1m, sortmap, 192,
                                                     128);
  vin16v8_kernel<<<NPTS * 24 / 256, 256, 0, stream>>>(vb_b, 64, xb1m, 128, nbr, Gx, Gy, stg,
                                                      192);
  gemm16_kernel<1><<<dim3(2, 512), 256, 0, stream>>>(stg, Wt_v1, bv1, nullptr, vb_a, nullptr,
                                                     192, 128);

  // ---- layer 2 (cin=128 -> cout=256, no vector update)
  feat16v8_kernel<<<NPTS * 16 / 256, 256, 0, stream>>>(xb1m, 128, vb_a, nbr, C2, stg);
  gemm16_kernel<0><<<dim3(4, 256), 256, 0, stream>>>(stg, Wt_s2, bs2, out2, nullptr, sortmap,
                                                     384, 256);
}

// Round 18
// 277.848 us; speedup vs baseline: 1.5075x; 1.0268x over previous
//
#include <hip/hip_runtime.h>
#include <math.h>

#define NPTS 16384
#define KG 20
#define KN 10
#define KC 6
#define EPSF 1e-8f

#define GDIM 32
#define GL 4.75f
#define CW 0.296875f
#define GINV 3.3684210526f
#define RMAX 6

typedef __attribute__((ext_vector_type(8))) short short8v;
typedef __attribute__((ext_vector_type(4))) float floatx4;

__device__ __forceinline__ unsigned short f2bf(float v) {
  union { float f; unsigned u; } x;
  x.f = v;
  unsigned r = x.u + 0x7FFFu + ((x.u >> 16) & 1u);  // RNE (finite inputs)
  return (unsigned short)(r >> 16);
}

__device__ __forceinline__ float bf2f(unsigned short u) {
  union { unsigned u32; float f; } x;
  x.u32 = (unsigned)u << 16;
  return x.f;
}

// sorted insert into KG-register list (strict <, stable by scan order)
#define KNN_INSERT(d2v, iv)                                                 \
  if ((d2v) < dist[KG - 1]) {                                               \
    dist[KG - 1] = (d2v); idx[KG - 1] = (iv);                               \
    _Pragma("unroll")                                                       \
    for (int s_ = KG - 1; s_ > 0; --s_) {                                   \
      if (dist[s_] < dist[s_ - 1]) {                                        \
        float td_ = dist[s_]; dist[s_] = dist[s_ - 1]; dist[s_ - 1] = td_;  \
        int ti_ = idx[s_]; idx[s_] = idx[s_ - 1]; idx[s_ - 1] = ti_;        \
      }                                                                     \
    }                                                                       \
  }

// sorted insert into KC-register list
#define KNN_INSERTC(d2v, iv)                                                \
  if ((d2v) < dist[KC - 1]) {                                               \
    dist[KC - 1] = (d2v); idx[KC - 1] = (iv);                               \
    _Pragma("unroll")                                                       \
    for (int s_ = KC - 1; s_ > 0; --s_) {                                   \
      if (dist[s_] < dist[s_ - 1]) {                                        \
        float td_ = dist[s_]; dist[s_] = dist[s_ - 1]; dist[s_ - 1] = td_;  \
        int ti_ = idx[s_]; idx[s_] = idx[s_ - 1]; idx[s_ - 1] = ti_;        \
      }                                                                     \
    }                                                                       \
  }

__device__ __forceinline__ int cell_of(float x) {
  int c = (int)floorf((x + GL) * GINV);
  return min(max(c, 0), GDIM - 1);
}

// ---------------- pos concat + bin (blocks 0..63) fused with weight prep (blocks 64..671)
__device__ __forceinline__ void wprep_one(const float* W, unsigned short* Wt, int K, int Kp,
                                          int N, int i) {
  int n = i / Kp, k = i - n * Kp;
  Wt[i] = (k < K) ? f2bf(W[(size_t)k * N + n]) : (unsigned short)0;
}

// Wv0 with K-permutation: Wt row kp<64 -> W[3+kp] (grad), kp in [64,67) -> W[kp-64] (v), else 0.
// Matches vin0 staging layout [grad(64) | v(3) | pad(29)]; GEMM invariant to consistent K-perm.
__device__ __forceinline__ void wprep_v0(const float* W, unsigned short* Wt, int i) {
  int n = i / 96, kp = i - n * 96;
  if (kp < 64) Wt[i] = f2bf(W[(size_t)(3 + kp) * 64 + n]);
  else if (kp < 67) Wt[i] = f2bf(W[(size_t)(kp - 64) * 64 + n]);
  else Wt[i] = 0;
}

__global__ __launch_bounds__(256) void posbin_wprep_kernel(
    const float* __restrict__ pts, const float* __restrict__ als, float4* __restrict__ pos4,
    int* __restrict__ cell_count, int* __restrict__ pt_cell,
    const float* __restrict__ Ws0, const float* __restrict__ Wv0,
    const float* __restrict__ Ws1, const float* __restrict__ Wv1,
    const float* __restrict__ Ws2, unsigned short* __restrict__ Wt_s0,
    unsigned short* __restrict__ Wt_v0, unsigned short* __restrict__ Wt_s1,
    unsigned short* __restrict__ Wt_v1, unsigned short* __restrict__ Wt_s2) {
  if (blockIdx.x < 64) {
    int n = blockIdx.x * 256 + threadIdx.x;
    if (n >= NPTS) return;
    const float* src = (n < 8192) ? (pts + (size_t)n * 3) : (als + (size_t)(n - 8192) * 3);
    float x = src[0], y = src[1], z = src[2];
    pos4[n] = make_float4(x, y, z, 0.f);
    int c = (cell_of(z) * GDIM + cell_of(y)) * GDIM + cell_of(x);
    pt_cell[n] = c;
    atomicAdd(&cell_count[c], 1);
  } else {
    int gid = (blockIdx.x - 64) * 256 + threadIdx.x;
    if (gid < 2048) wprep_one(Ws0, Wt_s0, 9, 32, 64, gid);
    else if (gid < 8192) wprep_v0(Wv0, Wt_v0, gid - 2048);
    else if (gid < 32768) wprep_one(Ws1, Wt_s1, 192, 192, 128, gid - 8192);
    else if (gid < 57344) wprep_one(Wv1, Wt_v1, 192, 192, 128, gid - 32768);
    else if (gid < 155648) wprep_one(Ws2, Wt_s2, 384, 384, 256, gid - 57344);
  }
}

__global__ __launch_bounds__(1024) void scan_kernel(const int* __restrict__ cell_count,
                                                    int* __restrict__ cell_start,
                                                    int* __restrict__ cell_cursor) {
  __shared__ int s[1024];
  int tid = threadIdx.x;
  int base = tid * 32;
  int local[32];
  int sum = 0;
#pragma unroll
  for (int i = 0; i < 32; ++i) { local[i] = cell_count[base + i]; sum += local[i]; }
  s[tid] = sum;
  __syncthreads();
  for (int off = 1; off < 1024; off <<= 1) {
    int v = (tid >= off) ? s[tid - off] : 0;
    __syncthreads();
    s[tid] += v;
    __syncthreads();
  }
  int run = s[tid] - sum;  // exclusive prefix
#pragma unroll
  for (int i = 0; i < 32; ++i) {
    cell_start[base + i] = run;
    cell_cursor[base + i] = run;
    run += local[i];
  }
}

// scatter into sorted order; sortmap[slot] = original index
__global__ __launch_bounds__(256) void scatter_kernel(const float4* __restrict__ pos4,
                                                      const int* __restrict__ pt_cell,
                                                      int* __restrict__ cell_cursor,
                                                      float4* __restrict__ sorted4,
                                                      int* __restrict__ sortmap) {
  int i = blockIdx.x * 256 + threadIdx.x;
  if (i >= NPTS) return;
  int c = pt_cell[i];
  int dst = atomicAdd(&cell_cursor[c], 1);
  float4 p = pos4[i];
  p.w = __int_as_float(i);
  sorted4[dst] = p;
  sortmap[dst] = i;
}

// --------- grid knn in SORTED-SLOT space: 2 queries/wave, 32 lanes each, cap-KC.
__global__ __launch_bounds__(256) void knn_grid_kernel(const float4* __restrict__ sorted4,
                                                       const int* __restrict__ cell_start,
                                                       const int* __restrict__ cell_count,
                                                       int* __restrict__ nbr,
                                                       int* __restrict__ fb_list,
                                                       int* __restrict__ fb_count) {
  int lane = threadIdx.x & 63;
  int sub = lane >> 5;   // 2 query subgroups per wave
  int sl = lane & 31;    // lane within subgroup
  int qs = blockIdx.x * 8 + (threadIdx.x >> 6) * 2 + sub;  // sorted-order query slot
  if (qs >= NPTS) return;
  float4 p = sorted4[qs];
  int cx = cell_of(p.x), cy = cell_of(p.y), cz = cell_of(p.z);
  float dist[KC];
  int idx[KC];
#pragma unroll
  for (int i = 0; i < KC; ++i) { dist[i] = 3.4e38f; idx[i] = 0; }

  // ---- phase 1: full box r<=1, continuous round-robin, 2-way unrolled for ILP
  {
    int tot = 0;
    int x0 = max(cx - 1, 0), x1 = min(cx + 1, GDIM - 1);
    int zlo = max(cz - 1, 0), zhi = min(cz + 1, GDIM - 1);
    int ylo = max(cy - 1, 0), yhi = min(cy + 1, GDIM - 1);
    for (int z = zlo; z <= zhi; ++z) {
      for (int y = ylo; y <= yhi; ++y) {
        int c0 = (z * GDIM + y) * GDIM + x0;
        int c1 = (z * GDIM + y) * GDIM + x1;
        int beg = cell_start[c0];
        int end = cell_start[c1] + cell_count[c1];
        int off = (sl - tot) & 31;
        for (int j = beg + off; j < end; j += 64) {
          int j1 = j + 32;
          float4 sp0 = sorted4[j];
          float4 sp1 = sorted4[(j1 < end) ? j1 : j];
          float dx0 = sp0.x - p.x, dy0 = sp0.y - p.y, dz0 = sp0.z - p.z;
          float d20 = dx0 * dx0 + dy0 * dy0 + dz0 * dz0;
          float dx1 = sp1.x - p.x, dy1 = sp1.y - p.y, dz1 = sp1.z - p.z;
          float d21 = dx1 * dx1 + dy1 * dy1 + dz1 * dz1;
          KNN_INSERTC(d20, j);
          if (j1 < end) { KNN_INSERTC(d21, j1); }
        }
        tot += end - beg;
      }
    }
  }
  int done;
  {
    float b2 = CW * CW;
    int cnt = 0;
#pragma unroll
    for (int i = 0; i < KC; ++i) cnt += (dist[i] <= b2) ? 1 : 0;
#pragma unroll
    for (int s = 1; s < 32; s <<= 1) cnt += __shfl_xor(cnt, s, 64);
    done = (cnt >= KG) ? 1 : 0;
  }

  // ---- phase 2: rings r=2..RMAX, lane-per-segment over 32 lanes
  for (int r = 2; r <= RMAX && !done; ++r) {
    int side = 2 * r + 1;
    int nt = side * side;
    float rcp = 1.0f / (float)side;
    for (int t = sl; t < nt; t += 32) {
      int qz = (int)(((float)t + 0.5f) * rcp);  // exact floor(t/side) for t<169
      int dz = qz - r;
      int dy = t - qz * side - r;
      int z = cz + dz, y = cy + dy;
      if (z < 0 || z >= GDIM || y < 0 || y >= GDIM) continue;
      int rowbase = (z * GDIM + y) * GDIM;
      if (dz == -r || dz == r || dy == -r || dy == r) {
        int xa = max(cx - r, 0), xb = min(cx + r, GDIM - 1);
        int beg = cell_start[rowbase + xa];
        int end = cell_start[rowbase + xb] + cell_count[rowbase + xb];
        for (int j = beg; j < end; ++j) {
          float4 sp = sorted4[j];
          float ddx = sp.x - p.x, ddy = sp.y - p.y, ddz = sp.z - p.z;
          float d2 = ddx * ddx + ddy * ddy + ddz * ddz;
          KNN_INSERTC(d2, j);
        }
      } else {
        int x = cx - r;
        if (x >= 0) {
          int c = rowbase + x;
          int beg = cell_start[c], end = beg + cell_count[c];
          for (int j = beg; j < end; ++j) {
            float4 sp = sorted4[j];
            float ddx = sp.x - p.x, ddy = sp.y - p.y, ddz = sp.z - p.z;
            float d2 = ddx * ddx + ddy * ddy + ddz * ddz;
            KNN_INSERTC(d2, j);
          }
        }
        x = cx + r;
        if (x < GDIM) {
          int c = rowbase + x;
          int beg = cell_start[c], end = beg + cell_count[c];
          for (int j = beg; j < end; ++j) {
            float4 sp = sorted4[j];
            float ddx = sp.x - p.x, ddy = sp.y - p.y, ddz = sp.z - p.z;
            float d2 = ddx * ddx + ddy * ddy + ddz * ddz;
            KNN_INSERTC(d2, j);
          }
        }
      }
    }
    float b = CW * (float)r;
    float b2 = b * b;
    int cnt = 0;
#pragma unroll
    for (int i = 0; i < KC; ++i) cnt += (dist[i] <= b2) ? 1 : 0;
#pragma unroll
    for (int s = 1; s < 32; s <<= 1) cnt += __shfl_xor(cnt, s, 64);
    if (cnt >= KG) done = 1;
  }

  // 32-way merge: 20 rounds of f32 min-reduce + ballot winner (lowest lane pops & writes).
  int popc = 0, ovf = 0;
  for (int round = 0; round < KG; ++round) {
    float m = dist[0];
#pragma unroll
    for (int s = 1; s < 32; s <<= 1) m = fminf(m, __shfl_xor(m, s, 64));
    unsigned long long vote = __ballot(dist[0] == m);
    unsigned msk = (unsigned)(vote >> (sub << 5));
    int wl = __ffs(msk) - 1;
    if (sl == wl) {
      nbr[(size_t)qs * KG + round] = idx[0];
#pragma unroll
      for (int s = 0; s < KC - 1; ++s) { dist[s] = dist[s + 1]; idx[s] = idx[s + 1]; }
      dist[KC - 1] = 3.4e38f;
      idx[KC - 1] = 0;
      if (++popc == KC) ovf = 1;
    }
  }
#pragma unroll
  for (int s = 1; s < 32; s <<= 1) ovf |= __shfl_xor(ovf, s, 64);
  if ((ovf || !done) && sl == 0) {
    int s = atomicAdd(fb_count, 1);
    fb_list[s] = qs;
  }
}

// ---------------------------------------------------------------- brute-force fallback (slots)
__global__ __launch_bounds__(256) void knn_fb_kernel(const float4* __restrict__ sorted4,
                                                     const int* __restrict__ fb_list,
                                                     const int* __restrict__ fb_count,
                                                     int* __restrict__ nbr) {
  __shared__ unsigned long long lists[256 * KG];
  __shared__ unsigned long long heads[256];
  __shared__ unsigned long long winner;
  int tid = threadIdx.x;
  int cnt = *fb_count;
  for (int qi = blockIdx.x; qi < cnt; qi += gridDim.x) {
    int t = fb_list[qi];
    float4 p = sorted4[t];
    float dist[KG];
    int idx[KG];
#pragma unroll
    for (int i = 0; i < KG; ++i) { dist[i] = 3.4e38f; idx[i] = 0; }
    int j0 = tid * 64;
    for (int j = j0; j < j0 + 64; ++j) {
      float4 c = sorted4[j];
      float dx = c.x - p.x, dy = c.y - p.y, dz = c.z - p.z;
      float d2 = dx * dx + dy * dy + dz * dz;
      KNN_INSERT(d2, j);
    }
#pragma unroll
    for (int i = 0; i < KG; ++i)
      lists[tid * KG + i] = ((unsigned long long)__float_as_uint(dist[i]) << 22) |
                            ((unsigned long long)(unsigned)idx[i] << 8) |
                            (unsigned long long)tid;
    int hp = 0;
    __syncthreads();
    for (int round = 0; round < KG; ++round) {
      heads[tid] = (hp < KG) ? lists[tid * KG + hp] : ~0ull;
      __syncthreads();
      if (tid < 64) {
        unsigned long long m = heads[tid];
        unsigned long long o = heads[tid + 64];  if (o < m) m = o;
        o = heads[tid + 128]; if (o < m) m = o;
        o = heads[tid + 192]; if (o < m) m = o;
#pragma unroll
        for (int s = 32; s > 0; s >>= 1) {
          unsigned long long x = __shfl_xor(m, s, 64);
          if (x < m) m = x;
        }
        if (tid == 0) winner = m;
      }
      __syncthreads();
      unsigned long long w = winner;
      if (tid == (int)(w & 0xFF)) hp++;
      if (tid == 0) nbr[(size_t)t * KG + round] = (int)((w >> 8) & 0x3FFF);
      __syncthreads();
    }
  }
}

// ---------------------------------------------------- basis (sorted space, f32)
__global__ __launch_bounds__(256) void basis_kernel(const float4* __restrict__ sorted4,
                                                    const int* __restrict__ nbr,
                                                    float4* __restrict__ xb4,
                                                    float4* __restrict__ yb4) {
  int n = blockIdx.x * 256 + threadIdx.x;
  if (n >= NPTS) return;
  float4 p = sorted4[n];
  float c00 = 0, c01 = 0, c02 = 0, c11 = 0, c12 = 0, c22 = 0;
  for (int k = 0; k < KN; ++k) {
    int m = nbr[(size_t)n * KG + k];
    float4 pm = sorted4[m];
    float dx = pm.x - p.x, dy = pm.y - p.y, dz = pm.z - p.z;
    c00 += dx * dx; c01 += dx * dy; c02 += dx * dz;
    c11 += dy * dy; c12 += dy * dz; c22 += dz * dz;
  }
  float nx = 0.f, ny = 0.f, nz = 1.f;
  float p1 = c01 * c01 + c02 * c02 + c12 * c12;
  float qm = (c00 + c11 + c22) * (1.f / 3.f);
  float g0 = c00 - qm, g1 = c11 - qm, g2 = c22 - qm;
  float p2 = g0 * g0 + g1 * g1 + g2 * g2 + 2.f * p1;
  if (p2 > 1e-16f) {
    float pp = sqrtf(p2 * (1.f / 6.f));
    float inv = 1.f / pp;
    float b00 = g0 * inv, b11 = g1 * inv, b22 = g2 * inv;
    float b01 = c01 * inv, b02 = c02 * inv, b12 = c12 * inv;
    float detB = b00 * (b11 * b22 - b12 * b12) - b01 * (b01 * b22 - b12 * b02) +
                 b02 * (b01 * b12 - b11 * b02);
    float r = 0.5f * detB;
    r = fminf(1.f, fmaxf(-1.f, r));
    float phi = acosf(r) * (1.f / 3.f);
    float e1 = qm + 2.f * pp * __cosf(phi);
    float e3 = qm + 2.f * pp * __cosf(phi + 2.0943951023931953f);
    float e2 = 3.f * qm - e1 - e3;
    float a00 = c00 - e1, a11 = c11 - e1, a22 = c22 - e1;
    float f00 = c00 - e2, f11 = c11 - e2, f22 = c22 - e2;
    float u0 = a00 * f00 + c01 * c01 + c02 * c02;
    float u1 = c01 * f00 + a11 * c01 + c12 * c02;
    float u2 = c02 * f00 + c12 * c01 + a22 * c02;
    float v0 = a00 * c01 + c01 * f11 + c02 * c12;
    float v1 = c01 * c01 + a11 * f11 + c12 * c12;
    float v2 = c02 * c01 + c12 * f11 + a22 * c12;
    float w0 = a00 * c02 + c01 * c12 + c02 * f22;
    float w1 = c01 * c02 + a11 * c12 + c12 * f22;
    float w2 = c02 * c02 + c12 * c12 + a22 * f22;
    float nu = u0 * u0 + u1 * u1 + u2 * u2;
    float nv = v0 * v0 + v1 * v1 + v2 * v2;
    float nw = w0 * w0 + w1 * w1 + w2 * w2;
    float bx = u0, by = u1, bz = u2, bn = nu;
    if (nv > bn) { bx = v0; by = v1; bz = v2; bn = nv; }
    if (nw > bn) { bx = w0; by = w1; bz = w2; bn = nw; }
    if (bn > 1e-30f) {
      float s = 1.f / sqrtf(bn);
      nx = bx * s; ny = by * s; nz = bz * s;
    }
  }
  float dotp = nx * p.x + ny * p.y + nz * p.z;
  if (dotp < 0.f) { nx = -nx; ny = -ny; nz = -nz; }
  float ax = fabsf(nx), ay = fabsf(ny), az = fabsf(nz);
  float ex = 0.f, ey = 0.f, ez = 0.f;
  if (ax <= ay && ax <= az) ex = 1.f;
  else if (ay <= az) ey = 1.f;
  else ez = 1.f;
  float tx = ny * ez - nz * ey, ty = nz * ex - nx * ez, tz = nx * ey - ny * ex;
  float tn = 1.f / sqrtf(tx * tx + ty * ty + tz * tz);
  tx *= tn; ty *= tn; tz *= tn;
  float ux = ny * tz - nz * ty, uy = nz * tx - nx * tz, uz = nx * ty - ny * tx;
  xb4[n] = make_float4(tx, ty, tz, 0.f);
  yb4[n] = make_float4(ux, uy, uz, 0.f);
}

// --------------------------- Gx/Gy + C2 + v0 = grad(pos) (sorted space, f32)
__global__ __launch_bounds__(256) void graddiv_kernel(const float4* __restrict__ sorted4,
                                                      const int* __restrict__ nbr,
                                                      const float4* __restrict__ xb4,
                                                      const float4* __restrict__ yb4,
                                                      float* __restrict__ Gx,
                                                      float* __restrict__ Gy,
                                                      float2* __restrict__ C2,
                                                      float* __restrict__ v0) {
  int n = blockIdx.x * 256 + threadIdx.x;
  if (n >= NPTS) return;
  float4 p = sorted4[n], xb = xb4[n], yb = yb4[n];
  float u[KG], vv[KG], w[KG];
  int mm[KG];
  float hsum = 0.f;
#pragma unroll
  for (int k = 0; k < KG; ++k) {
    int m = nbr[(size_t)n * KG + k];
    mm[k] = m;
    float4 pm = sorted4[m];
    float rx = pm.x - p.x, ry = pm.y - p.y, rz = pm.z - p.z;
    u[k] = rx * xb.x + ry * xb.y + rz * xb.z;
    vv[k] = rx * yb.x + ry * yb.y + rz * yb.z;
    float dd = sqrtf(rx * rx + ry * ry + rz * rz + EPSF);
    w[k] = dd; hsum += dd;
  }
  float h = hsum * (1.f / KG);
  float invden = 1.f / (h * h + EPSF);
  float A00 = 0, A01 = 0, A02 = 0, A11 = 0, A12 = 0, A22 = 0;
#pragma unroll
  for (int k = 0; k < KG; ++k) {
    float wk = __expf(-(w[k] * w[k]) * invden);
    w[k] = wk;
    A00 += wk; A01 += wk * u[k]; A02 += wk * vv[k];
    A11 += wk * u[k] * u[k]; A12 += wk * u[k] * vv[k];
    A22 += wk * vv[k] * vv[k];
  }
  A00 += 0.001f; A11 += 0.001f; A22 += 0.001f;
  float det = A00 * (A11 * A22 - A12 * A12) - A01 * (A01 * A22 - A12 * A02) +
              A02 * (A01 * A12 - A11 * A02);
  float idet = 1.f / det;
  float i10 = (A02 * A12 - A01 * A22) * idet;
  float i11 = (A00 * A22 - A02 * A02) * idet;
  float i12 = (A01 * A02 - A00 * A12) * idet;
  float i20 = (A01 * A12 - A02 * A11) * idet;
  float i21 = i12;
  float i22 = (A00 * A11 - A01 * A01) * idet;
  float a0x = 0, a0y = 0, a0z = 0, a1x = 0, a1y = 0, a1z = 0;
#pragma unroll
  for (int k = 0; k < KG; ++k) {
    float gx = w[k] * (i10 + i11 * u[k] + i12 * vv[k]);
    float gy = w[k] * (i20 + i21 * u[k] + i22 * vv[k]);
    Gx[(size_t)n * KG + k] = gx;
    Gy[(size_t)n * KG + k] = gy;
    int m = mm[k];
    float4 pm = sorted4[m];
    a0x += gx * pm.x; a0y += gx * pm.y; a0z += gx * pm.z;
    a1x += gy * pm.x; a1y += gy * pm.y; a1z += gy * pm.z;
    float4 xm = xb4[m], ym = yb4[m];
    float g3x = gx * xb.x + gy * yb.x;
    float g3y = gx * xb.y + gy * yb.y;
    float g3z = gx * xb.z + gy * yb.z;
    float ca = g3x * xm.x + g3y * xm.y + g3z * xm.z;
    float cb = g3x * ym.x + g3y * ym.y + g3z * ym.z;
    C2[(size_t)n * KG + k] = make_float2(ca, cb);
  }
  v0[((size_t)n * 2 + 0) * 3 + 0] = a0x;
  v0[((size_t)n * 2 + 0) * 3 + 1] = a0y;
  v0[((size_t)n * 2 + 0) * 3 + 2] = a0z;
  v0[((size_t)n * 2 + 1) * 3 + 0] = a1x;
  v0[((size_t)n * 2 + 1) * 3 + 1] = a1y;
  v0[((size_t)n * 2 + 1) * 3 + 2] = a1z;
}

// ------------------------------------------------- feat scalar (layer 0, cin=3, f32 in)
template <int CENTRAL>
__global__ __launch_bounds__(256) void feat16_kernel(const float* __restrict__ x, int ldx,
                                                     int cin,
                                                     const float* __restrict__ v,
                                                     const int* __restrict__ nbr,
                                                     const float2* __restrict__ C2,
                                                     unsigned short* __restrict__ feat, int Kp) {
  int per = Kp - 2 * cin;
  int gid = blockIdx.x * 256 + threadIdx.x;
  if (gid >= NPTS * per) return;
  int n = gid / per;
  int c = gid - n * per;
  size_t fb = (size_t)n * Kp;
  if (c >= cin) {  // pad column
    feat[fb + 3 * cin + (c - cin)] = 0;
    return;
  }
  float xc = x[(size_t)n * ldx + c];
  float xmax = -3.4e38f, dv = 0.f, cv = 0.f;
  for (int k = 0; k < KG; ++k) {
    int m = nbr[(size_t)n * KG + k];
    float2 cc = C2[(size_t)n * KG + k];
    float xm = x[(size_t)m * ldx + c];
    xmax = fmaxf(xmax, CENTRAL ? (xm - xc) : xm);
    float va = v[((size_t)m * 2 + 0) * cin + c];
    float vb = v[((size_t)m * 2 + 1) * cin + c];
    dv += cc.x * va + cc.y * vb;
    cv += cc.y * va - cc.x * vb;
  }
  feat[fb + c] = f2bf(xmax);
  feat[fb + cin + c] = f2bf(dv);
  feat[fb + 2 * cin + c] = f2bf(cv);
}

// ----------------------- feat vectorized: bf16 x/v mirrors, 8 ch/thread,
// per-point nbr+C2 staged in LDS once per block
__global__ __launch_bounds__(256) void feat16v8_kernel(const unsigned short* __restrict__ x,
                                                       int cin,
                                                       const unsigned short* __restrict__ v,
                                                       const int* __restrict__ nbr,
                                                       const float2* __restrict__ C2,
                                                       unsigned short* __restrict__ feat) {
  __shared__ int s_nbr[32 * KG];
  __shared__ float2 s_c2[32 * KG];
  int per = cin >> 3;            // 8 (cin=64) or 16 (cin=128)
  int ppb = 256 / per;           // 32 or 16 points per block (divides NPTS)
  int pbase = blockIdx.x * ppb;
  for (int i = threadIdx.x; i < ppb * KG; i += 256) {
    int pl = i / KG;
    int kk = i - pl * KG;
    size_t src = (size_t)(pbase + pl) * KG + kk;
    s_nbr[i] = nbr[src];
    s_c2[i] = C2[src];
  }
  __syncthreads();
  int nl = threadIdx.x / per;    // local point
  int n = pbase + nl;
  int c8 = (threadIdx.x - nl * per) << 3;
  float xmax[8], dv[8], cv[8];
#pragma unroll
  for (int i = 0; i < 8; ++i) { xmax[i] = -3.4e38f; dv[i] = 0.f; cv[i] = 0.f; }
  const int* nrow = s_nbr + nl * KG;
  const float2* crow = s_c2 + nl * KG;
#pragma unroll 4
  for (int k = 0; k < KG; ++k) {
    int m = nrow[k];
    float2 cc = crow[k];
    short8v xm = *reinterpret_cast<const short8v*>(x + (size_t)m * cin + c8);
    short8v va = *reinterpret_cast<const short8v*>(v + ((size_t)m * 2 + 0) * cin + c8);
    short8v vb = *reinterpret_cast<const short8v*>(v + ((size_t)m * 2 + 1) * cin + c8);
#pragma unroll
    for (int i = 0; i < 8; ++i) {
      float xf = bf2f((unsigned short)xm[i]);
      float af = bf2f((unsigned short)va[i]);
      float bf = bf2f((unsigned short)vb[i]);
      xmax[i] = fmaxf(xmax[i], xf);
      dv[i] += cc.x * af + cc.y * bf;
      cv[i] += cc.y * af - cc.x * bf;
    }
  }
  size_t fb = (size_t)n * (3 * cin);
  short8v o0, o1, o2;
#pragma unroll
  for (int i = 0; i < 8; ++i) {
    o0[i] = (short)f2bf(xmax[i]);
    o1[i] = (short)f2bf(dv[i]);
    o2[i] = (short)f2bf(cv[i]);
  }
  *reinterpret_cast<short8v*>(&feat[fb + c8]) = o0;
  *reinterpret_cast<short8v*>(&feat[fb + cin + c8]) = o1;
  *reinterpret_cast<short8v*>(&feat[fb + 2 * cin + c8]) = o2;
}

// ----------------------- layer-0 vin: Kp=96 layout [grad(64) | v(3) | pad(29)].
// 12 threads/point: t<8 vector-gather 8 grad channels; t in [8,12) scalar v-copy/pad.
__global__ __launch_bounds__(256) void vin0_kernel(const float* __restrict__ v0f,
                                                   const unsigned short* __restrict__ xout,
                                                   const int* __restrict__ nbr,
                                                   const float* __restrict__ Gx,
                                                   const float* __restrict__ Gy,
                                                   unsigned short* __restrict__ vinb) {
  int gid = blockIdx.x * 256 + threadIdx.x;
  int n = gid / 12;
  int t = gid - n * 12;
  if (n >= NPTS) return;
  if (t < 8) {
    int c8 = t << 3;
    float a0[8], a1[8];
#pragma unroll
    for (int i = 0; i < 8; ++i) { a0[i] = 0.f; a1[i] = 0.f; }
    const int* nrow = nbr + (size_t)n * KG;
    const float* gxr = Gx + (size_t)n * KG;
    const float* gyr = Gy + (size_t)n * KG;
#pragma unroll 4
    for (int k = 0; k < KG; ++k) {
      int m = nrow[k];
      float gx = gxr[k], gy = gyr[k];
      short8v f = *reinterpret_cast<const short8v*>(xout + (size_t)m * 64 + c8);
#pragma unroll
      for (int i = 0; i < 8; ++i) {
        float ff = bf2f((unsigned short)f[i]);
        a0[i] += gx * ff;
        a1[i] += gy * ff;
      }
    }
    short8v o0, o1;
#pragma unroll
    for (int i = 0; i < 8; ++i) {
      o0[i] = (short)f2bf(a0[i]);
      o1[i] = (short)f2bf(a1[i]);
    }
    *reinterpret_cast<short8v*>(&vinb[((size_t)n * 2 + 0) * 96 + c8]) = o0;
    *reinterpret_cast<short8v*>(&vinb[((size_t)n * 2 + 1) * 96 + c8]) = o1;
  } else {
    int base = 64 + ((t - 8) << 3);  // 64, 72, 80, 88
#pragma unroll
    for (int i = 0; i < 8; ++i) {
      int c = base + i;
      unsigned short o0 = 0, o1 = 0;
      if (c < 67) {
        o0 = f2bf(v0f[((size_t)n * 2 + 0) * 3 + (c - 64)]);
        o1 = f2bf(v0f[((size_t)n * 2 + 1) * 3 + (c - 64)]);
      }
      vinb[((size_t)n * 2 + 0) * 96 + c] = o0;
      vinb[((size_t)n * 2 + 1) * 96 + c] = o1;
    }
  }
}

// ----------------------- vin vectorized: bf16 v + bf16 xout mirror, 8 ch/thread
__global__ __launch_bounds__(256) void vin16v8_kernel(const unsigned short* __restrict__ v,
                                                      int cin,
                                                      const unsigned short* __restrict__ xout,
                                                      int cout,
                                                      const int* __restrict__ nbr,
                                                      const float* __restrict__ Gx,
                                                      const float* __restrict__ Gy,
                                                      unsigned short* __restrict__ vinb,
                                                      int Kp) {
  int per = Kp >> 3;
  int gid = blockIdx.x * 256 + threadIdx.x;
  if (gid >= NPTS * per) return;
  int n = gid / per;
  int c8 = (gid - n * per) << 3;
  short8v o0, o1;
  if (c8 < cin) {
    o0 = *reinterpret_cast<const short8v*>(v + ((size_t)n * 2 + 0) * cin + c8);
    o1 = *reinterpret_cast<const short8v*>(v + ((size_t)n * 2 + 1) * cin + c8);
  } else {
    int cc8 = c8 - cin;
    float a0[8], a1[8];
#pragma unroll
    for (int i = 0; i < 8; ++i) { a0[i] = 0.f; a1[i] = 0.f; }
    const int* nrow = nbr + (size_t)n * KG;
    const float* gxr = Gx + (size_t)n * KG;
    const float* gyr = Gy + (size_t)n * KG;
#pragma unroll 4
    for (int k = 0; k < KG; ++k) {
      int m = nrow[k];
      float gx = gxr[k], gy = gyr[k];
      short8v f = *reinterpret_cast<const short8v*>(xout + (size_t)m * cout + cc8);
#pragma unroll
      for (int i = 0; i < 8; ++i) {
        float ff = bf2f((unsigned short)f[i]);
        a0[i] += gx * ff;
        a1[i] += gy * ff;
      }
    }
#pragma unroll
    for (int i = 0; i < 8; ++i) {
      o0[i] = (short)f2bf(a0[i]);
      o1[i] = (short)f2bf(a1[i]);
    }
  }
  *reinterpret_cast<short8v*>(&vinb[((size_t)n * 2 + 0) * Kp + c8]) = o0;
  *reinterpret_cast<short8v*>(&vinb[((size_t)n * 2 + 1) * Kp + c8]) = o1;
}

// ------------------------------------------------- bf16 MFMA GEMM
// MODE 0: Cf[rowmap[row]] = relu(A@B+bias) f32 (+ optional bf16 mirror Cb[row], sorted).
// MODE 1: normgate over row pairs, bf16 output to Cb only (sorted rows).
template <int MODE>
__global__ __launch_bounds__(256) void gemm16_kernel(const unsigned short* __restrict__ A,
                                                     const unsigned short* __restrict__ Bt,
                                                     const float* __restrict__ bias,
                                                     float* __restrict__ Cf,
                                                     unsigned short* __restrict__ Cb,
                                                     const int* __restrict__ rowmap,
                                                     int Kp, int Ncol) {
  int lane = threadIdx.x & 63;
  int wave = threadIdx.x >> 6;
  int rowBase = blockIdx.y * 64 + wave * 16;
  int colBase = blockIdx.x * 64;
  int lr = lane & 15;
  int kg = (lane >> 4) * 8;
  floatx4 acc0 = {0.f, 0.f, 0.f, 0.f};
  floatx4 acc1 = acc0, acc2 = acc0, acc3 = acc0;
  const unsigned short* arow = A + (size_t)(rowBase + lr) * Kp + kg;
  const unsigned short* b0p = Bt + (size_t)(colBase + lr) * Kp + kg;
  for (int k0 = 0; k0 < Kp; k0 += 32) {
    short8v a = *reinterpret_cast<const short8v*>(arow + k0);
    short8v b0 = *reinterpret_cast<const short8v*>(b0p + k0);
    short8v b1 = *reinterpret_cast<const short8v*>(b0p + (size_t)16 * Kp + k0);
    short8v b2 = *reinterpret_cast<const short8v*>(b0p + (size_t)32 * Kp + k0);
    short8v b3 = *reinterpret_cast<const short8v*>(b0p + (size_t)48 * Kp + k0);
    acc0 = __builtin_amdgcn_mfma_f32_16x16x32_bf16(a, b0, acc0, 0, 0, 0);
    acc1 = __builtin_amdgcn_mfma_f32_16x16x32_bf16(a, b1, acc1, 0, 0, 0);
    acc2 = __builtin_amdgcn_mfma_f32_16x16x32_bf16(a, b2, acc2, 0, 0, 0);
    acc3 = __builtin_amdgcn_mfma_f32_16x16x32_bf16(a, b3, acc3, 0, 0, 0);
  }
  int rsub = (lane >> 4) * 4;
  floatx4 accs[4] = {acc0, acc1, acc2, acc3};
  int orow[4];
  if (MODE == 0) {
#pragma unroll
    for (int r = 0; r < 4; ++r) orow[r] = rowmap[rowBase + rsub + r];
  }
#pragma unroll
  for (int nb = 0; nb < 4; ++nb) {
    int col = colBase + nb * 16 + lr;
    float bb = bias[col];
    if (MODE == 0) {
#pragma unroll
      for (int r = 0; r < 4; ++r) {
        int row = rowBase + rsub + r;
        float val = fmaxf(accs[nb][r] + bb, 0.f);
        Cf[(size_t)orow[r] * Ncol + col] = val;
        if (Cb) Cb[(size_t)row * Ncol + col] = f2bf(val);
      }
    } else {
#pragma unroll
      for (int pr = 0; pr < 2; ++pr) {
        float a0 = accs[nb][2 * pr], a1 = accs[nb][2 * pr + 1];
        float nrm = sqrtf(a0 * a0 + a1 * a1 + EPSF);
        float s = fmaxf(nrm + bb, 0.f) / (nrm + EPSF);
        int row = rowBase + rsub + 2 * pr;
        Cb[(size_t)row * Ncol + col] = f2bf(a0 * s);
        Cb[(size_t)(row + 1) * Ncol + col] = f2bf(a1 * s);
      }
    }
  }
}

// ---------------------------------------------------------------- launch
extern "C" void kernel_launch(void* const* d_in, const int* in_sizes, int n_in,
                              void* d_out, int out_size, void* d_ws, size_t ws_size,
                              hipStream_t stream) {
  const float* pts = (const float*)d_in[0];
  const float* als = (const float*)d_in[1];
  const float* Ws0 = (const float*)d_in[2];
  const float* bs0 = (const float*)d_in[3];
  const float* Wv0 = (const float*)d_in[4];
  const float* bv0 = (const float*)d_in[5];
  const float* Ws1 = (const float*)d_in[6];
  const float* bs1 = (const float*)d_in[7];
  const float* Wv1 = (const float*)d_in[8];
  const float* bv1 = (const float*)d_in[9];
  const float* Ws2 = (const float*)d_in[10];
  const float* bs2 = (const float*)d_in[11];

  char* ws = (char*)d_ws;
  float4* pos4 = (float4*)(ws + 0);               //  256 KB (original order, staging)
  int* nbr = (int*)(ws + 262144);                 // 1.31 MB (sorted-slot space)
  float4* xb4 = (float4*)(ws + 1572864);          //  256 KB (sorted)
  float4* yb4 = (float4*)(ws + 1835008);          //  256 KB (sorted)
  float* Gx = (float*)(ws + 2097152);             // 1.31 MB (sorted)
  float* Gy = (float*)(ws + 3407872);             // 1.31 MB (sorted)
  float2* C2 = (float2*)(ws + 4718592);           // 2.62 MB (sorted)
  float* v0f = (float*)(ws + 7340032);            //  393 KB (sorted)
  unsigned short* vb_a = (unsigned short*)(ws + 8388608);    // 8.39 MB (sorted)
  unsigned short* vb_b = (unsigned short*)(ws + 17825792);   // 4.19 MB (sorted)
  unsigned short* xb0m = (unsigned short*)(ws + 23068672);   // 2.10 MB (sorted)
  unsigned short* xb1m = (unsigned short*)(ws + 26214400);   // 4.19 MB (sorted)
  unsigned short* stg = (unsigned short*)(ws + 31457280);    // 12.6 MB (sorted)
  char* wtb = ws + 45088768;                      // transposed bf16 weights (~311 KB)
  unsigned short* Wt_s0 = (unsigned short*)(wtb + 0);
  unsigned short* Wt_v0 = (unsigned short*)(wtb + 4096);
  unsigned short* Wt_s1 = (unsigned short*)(wtb + 16384);
  unsigned short* Wt_v1 = (unsigned short*)(wtb + 65536);
  unsigned short* Wt_s2 = (unsigned short*)(wtb + 114688);

  char* gws = ws + 46137344;                      // knn scratch
  int* cell_count = (int*)(gws + 0);              // 128 KB
  int* fb_count = (int*)(gws + 131072);           // 4 B (memset together with cell_count)
  int* cell_start = (int*)(gws + 135168);         // 128 KB
  int* cell_cursor = (int*)(gws + 266240);        // 128 KB
  int* pt_cell = (int*)(gws + 397312);            // 64 KB
  int* fb_list = (int*)(gws + 462848);            // 64 KB
  float4* sorted4 = (float4*)(gws + 532480);      // 256 KB
  int* sortmap = (int*)(gws + 794624);            // 64 KB (slot -> original row)

  float* out0 = (float*)d_out;             // (N,64) original order
  float* out1 = out0 + (size_t)NPTS * 64;  // (N,128)
  float* out2 = out1 + (size_t)NPTS * 128; // (N,256)

  hipMemsetAsync(cell_count, 0, 131072 + 4, stream);  // cell_count + fb_count
  posbin_wprep_kernel<<<672, 256, 0, stream>>>(pts, als, pos4, cell_count, pt_cell, Ws0, Wv0,
                                               Ws1, Wv1, Ws2, Wt_s0, Wt_v0, Wt_s1, Wt_v1,
                                               Wt_s2);
  scan_kernel<<<1, 1024, 0, stream>>>(cell_count, cell_start, cell_cursor);
  scatter_kernel<<<64, 256, 0, stream>>>(pos4, pt_cell, cell_cursor, sorted4, sortmap);
  knn_grid_kernel<<<NPTS / 8, 256, 0, stream>>>(sorted4, cell_start, cell_count, nbr, fb_list,
                                                fb_count);
  knn_fb_kernel<<<128, 256, 0, stream>>>(sorted4, fb_list, fb_count, nbr);

  basis_kernel<<<64, 256, 0, stream>>>(sorted4, nbr, xb4, yb4);
  graddiv_kernel<<<64, 256, 0, stream>>>(sorted4, nbr, xb4, yb4, Gx, Gy, C2, v0f);

  // ---- layer 0 (cin=3 -> cout=64, centralized), all in sorted space
  feat16_kernel<1><<<(NPTS * 26 + 255) / 256, 256, 0, stream>>>((const float*)sorted4, 4, 3,
                                                                v0f, nbr, C2, stg, 32);
  gemm16_kernel<0><<<dim3(1, 256), 256, 0, stream>>>(stg, Wt_s0, bs0, out0, xb0m, sortmap, 32,
                                                     64);
  vin0_kernel<<<NPTS * 12 / 256, 256, 0, stream>>>(v0f, xb0m, nbr, Gx, Gy, stg);
  gemm16_kernel<1><<<dim3(1, 512), 256, 0, stream>>>(stg, Wt_v0, bv0, nullptr, vb_b, nullptr,
                                                     96, 64);

  // ---- layer 1 (cin=64 -> cout=128)
  feat16v8_kernel<<<NPTS * 8 / 256, 256, 0, stream>>>(xb0m, 64, vb_b, nbr, C2, stg);
  gemm16_kernel<0><<<dim3(2, 256), 256, 0, stream>>>(stg, Wt_s1, bs1, out1, xb1m, sortmap, 192,
                                                     128);
  vin16v8_kernel<<<NPTS * 24 / 256, 256, 0, stream>>>(vb_b, 64, xb1m, 128, nbr, Gx, Gy, stg,
                                                      192);
  gemm16_kernel<1><<<dim3(2, 512), 256, 0, stream>>>(stg, Wt_v1, bv1, nullptr, vb_a, nullptr,
                                                     192, 128);

  // ---- layer 2 (cin=128 -> cout=256, no vector update)
  feat16v8_kernel<<<NPTS * 16 / 256, 256, 0, stream>>>(xb1m, 128, vb_a, nbr, C2, stg);
  gemm16_kernel<0><<<dim3(4, 256), 256, 0, stream>>>(stg, Wt_s2, bs2, out2, nullptr, sortmap,
                                                     384, 256);
}